// Round 11
// baseline (257.228 us; speedup 1.0000x reference)
//
#include <hip/hip_runtime.h>
#include <hip/hip_bf16.h>

#define NB 256
#define NN 1024
#define NSTAGES 11
#define EPSF 1e-7f

typedef unsigned short u16;
typedef unsigned int u32;
typedef unsigned long long u64;
typedef __attribute__((ext_vector_type(8))) short short8;
typedef __attribute__((ext_vector_type(16))) float f32x16;

// Output layout (float32, concatenated):
//   losses (B, 11, N); preds (B, N, 11, 2); norms (B, 11, N)
static constexpr size_t PRED_BASE = (size_t)NB * NSTAGES * NN;
static constexpr size_t NORM_BASE = PRED_BASE + (size_t)NB * NN * NSTAGES * 2;

// wfrag (u16 units): 48 B-fragments for mfma_f32_32x32x16_bf16, channel-pair
// permuted: B[k][n] at lane l, frag (ks,nt): n = 2*(l&31)+nt, k = ks*16+(l>>5)*8+j.
//   cn_W1: 0..15 (K=128) | bn_W1[0:128]: 16..31 | cn_W2: 32..39 | bn_W2: 40..47
//   packed llr_W bf16 pairs (u32[64]) at u16 offset 24576
// labW_g (separate fp32[2][64]): lab_emb[v] @ bn_W1[128:192] + bn_b1  (prep-fused)
static constexpr int LW_OFF = 24576;

// SPLIT design (R10, confirmed: FETCH 330->11 MB): stages 1..9 have pair
// distance <= 256 -> pairs stay in 512-row halves. Kernel A: 2 blocks/batch,
// ALL 48 frags in LDS. Kernel B: stage 10 + epilogues 9/10 (+fused pred
// transpose, R11). R11 also pads kernel A's e-rows to 144 B: the old 128 B
// stride put every row at bank 0 (5.5M conflicts); 144 B -> base bank 4*row.
#define WLDS_FR 30   // kernel B / mono fallback

// Workspace layout:
//   wfrag @0 (64 KB) | labW_g @65536 | pred_ws @131072 (23,068,672 B)
//   e9_ws @E9_OFF (512 chunks x 65536 B, UNPADDED layout) | vm_ws @VM_OFF
static constexpr size_t STAGE_OFF = 131072;
static constexpr size_t PRED_F2_PER_B = (size_t)NSTAGES * NN;
static constexpr size_t PRED_BYTES = (size_t)NB * NSTAGES * NN * 2 * sizeof(float);
static constexpr size_t E9_OFF = STAGE_OFF + PRED_BYTES;
static constexpr size_t E9_BYTES = (size_t)512 * 65536;
static constexpr size_t VM_OFF = E9_OFF + E9_BYTES;
static constexpr size_t NEED_SPLIT = VM_OFF + (size_t)512 * 16 * sizeof(u32);
static constexpr size_t NEED_STAGED = STAGE_OFF + PRED_BYTES;

__device__ __forceinline__ u16 f2bf(float f) {
  unsigned u = __float_as_uint(f);
  unsigned r = (u + 0x7fffu + ((u >> 16) & 1u)) >> 16;
  return (u16)r;
}
__device__ __forceinline__ unsigned pack_bf2(float a, float b) {
  __hip_bfloat162 h = __float22bfloat162_rn(make_float2(a, b));
  return *(unsigned*)&h;
}
__device__ __forceinline__ u32 spread16(u32 v) {
  v = (v | (v << 8)) & 0x00FF00FFu;
  v = (v | (v << 4)) & 0x0F0F0F0Fu;
  v = (v | (v << 2)) & 0x33333333u;
  v = (v | (v << 1)) & 0x55555555u;
  return v;
}
// STAGED: preds -> workspace in (b,s,n,2) order (dense 8 KB/stage window).
// !STAGED: direct scatter to the final (b,n,11,2) layout (fallback).
template <bool STAGED>
__device__ __forceinline__ void emit_out(float* __restrict__ out, float* __restrict__ pred_ws,
                                         int b, int n, int s,
                                         float z0, float z1, float nrm2, int label) {
  float m  = fmaxf(z0, z1);
  float p0 = expf(z0 - m), p1 = expf(z1 - m);
  float inv = 1.0f / (p0 + p1);
  p0 *= inv; p1 *= inv;
  float pt = label ? p1 : p0;
  pt = fminf(fmaxf(pt, EPSF), 1.0f);
  out[((size_t)b * NSTAGES + s) * NN + n] = -logf(pt);
  if (STAGED) {
    ((float2*)pred_ws)[((size_t)b * NSTAGES + s) * NN + n] = make_float2(p0, p1);
  } else {
    size_t pb = PRED_BASE + (((size_t)b * NN + n) * NSTAGES + s) * 2;
    out[pb + 0] = p0;
    out[pb + 1] = p1;
  }
  out[NORM_BASE + ((size_t)b * NSTAGES + s) * NN + n] = sqrtf(nrm2);
}

// Unpadded swizzled e-LDS addressing (kernel B, e9_ws layout): row = 64 u16
// (128 B) = 8 chunks of 16 B; chunk = logical XOR (row & 7).
__device__ __forceinline__ int eaddr(int row, int c16) {
  return row * 64 + (((c16) ^ (row & 7)) << 3);
}
__device__ __forceinline__ int eaddr32(int row, int m31) {
  return row * 64 + (((((m31) >> 2) ^ (row & 7)) << 3) | (((m31) & 3) << 1));
}
// Padded variants (kernel A only): row stride 72 u16 = 144 B -> row base
// bank = 4*row mod 32, breaking the all-rows-at-bank-0 aliasing of the
// 128 B stride (R10: 5.5M conflict-cycles). Same chunk-XOR swizzle.
__device__ __forceinline__ int eaddrA(int row, int c16) {
  return row * 72 + (((c16) ^ (row & 7)) << 3);
}
__device__ __forceinline__ int eaddr32A(int row, int m31) {
  return row * 72 + (((((m31) >> 2) ^ (row & 7)) << 3) | (((m31) & 3) << 1));
}

__global__ __launch_bounds__(256) void prep_kernel(
    const float* __restrict__ cn_W1, const float* __restrict__ bn_W1,
    const float* __restrict__ cn_W2, const float* __restrict__ bn_W2,
    const float* __restrict__ lab_emb, const float* __restrict__ llr_W,
    const float* __restrict__ bn_b1,
    u16* __restrict__ wfrag, float* __restrict__ labW_g) {
  int t = blockIdx.x * 256 + threadIdx.x;
  if (t < 3072) {
    int f = t >> 6, l = t & 63, h = l >> 5, c = l & 31;
    const float* src; int ks, nt;
    if (f < 16)      { src = cn_W1; ks = f >> 1; nt = f & 1; }
    else if (f < 32) { int g = f - 16; src = bn_W1; ks = g >> 1; nt = g & 1; }
    else if (f < 40) { int g = f - 32; src = cn_W2; ks = g >> 1; nt = g & 1; }
    else             { int g = f - 40; src = bn_W2; ks = g >> 1; nt = g & 1; }
    int col = 2 * c + nt;
    u16 vals[8];
    #pragma unroll
    for (int j = 0; j < 8; ++j) {
      int k = ks * 16 + h * 8 + j;
      vals[j] = f2bf(src[k * 64 + col]);
    }
    uint4 u;
    u.x = (unsigned)vals[0] | ((unsigned)vals[1] << 16);
    u.y = (unsigned)vals[2] | ((unsigned)vals[3] << 16);
    u.z = (unsigned)vals[4] | ((unsigned)vals[5] << 16);
    u.w = (unsigned)vals[6] | ((unsigned)vals[7] << 16);
    *(uint4*)(wfrag + (size_t)t * 8) = u;
  } else if (t < 3136) {
    int k = t - 3072;
    unsigned wv = (unsigned)f2bf(llr_W[k * 2]) | ((unsigned)f2bf(llr_W[k * 2 + 1]) << 16);
    ((unsigned*)(wfrag + LW_OFF))[k] = wv;
  } else if (t < 3264) {
    int idx = t - 3136;
    int v = idx >> 6, c = idx & 63;
    float acc = bn_b1[c];
    for (int d = 0; d < 64; ++d)
      acc = fmaf(lab_emb[v * 64 + d], bn_W1[(128 + d) * 64 + c], acc);
    labW_g[idx] = acc;
  }
}

// Memory-only finisher (mono fallback path only; split path fuses this into
// polar_b): ws (b,s,n,2) -> out preds (b,n,11,2) via an LDS tile.
__global__ __launch_bounds__(512) void pred_transpose_kernel(
    const float* __restrict__ pred_ws, float* __restrict__ out) {
  __shared__ float2 tb[NSTAGES * 1026];
  const int tid = threadIdx.x;
  const int b = blockIdx.x;
  const float2* src = (const float2*)pred_ws + (size_t)b * PRED_F2_PER_B;
  for (int i = tid; i < NSTAGES * NN; i += 512) {
    int s = i >> 10, n = i & (NN - 1);
    tb[s * 1026 + n] = src[i];
  }
  __syncthreads();
  float2* dst = (float2*)(out + PRED_BASE) + (size_t)b * PRED_F2_PER_B;
  for (int j = tid; j < NSTAGES * NN; j += 512) {
    int n = j / NSTAGES, s = j - n * NSTAGES;
    dst[j] = tb[s * 1026 + n];
  }
}

// All-LDS frag read (kernel A, 48 frags resident).
#define AFR(FI) (*(const short8*)(wlds + (FI) * 512 + ln * 8))
// Mixed read (kernel B / mono): 30 LDS + 18 global.
#define BFR(FI) (((FI) < WLDS_FR) ? *(const short8*)(wlds + (FI) * 512 + ln * 8) \
                                  : *(const short8*)(wfrag + (size_t)(FI) * 512 + ln * 8))

// ===================== Kernel A: stages 0..9, half-row blocks ==============
// grid 512: b = blockIdx.x >> 1, h = blockIdx.x & 1. Owns rows [512h,512h+512).
// 8 waves x 1 tile of 32 pairs. eLh rows padded to 144 B (R11).
__global__ __launch_bounds__(512, 2) void polar_a_kernel(
    const int* __restrict__ x, const float* __restrict__ y,
    const float* __restrict__ emb_W, const float* __restrict__ emb_b,
    const u16* __restrict__ wfrag, const float* __restrict__ labW_g,
    const float* __restrict__ cn_b1, const float* __restrict__ cn_b2,
    const float* __restrict__ bn_b2, const float* __restrict__ llr_W,
    const float* __restrict__ llr_b, float* __restrict__ pred_ws,
    u16* __restrict__ e9_ws, u32* __restrict__ vm_ws,
    float* __restrict__ out) {
  __shared__ __align__(16) u16 eLh[512 * 72];          // 73728 B (padded rows)
  __shared__ __align__(16) u16 wlds[48 * 512];         // 49152 B (ALL frags)
  __shared__ u32 lwL[64];                              // 256 B
  __shared__ u32 vmask[2][16];                         // 128 B
  __shared__ float labW[2][64];                        // 512 B

  const int tid = threadIdx.x;
  const int w = tid >> 6, ln = tid & 63;
  const int m31 = ln & 31, h8 = ln >> 5;
  const int b = blockIdx.x >> 1, h = blockIdx.x & 1;

  for (int i = tid; i < 48 * 64; i += 512)
    ((uint4*)wlds)[i] = ((const uint4*)wfrag)[i];
  if (tid < 64) lwL[tid] = ((const u32*)(wfrag + LW_OFF))[tid];
  if (tid < 128) ((float*)labW)[tid] = labW_g[tid];

  const float lb0 = llr_b[0], lb1 = llr_b[1];
  const float2 cb1 = *(const float2*)(cn_b1 + 2 * m31);
  const float2 cb2 = *(const float2*)(cn_b2 + 2 * m31);
  const float2 bb2 = *(const float2*)(bn_b2 + 2 * m31);

  // ---------------- stage 0: one row per thread ----------------
  {
    int nl = tid;
    int n = 512 * h + nl;
    float2 yv = *(const float2*)(y + ((size_t)b * NN + n) * 2);
    float z0 = lb0, z1 = lb1, nr = 0.f;
    #pragma unroll
    for (int o8 = 0; o8 < 8; ++o8) {
      u32 vals[4];
      #pragma unroll
      for (int jj = 0; jj < 4; ++jj) {
        int o = o8 * 8 + jj * 2;
        float e0 = fmaf(yv.x, emb_W[o],     fmaf(yv.y, emb_W[64 + o],     emb_b[o]));
        float e1 = fmaf(yv.x, emb_W[o + 1], fmaf(yv.y, emb_W[64 + o + 1], emb_b[o + 1]));
        vals[jj] = pack_bf2(e0, e1);
        z0 = fmaf(e0, llr_W[o * 2 + 0], z0); z1 = fmaf(e0, llr_W[o * 2 + 1], z1);
        nr = fmaf(e0, e0, nr);
        z0 = fmaf(e1, llr_W[o * 2 + 2], z0); z1 = fmaf(e1, llr_W[o * 2 + 3], z1);
        nr = fmaf(e1, e1, nr);
      }
      uint4 q; q.x = vals[0]; q.y = vals[1]; q.z = vals[2]; q.w = vals[3];
      *(uint4*)(eLh + eaddrA(nl, o8)) = q;
    }
    int v = x[(size_t)b * NN + n] & 1;
    emit_out<true>(out, pred_ws, b, n, 0, z0, z1, nr, v);
    u64 bm = __ballot(v != 0);
    if (ln == 0)  vmask[0][2 * w]     = (u32)bm;
    if (ln == 32) vmask[0][2 * w + 1] = (u32)(bm >> 32);
  }
  __syncthreads();

  const float2 lwv0 = *(const float2*)(&labW[0][2 * m31]);
  const float2 lwv1 = *(const float2*)(&labW[1][2 * m31]);

  // ---------------- stages 1..9 (pairs stay in this half) ----------------
  #pragma unroll 1
  for (int s = 1; s <= 9; ++s) {
    const int sh = s - 1;
    const int half = 1 << sh;
    const u32* vmR = vmask[(s - 1) & 1];
    u32* vmW = vmask[s & 1];

    short8 Ao[4], Ae[4];
    int iog, ieg, iol, iel, vo, ve, vx;
    u32 bxs;
    {
      int i = 256 * h + 32 * w + m31;              // global pair index
      int g = i >> sh, u = i & (half - 1);
      iog = g * (half << 1) + u;
      ieg = iog + half;
      iol = iog & 511; iel = ieg & 511;            // local rows
      #pragma unroll
      for (int f = 0; f < 4; ++f) {
        Ao[f] = *(const short8*)(eLh + eaddrA(iol, f * 2 + h8));
        Ae[f] = *(const short8*)(eLh + eaddrA(iel, f * 2 + h8));
      }
      vo = (vmR[iol >> 5] >> (iol & 31)) & 1;
      ve = (vmR[iel >> 5] >> (iel & 31)) & 1;
      vx = vo ^ ve;
      u32 bx = (u32)__ballot(vx != 0);
      u32 be = (u32)__ballot(ve != 0);
      bxs = bx;
      u32 lo = spread16(bx & 0xffffu) | (spread16(be & 0xffffu) << 1);
      u32 hi = spread16(bx >> 16) | (spread16(be >> 16) << 1);
      if (ln == 0) { vmW[2 * w] = lo; vmW[2 * w + 1] = hi; }
    }
    __syncthreads();

    // epilogue for stage s-1 (s>=2), using A-frags in regs
    if (s >= 2) {
      const uint4* lwq = (const uint4*)lwL;
      uint4 lq[4][2];
      #pragma unroll
      for (int f = 0; f < 4; ++f) {
        lq[f][0] = lwq[f * 4 + h8 * 2];
        lq[f][1] = lwq[f * 4 + h8 * 2 + 1];
      }
      #pragma unroll
      for (int side = 0; side < 2; ++side) {
        float z0 = 0.f, z1 = 0.f, nr = 0.f;
        #pragma unroll
        for (int f = 0; f < 4; ++f) {
          short8 av8 = side ? Ae[f] : Ao[f];
          #pragma unroll
          for (int j = 0; j < 8; ++j) {
            u32 pv = ((const u32*)&av8)[j >> 1];
            float val = __uint_as_float((j & 1) ? (pv & 0xffff0000u) : (pv << 16));
            u32 lwp = (j < 4) ? ((const u32*)&lq[f][0])[j] : ((const u32*)&lq[f][1])[j - 4];
            z0 = fmaf(val, __uint_as_float(lwp << 16), z0);
            z1 = fmaf(val, __uint_as_float(lwp & 0xffff0000u), z1);
            nr = fmaf(val, val, nr);
          }
        }
        z0 += __shfl_xor(z0, 32);
        z1 += __shfl_xor(z1, 32);
        nr += __shfl_xor(nr, 32);
        if (h8 == 0)
          emit_out<true>(out, pred_ws, b, side ? ieg : iog, s - 1,
                         z0 + lb0, z1 + lb1, nr, side ? ve : vo);
      }
    }

    // ---- layer-1 cn (K=128) ----
    f32x16 a0, a1;
    #pragma unroll
    for (int r = 0; r < 16; ++r) { a0[r] = cb1.x; a1[r] = cb1.y; }
    #pragma unroll
    for (int ks = 0; ks < 8; ++ks) {
      short8 B0 = AFR(ks * 2 + 0);
      short8 B1 = AFR(ks * 2 + 1);
      short8 a = (ks < 4) ? Ao[ks] : Ae[ks - 4];
      a0 = __builtin_amdgcn_mfma_f32_32x32x16_bf16(a, B0, a0, 0, 0, 0);
      a1 = __builtin_amdgcn_mfma_f32_32x32x16_bf16(a, B1, a1, 0, 0, 0);
    }
    {
      int obase = 64 * w;
      #pragma unroll
      for (int r = 0; r < 16; ++r) {
        int row = (r & 3) + 8 * (r >> 2) + 4 * h8;
        int R = obase + 2 * row;
        *(u32*)(eLh + eaddr32A(R, m31)) =
            pack_bf2(fmaxf(a0[r], 0.f), fmaxf(a1[r], 0.f));
      }
    }

    // ---- layer-1 bn (K=128 + fused labW bias) ----
    #pragma unroll
    for (int r = 0; r < 16; ++r) {
      int row = (r & 3) + 8 * (r >> 2) + 4 * h8;
      int bit = (bxs >> row) & 1;
      a0[r] = bit ? lwv1.x : lwv0.x;
      a1[r] = bit ? lwv1.y : lwv0.y;
    }
    #pragma unroll
    for (int ks = 0; ks < 8; ++ks) {
      short8 B0 = AFR(16 + ks * 2 + 0);
      short8 B1 = AFR(16 + ks * 2 + 1);
      short8 a = (ks < 4) ? Ao[ks] : Ae[ks - 4];
      a0 = __builtin_amdgcn_mfma_f32_32x32x16_bf16(a, B0, a0, 0, 0, 0);
      a1 = __builtin_amdgcn_mfma_f32_32x32x16_bf16(a, B1, a1, 0, 0, 0);
    }
    {
      int obase = 64 * w;
      #pragma unroll
      for (int r = 0; r < 16; ++r) {
        int row = (r & 3) + 8 * (r >> 2) + 4 * h8;
        int R = obase + 2 * row + 1;
        *(u32*)(eLh + eaddr32A(R, m31)) =
            pack_bf2(fmaxf(a0[r], 0.f), fmaxf(a1[r], 0.f));
      }
    }

    // ---- layer-2 cn ----
    {
      short8 Hc[4];
      {
        int R = 64 * w + 2 * m31;
        #pragma unroll
        for (int f = 0; f < 4; ++f)
          Hc[f] = *(const short8*)(eLh + eaddrA(R, f * 2 + h8));
      }
      f32x16 d0, d1;
      #pragma unroll
      for (int r = 0; r < 16; ++r) { d0[r] = cb2.x; d1[r] = cb2.y; }
      #pragma unroll
      for (int ks = 0; ks < 4; ++ks) {
        short8 B0 = AFR(32 + ks * 2 + 0);
        short8 B1 = AFR(32 + ks * 2 + 1);
        d0 = __builtin_amdgcn_mfma_f32_32x32x16_bf16(Hc[ks], B0, d0, 0, 0, 0);
        d1 = __builtin_amdgcn_mfma_f32_32x32x16_bf16(Hc[ks], B1, d1, 0, 0, 0);
      }
      int obase = 64 * w;
      #pragma unroll
      for (int r = 0; r < 16; ++r) {
        int row = (r & 3) + 8 * (r >> 2) + 4 * h8;
        int R = obase + 2 * row;
        *(u32*)(eLh + eaddr32A(R, m31)) = pack_bf2(d0[r], d1[r]);
      }
    }

    // ---- layer-2 bn ----
    {
      short8 Hb[4];
      {
        int R = 64 * w + 2 * m31 + 1;
        #pragma unroll
        for (int f = 0; f < 4; ++f)
          Hb[f] = *(const short8*)(eLh + eaddrA(R, f * 2 + h8));
      }
      f32x16 d0, d1;
      #pragma unroll
      for (int r = 0; r < 16; ++r) { d0[r] = bb2.x; d1[r] = bb2.y; }
      #pragma unroll
      for (int ks = 0; ks < 4; ++ks) {
        short8 B0 = AFR(40 + ks * 2 + 0);
        short8 B1 = AFR(40 + ks * 2 + 1);
        d0 = __builtin_amdgcn_mfma_f32_32x32x16_bf16(Hb[ks], B0, d0, 0, 0, 0);
        d1 = __builtin_amdgcn_mfma_f32_32x32x16_bf16(Hb[ks], B1, d1, 0, 0, 0);
      }
      int obase = 64 * w;
      #pragma unroll
      for (int r = 0; r < 16; ++r) {
        int row = (r & 3) + 8 * (r >> 2) + 4 * h8;
        int R = obase + 2 * row + 1;
        *(u32*)(eLh + eaddr32A(R, m31)) = pack_bf2(d0[r], d1[r]);
      }
    }
    __syncthreads();
  }

  // ---------------- dump e9 half (padded -> unpadded) + stage-9 vmask ------
  {
    u16* dst = e9_ws + (size_t)(b * 2 + h) * 32768;
    for (int idx = tid; idx < 4096; idx += 512) {
      int r = idx >> 3, c = idx & 7;
      *(uint4*)(dst + r * 64 + c * 8) = *(const uint4*)(eLh + r * 72 + c * 8);
    }
    if (tid < 16) vm_ws[(b * 2 + h) * 16 + tid] = vmask[1][tid];  // 9&1 == 1
  }
}

// ===================== Kernel B: stage 10 + epilogues 9,10 + transpose =====
// grid 256 (b), 8 waves x 2 tiles. Reads e9 pairs (i, i+512) from workspace;
// computes stage 10 into full eL; final epilogue; then (R11) reuses the dead
// eL as the pred-transpose tile, replacing the separate transpose kernel.
__global__ __launch_bounds__(512, 2) void polar_b_kernel(
    const u16* __restrict__ wfrag, const float* __restrict__ labW_g,
    const float* __restrict__ cn_b1, const float* __restrict__ cn_b2,
    const float* __restrict__ bn_b2, const float* __restrict__ llr_b,
    float* __restrict__ pred_ws, const u16* __restrict__ e9_ws,
    const u32* __restrict__ vm_ws, float* __restrict__ out) {
  __shared__ __align__(16) u16 eL[NN * 64];            // 131072 B
  __shared__ __align__(16) u16 wlds[WLDS_FR * 512];    // 30720 B
  __shared__ u32 lwL[64];                              // 256 B
  __shared__ u32 vmA[32];                              // stage-9 labels
  __shared__ u32 vmB[32];                              // stage-10 labels
  __shared__ float labW[2][64];                        // 512 B

  const int tid = threadIdx.x;
  const int w = tid >> 6, ln = tid & 63;
  const int m31 = ln & 31, h8 = ln >> 5;
  const int b = blockIdx.x;

  for (int i = tid; i < WLDS_FR * 64; i += 512)
    ((uint4*)wlds)[i] = ((const uint4*)wfrag)[i];
  if (tid < 64) lwL[tid] = ((const u32*)(wfrag + LW_OFF))[tid];
  if (tid < 128) ((float*)labW)[tid] = labW_g[tid];
  if (tid < 32) vmA[tid] = vm_ws[b * 32 + tid];        // h=0 words 0..15, h=1 16..31

  const float lb0 = llr_b[0], lb1 = llr_b[1];
  const float2 cb1 = *(const float2*)(cn_b1 + 2 * m31);
  const float2 cb2 = *(const float2*)(cn_b2 + 2 * m31);
  const float2 bb2 = *(const float2*)(bn_b2 + 2 * m31);
  __syncthreads();                                     // preamble LDS visible

  const float2 lwv0 = *(const float2*)(&labW[0][2 * m31]);
  const float2 lwv1 = *(const float2*)(&labW[1][2 * m31]);

  const u16* e9a = e9_ws + (size_t)(b * 2 + 0) * 32768;
  const u16* e9b = e9_ws + (size_t)(b * 2 + 1) * 32768;

  // ---- A-read phase: pairs (i, i+512) from the two halves ----
  short8 Ao[2][4], Ae[2][4];
  int io[2], ie[2], vo[2], ve[2], vx[2];
  u32 bxs[2];
  #pragma unroll
  for (int t = 0; t < 2; ++t) {
    int i = 64 * w + 32 * t + m31;                     // pair index [0,512)
    io[t] = i; ie[t] = i + 512;
    #pragma unroll
    for (int f = 0; f < 4; ++f) {
      Ao[t][f] = *(const short8*)(e9a + eaddr(i, f * 2 + h8));
      Ae[t][f] = *(const short8*)(e9b + eaddr(i, f * 2 + h8));  // local row = i
    }
    vo[t] = (vmA[i >> 5] >> (i & 31)) & 1;
    ve[t] = (vmA[(i >> 5) + 16] >> (i & 31)) & 1;
    vx[t] = vo[t] ^ ve[t];
    u32 bx = (u32)__ballot(vx[t] != 0);
    u32 be = (u32)__ballot(ve[t] != 0);
    bxs[t] = bx;
    u32 lo = spread16(bx & 0xffffu) | (spread16(be & 0xffffu) << 1);
    u32 hi = spread16(bx >> 16) | (spread16(be >> 16) << 1);
    if (ln == 0) { vmB[4 * w + 2 * t] = lo; vmB[4 * w + 2 * t + 1] = hi; }
  }
  __syncthreads();

  // ---- epilogue for stage 9 (A-frags in regs) ----
  {
    const uint4* lwq = (const uint4*)lwL;
    uint4 lq[4][2];
    #pragma unroll
    for (int f = 0; f < 4; ++f) {
      lq[f][0] = lwq[f * 4 + h8 * 2];
      lq[f][1] = lwq[f * 4 + h8 * 2 + 1];
    }
    #pragma unroll
    for (int t = 0; t < 2; ++t) {
      #pragma unroll
      for (int side = 0; side < 2; ++side) {
        float z0 = 0.f, z1 = 0.f, nr = 0.f;
        #pragma unroll
        for (int f = 0; f < 4; ++f) {
          short8 av8 = side ? Ae[t][f] : Ao[t][f];
          #pragma unroll
          for (int j = 0; j < 8; ++j) {
            u32 pv = ((const u32*)&av8)[j >> 1];
            float val = __uint_as_float((j & 1) ? (pv & 0xffff0000u) : (pv << 16));
            u32 lwp = (j < 4) ? ((const u32*)&lq[f][0])[j] : ((const u32*)&lq[f][1])[j - 4];
            z0 = fmaf(val, __uint_as_float(lwp << 16), z0);
            z1 = fmaf(val, __uint_as_float(lwp & 0xffff0000u), z1);
            nr = fmaf(val, val, nr);
          }
        }
        z0 += __shfl_xor(z0, 32);
        z1 += __shfl_xor(z1, 32);
        nr += __shfl_xor(nr, 32);
        if (h8 == 0)
          emit_out<true>(out, pred_ws, b, side ? ie[t] : io[t], 9,
                         z0 + lb0, z1 + lb1, nr, side ? ve[t] : vo[t]);
      }
    }
  }

  // ---- layer-1 cn ----
  f32x16 a0[2], a1[2];
  #pragma unroll
  for (int t = 0; t < 2; ++t)
    #pragma unroll
    for (int r = 0; r < 16; ++r) { a0[t][r] = cb1.x; a1[t][r] = cb1.y; }
  #pragma unroll
  for (int ks = 0; ks < 8; ++ks) {
    short8 B0 = BFR(ks * 2 + 0);
    short8 B1 = BFR(ks * 2 + 1);
    #pragma unroll
    for (int t = 0; t < 2; ++t) {
      short8 a = (ks < 4) ? Ao[t][ks] : Ae[t][ks - 4];
      a0[t] = __builtin_amdgcn_mfma_f32_32x32x16_bf16(a, B0, a0[t], 0, 0, 0);
      a1[t] = __builtin_amdgcn_mfma_f32_32x32x16_bf16(a, B1, a1[t], 0, 0, 0);
    }
  }
  #pragma unroll
  for (int t = 0; t < 2; ++t) {
    int obase = 128 * w + 64 * t;
    #pragma unroll
    for (int r = 0; r < 16; ++r) {
      int row = (r & 3) + 8 * (r >> 2) + 4 * h8;
      int R = obase + 2 * row;
      *(u32*)(eL + eaddr32(R, m31)) =
          pack_bf2(fmaxf(a0[t][r], 0.f), fmaxf(a1[t][r], 0.f));
    }
  }

  // ---- layer-1 bn ----
  #pragma unroll
  for (int t = 0; t < 2; ++t)
    #pragma unroll
    for (int r = 0; r < 16; ++r) {
      int row = (r & 3) + 8 * (r >> 2) + 4 * h8;
      int bit = (bxs[t] >> row) & 1;
      a0[t][r] = bit ? lwv1.x : lwv0.x;
      a1[t][r] = bit ? lwv1.y : lwv0.y;
    }
  #pragma unroll
  for (int ks = 0; ks < 8; ++ks) {
    short8 B0 = BFR(16 + ks * 2 + 0);
    short8 B1 = BFR(16 + ks * 2 + 1);
    #pragma unroll
    for (int t = 0; t < 2; ++t) {
      short8 a = (ks < 4) ? Ao[t][ks] : Ae[t][ks - 4];
      a0[t] = __builtin_amdgcn_mfma_f32_32x32x16_bf16(a, B0, a0[t], 0, 0, 0);
      a1[t] = __builtin_amdgcn_mfma_f32_32x32x16_bf16(a, B1, a1[t], 0, 0, 0);
    }
  }
  #pragma unroll
  for (int t = 0; t < 2; ++t) {
    int obase = 128 * w + 64 * t;
    #pragma unroll
    for (int r = 0; r < 16; ++r) {
      int row = (r & 3) + 8 * (r >> 2) + 4 * h8;
      int R = obase + 2 * row + 1;
      *(u32*)(eL + eaddr32(R, m31)) =
          pack_bf2(fmaxf(a0[t][r], 0.f), fmaxf(a1[t][r], 0.f));
    }
  }

  // ---- layer-2 cn ----
  {
    short8 Hc[2][4];
    #pragma unroll
    for (int t = 0; t < 2; ++t) {
      int R = 128 * w + 64 * t + 2 * m31;
      #pragma unroll
      for (int f = 0; f < 4; ++f)
        Hc[t][f] = *(const short8*)(eL + eaddr(R, f * 2 + h8));
    }
    f32x16 d0[2], d1[2];
    #pragma unroll
    for (int t = 0; t < 2; ++t)
      #pragma unroll
      for (int r = 0; r < 16; ++r) { d0[t][r] = cb2.x; d1[t][r] = cb2.y; }
    #pragma unroll
    for (int ks = 0; ks < 4; ++ks) {
      short8 B0 = BFR(32 + ks * 2 + 0);
      short8 B1 = BFR(32 + ks * 2 + 1);
      #pragma unroll
      for (int t = 0; t < 2; ++t) {
        d0[t] = __builtin_amdgcn_mfma_f32_32x32x16_bf16(Hc[t][ks], B0, d0[t], 0, 0, 0);
        d1[t] = __builtin_amdgcn_mfma_f32_32x32x16_bf16(Hc[t][ks], B1, d1[t], 0, 0, 0);
      }
    }
    #pragma unroll
    for (int t = 0; t < 2; ++t) {
      int obase = 128 * w + 64 * t;
      #pragma unroll
      for (int r = 0; r < 16; ++r) {
        int row = (r & 3) + 8 * (r >> 2) + 4 * h8;
        int R = obase + 2 * row;
        *(u32*)(eL + eaddr32(R, m31)) = pack_bf2(d0[t][r], d1[t][r]);
      }
    }
  }

  // ---- layer-2 bn ----
  {
    short8 Hb[2][4];
    #pragma unroll
    for (int t = 0; t < 2; ++t) {
      int R = 128 * w + 64 * t + 2 * m31 + 1;
      #pragma unroll
      for (int f = 0; f < 4; ++f)
        Hb[t][f] = *(const short8*)(eL + eaddr(R, f * 2 + h8));
    }
    f32x16 d0[2], d1[2];
    #pragma unroll
    for (int t = 0; t < 2; ++t)
      #pragma unroll
      for (int r = 0; r < 16; ++r) { d0[t][r] = bb2.x; d1[t][r] = bb2.y; }
    #pragma unroll
    for (int ks = 0; ks < 4; ++ks) {
      short8 B0 = BFR(40 + ks * 2 + 0);
      short8 B1 = BFR(40 + ks * 2 + 1);
      #pragma unroll
      for (int t = 0; t < 2; ++t) {
        d0[t] = __builtin_amdgcn_mfma_f32_32x32x16_bf16(Hb[t][ks], B0, d0[t], 0, 0, 0);
        d1[t] = __builtin_amdgcn_mfma_f32_32x32x16_bf16(Hb[t][ks], B1, d1[t], 0, 0, 0);
      }
    }
    #pragma unroll
    for (int t = 0; t < 2; ++t) {
      int obase = 128 * w + 64 * t;
      #pragma unroll
      for (int r = 0; r < 16; ++r) {
        int row = (r & 3) + 8 * (r >> 2) + 4 * h8;
        int R = obase + 2 * row + 1;
        *(u32*)(eL + eaddr32(R, m31)) = pack_bf2(d0[t][r], d1[t][r]);
      }
    }
  }
  __syncthreads();

  // ---- final epilogue (stage 10) ----
  {
    const uint4* lwq = (const uint4*)lwL;
    uint4 lq[4][2];
    #pragma unroll
    for (int f = 0; f < 4; ++f) {
      lq[f][0] = lwq[f * 4 + h8 * 2];
      lq[f][1] = lwq[f * 4 + h8 * 2 + 1];
    }
    #pragma unroll
    for (int it = 0; it < 4; ++it) {
      int n = 128 * w + 32 * it + m31;
      float z0 = 0.f, z1 = 0.f, nr = 0.f;
      #pragma unroll
      for (int f = 0; f < 4; ++f) {
        short8 av8 = *(const short8*)(eL + eaddr(n, f * 2 + h8));
        #pragma unroll
        for (int j = 0; j < 8; ++j) {
          u32 pv = ((const u32*)&av8)[j >> 1];
          float val = __uint_as_float((j & 1) ? (pv & 0xffff0000u) : (pv << 16));
          u32 lwp = (j < 4) ? ((const u32*)&lq[f][0])[j] : ((const u32*)&lq[f][1])[j - 4];
          z0 = fmaf(val, __uint_as_float(lwp << 16), z0);
          z1 = fmaf(val, __uint_as_float(lwp & 0xffff0000u), z1);
          nr = fmaf(val, val, nr);
        }
      }
      z0 += __shfl_xor(z0, 32);
      z1 += __shfl_xor(z1, 32);
      nr += __shfl_xor(nr, 32);
      int lab = (vmB[n >> 5] >> (n & 31)) & 1;
      if (h8 == 0)
        emit_out<true>(out, pred_ws, b, n, NSTAGES - 1, z0 + lb0, z1 + lb1, nr, lab);
    }
  }

  // ---- fused pred transpose (eL is dead; reuse as (s,n) tile) ----
  // __syncthreads provides block-level visibility of our own pred_ws global
  // writes (stages 9,10); stages 0..8 were written by polar_a (kernel-ordered).
  __syncthreads();
  {
    float2* tb = (float2*)eL;                          // 11*1026*8 = 90288 B
    const float2* srcp = (const float2*)pred_ws + (size_t)b * PRED_F2_PER_B;
    for (int i = tid; i < NSTAGES * NN; i += 512) {
      int s = i >> 10, n = i & (NN - 1);
      tb[s * 1026 + n] = srcp[i];
    }
    __syncthreads();
    float2* dstp = (float2*)(out + PRED_BASE) + (size_t)b * PRED_F2_PER_B;
    for (int j = tid; j < NSTAGES * NN; j += 512) {
      int n = j / NSTAGES, s = j - n * NSTAGES;
      dstp[j] = tb[s * 1026 + n];
    }
  }
}

// ===================== Mono fallback (R6, best single-kernel) ==============
template <int STAGED>
__global__ __launch_bounds__(512, 2) void polar_mono_kernel(
    const int* __restrict__ x, const float* __restrict__ y,
    const float* __restrict__ emb_W, const float* __restrict__ emb_b,
    const u16* __restrict__ wfrag, const float* __restrict__ labW_g,
    const float* __restrict__ cn_b1, const float* __restrict__ cn_b2,
    const float* __restrict__ bn_b2, const float* __restrict__ llr_W,
    const float* __restrict__ llr_b, float* __restrict__ pred_ws,
    float* __restrict__ out) {
  __shared__ __align__(16) u16 eL[NN * 64];
  __shared__ __align__(16) u16 wlds[WLDS_FR * 512];
  __shared__ u32 lwL[64];
  __shared__ u32 vmask[2][32];
  __shared__ float labW[2][64];

  const int tid = threadIdx.x;
  const int w = tid >> 6, ln = tid & 63;
  const int m31 = ln & 31, h8 = ln >> 5;
  const int b = blockIdx.x;

  for (int i = tid; i < WLDS_FR * 64; i += 512)
    ((uint4*)wlds)[i] = ((const uint4*)wfrag)[i];
  if (tid < 64) lwL[tid] = ((const u32*)(wfrag + LW_OFF))[tid];
  if (tid < 128) ((float*)labW)[tid] = labW_g[tid];

  const float lb0 = llr_b[0], lb1 = llr_b[1];
  const float2 cb1 = *(const float2*)(cn_b1 + 2 * m31);
  const float2 cb2 = *(const float2*)(cn_b2 + 2 * m31);
  const float2 bb2 = *(const float2*)(bn_b2 + 2 * m31);

  #pragma unroll
  for (int rep = 0; rep < 2; ++rep) {
    int n = rep * 512 + tid;
    float2 yv = *(const float2*)(y + ((size_t)b * NN + n) * 2);
    float z0 = lb0, z1 = lb1, nr = 0.f;
    #pragma unroll
    for (int o8 = 0; o8 < 8; ++o8) {
      u32 vals[4];
      #pragma unroll
      for (int jj = 0; jj < 4; ++jj) {
        int o = o8 * 8 + jj * 2;
        float e0 = fmaf(yv.x, emb_W[o],     fmaf(yv.y, emb_W[64 + o],     emb_b[o]));
        float e1 = fmaf(yv.x, emb_W[o + 1], fmaf(yv.y, emb_W[64 + o + 1], emb_b[o + 1]));
        vals[jj] = pack_bf2(e0, e1);
        z0 = fmaf(e0, llr_W[o * 2 + 0], z0); z1 = fmaf(e0, llr_W[o * 2 + 1], z1);
        nr = fmaf(e0, e0, nr);
        z0 = fmaf(e1, llr_W[o * 2 + 2], z0); z1 = fmaf(e1, llr_W[o * 2 + 3], z1);
        nr = fmaf(e1, e1, nr);
      }
      uint4 q; q.x = vals[0]; q.y = vals[1]; q.z = vals[2]; q.w = vals[3];
      *(uint4*)(eL + eaddr(n, o8)) = q;
    }
    int v = x[(size_t)b * NN + n] & 1;
    emit_out<STAGED != 0>(out, pred_ws, b, n, 0, z0, z1, nr, v);
    u64 bm = __ballot(v != 0);
    if (ln == 0)  vmask[0][rep * 16 + 2 * w]     = (u32)bm;
    if (ln == 32) vmask[0][rep * 16 + 2 * w + 1] = (u32)(bm >> 32);
  }
  __syncthreads();

  const float2 lwv0 = *(const float2*)(&labW[0][2 * m31]);
  const float2 lwv1 = *(const float2*)(&labW[1][2 * m31]);

  #pragma unroll 1
  for (int s = 1; s <= 10; ++s) {
    const int sh = s - 1;
    const int half = 1 << sh;
    const u32* vmR = vmask[(s - 1) & 1];
    u32* vmW = vmask[s & 1];

    short8 Ao[2][4], Ae[2][4];
    int io[2], ie[2], vo[2], ve[2], vx[2];
    u32 bxs[2];
    #pragma unroll
    for (int t = 0; t < 2; ++t) {
      int i = 64 * w + 32 * t + m31;
      int g = i >> sh, u = i & (half - 1);
      io[t] = g * (half << 1) + u;
      ie[t] = io[t] + half;
      #pragma unroll
      for (int f = 0; f < 4; ++f) {
        Ao[t][f] = *(const short8*)(eL + eaddr(io[t], f * 2 + h8));
        Ae[t][f] = *(const short8*)(eL + eaddr(ie[t], f * 2 + h8));
      }
      vo[t] = (vmR[io[t] >> 5] >> (io[t] & 31)) & 1;
      ve[t] = (vmR[ie[t] >> 5] >> (ie[t] & 31)) & 1;
      vx[t] = vo[t] ^ ve[t];
      u32 bx = (u32)__ballot(vx[t] != 0);
      u32 be = (u32)__ballot(ve[t] != 0);
      bxs[t] = bx;
      u32 lo = spread16(bx & 0xffffu) | (spread16(be & 0xffffu) << 1);
      u32 hi = spread16(bx >> 16) | (spread16(be >> 16) << 1);
      if (ln == 0) { vmW[4 * w + 2 * t] = lo; vmW[4 * w + 2 * t + 1] = hi; }
    }
    __syncthreads();

    if (s >= 2) {
      const uint4* lwq = (const uint4*)lwL;
      uint4 lq[4][2];
      #pragma unroll
      for (int f = 0; f < 4; ++f) {
        lq[f][0] = lwq[f * 4 + h8 * 2];
        lq[f][1] = lwq[f * 4 + h8 * 2 + 1];
      }
      #pragma unroll
      for (int t = 0; t < 2; ++t) {
        #pragma unroll
        for (int side = 0; side < 2; ++side) {
          float z0 = 0.f, z1 = 0.f, nr = 0.f;
          #pragma unroll
          for (int f = 0; f < 4; ++f) {
            short8 av8 = side ? Ae[t][f] : Ao[t][f];
            #pragma unroll
            for (int j = 0; j < 8; ++j) {
              u32 pv = ((const u32*)&av8)[j >> 1];
              float val = __uint_as_float((j & 1) ? (pv & 0xffff0000u) : (pv << 16));
              u32 lwp = (j < 4) ? ((const u32*)&lq[f][0])[j] : ((const u32*)&lq[f][1])[j - 4];
              z0 = fmaf(val, __uint_as_float(lwp << 16), z0);
              z1 = fmaf(val, __uint_as_float(lwp & 0xffff0000u), z1);
              nr = fmaf(val, val, nr);
            }
          }
          z0 += __shfl_xor(z0, 32);
          z1 += __shfl_xor(z1, 32);
          nr += __shfl_xor(nr, 32);
          if (h8 == 0)
            emit_out<STAGED != 0>(out, pred_ws, b, side ? ie[t] : io[t], s - 1,
                                  z0 + lb0, z1 + lb1, nr, side ? ve[t] : vo[t]);
        }
      }
    }

    f32x16 a0[2], a1[2];
    #pragma unroll
    for (int t = 0; t < 2; ++t)
      #pragma unroll
      for (int r = 0; r < 16; ++r) { a0[t][r] = cb1.x; a1[t][r] = cb1.y; }
    #pragma unroll
    for (int ks = 0; ks < 8; ++ks) {
      short8 B0 = BFR(ks * 2 + 0);
      short8 B1 = BFR(ks * 2 + 1);
      #pragma unroll
      for (int t = 0; t < 2; ++t) {
        short8 a = (ks < 4) ? Ao[t][ks] : Ae[t][ks - 4];
        a0[t] = __builtin_amdgcn_mfma_f32_32x32x16_bf16(a, B0, a0[t], 0, 0, 0);
        a1[t] = __builtin_amdgcn_mfma_f32_32x32x16_bf16(a, B1, a1[t], 0, 0, 0);
      }
    }
    #pragma unroll
    for (int t = 0; t < 2; ++t) {
      int obase = 128 * w + 64 * t;
      #pragma unroll
      for (int r = 0; r < 16; ++r) {
        int row = (r & 3) + 8 * (r >> 2) + 4 * h8;
        int R = obase + 2 * row;
        *(u32*)(eL + eaddr32(R, m31)) =
            pack_bf2(fmaxf(a0[t][r], 0.f), fmaxf(a1[t][r], 0.f));
      }
    }

    #pragma unroll
    for (int t = 0; t < 2; ++t)
      #pragma unroll
      for (int r = 0; r < 16; ++r) {
        int row = (r & 3) + 8 * (r >> 2) + 4 * h8;
        int bit = (bxs[t] >> row) & 1;
        a0[t][r] = bit ? lwv1.x : lwv0.x;
        a1[t][r] = bit ? lwv1.y : lwv0.y;
      }
    #pragma unroll
    for (int ks = 0; ks < 8; ++ks) {
      short8 B0 = BFR(16 + ks * 2 + 0);
      short8 B1 = BFR(16 + ks * 2 + 1);
      #pragma unroll
      for (int t = 0; t < 2; ++t) {
        short8 a = (ks < 4) ? Ao[t][ks] : Ae[t][ks - 4];
        a0[t] = __builtin_amdgcn_mfma_f32_32x32x16_bf16(a, B0, a0[t], 0, 0, 0);
        a1[t] = __builtin_amdgcn_mfma_f32_32x32x16_bf16(a, B1, a1[t], 0, 0, 0);
      }
    }
    #pragma unroll
    for (int t = 0; t < 2; ++t) {
      int obase = 128 * w + 64 * t;
      #pragma unroll
      for (int r = 0; r < 16; ++r) {
        int row = (r & 3) + 8 * (r >> 2) + 4 * h8;
        int R = obase + 2 * row + 1;
        *(u32*)(eL + eaddr32(R, m31)) =
            pack_bf2(fmaxf(a0[t][r], 0.f), fmaxf(a1[t][r], 0.f));
      }
    }

    {
      short8 Hc[2][4];
      #pragma unroll
      for (int t = 0; t < 2; ++t) {
        int R = 128 * w + 64 * t + 2 * m31;
        #pragma unroll
        for (int f = 0; f < 4; ++f)
          Hc[t][f] = *(const short8*)(eL + eaddr(R, f * 2 + h8));
      }
      f32x16 d0[2], d1[2];
      #pragma unroll
      for (int t = 0; t < 2; ++t)
        #pragma unroll
        for (int r = 0; r < 16; ++r) { d0[t][r] = cb2.x; d1[t][r] = cb2.y; }
      #pragma unroll
      for (int ks = 0; ks < 4; ++ks) {
        short8 B0 = BFR(32 + ks * 2 + 0);
        short8 B1 = BFR(32 + ks * 2 + 1);
        #pragma unroll
        for (int t = 0; t < 2; ++t) {
          d0[t] = __builtin_amdgcn_mfma_f32_32x32x16_bf16(Hc[t][ks], B0, d0[t], 0, 0, 0);
          d1[t] = __builtin_amdgcn_mfma_f32_32x32x16_bf16(Hc[t][ks], B1, d1[t], 0, 0, 0);
        }
      }
      #pragma unroll
      for (int t = 0; t < 2; ++t) {
        int obase = 128 * w + 64 * t;
        #pragma unroll
        for (int r = 0; r < 16; ++r) {
          int row = (r & 3) + 8 * (r >> 2) + 4 * h8;
          int R = obase + 2 * row;
          *(u32*)(eL + eaddr32(R, m31)) = pack_bf2(d0[t][r], d1[t][r]);
        }
      }
    }

    {
      short8 Hb[2][4];
      #pragma unroll
      for (int t = 0; t < 2; ++t) {
        int R = 128 * w + 64 * t + 2 * m31 + 1;
        #pragma unroll
        for (int f = 0; f < 4; ++f)
          Hb[t][f] = *(const short8*)(eL + eaddr(R, f * 2 + h8));
      }
      f32x16 d0[2], d1[2];
      #pragma unroll
      for (int t = 0; t < 2; ++t)
        #pragma unroll
        for (int r = 0; r < 16; ++r) { d0[t][r] = bb2.x; d1[t][r] = bb2.y; }
      #pragma unroll
      for (int ks = 0; ks < 4; ++ks) {
        short8 B0 = BFR(40 + ks * 2 + 0);
        short8 B1 = BFR(40 + ks * 2 + 1);
        #pragma unroll
        for (int t = 0; t < 2; ++t) {
          d0[t] = __builtin_amdgcn_mfma_f32_32x32x16_bf16(Hb[t][ks], B0, d0[t], 0, 0, 0);
          d1[t] = __builtin_amdgcn_mfma_f32_32x32x16_bf16(Hb[t][ks], B1, d1[t], 0, 0, 0);
        }
      }
      #pragma unroll
      for (int t = 0; t < 2; ++t) {
        int obase = 128 * w + 64 * t;
        #pragma unroll
        for (int r = 0; r < 16; ++r) {
          int row = (r & 3) + 8 * (r >> 2) + 4 * h8;
          int R = obase + 2 * row + 1;
          *(u32*)(eL + eaddr32(R, m31)) = pack_bf2(d0[t][r], d1[t][r]);
        }
      }
    }
    __syncthreads();
  }

  {
    const uint4* lwq = (const uint4*)lwL;
    uint4 lq[4][2];
    #pragma unroll
    for (int f = 0; f < 4; ++f) {
      lq[f][0] = lwq[f * 4 + h8 * 2];
      lq[f][1] = lwq[f * 4 + h8 * 2 + 1];
    }
    #pragma unroll
    for (int it = 0; it < 4; ++it) {
      int n = 128 * w + 32 * it + m31;
      float z0 = 0.f, z1 = 0.f, nr = 0.f;
      #pragma unroll
      for (int f = 0; f < 4; ++f) {
        short8 av8 = *(const short8*)(eL + eaddr(n, f * 2 + h8));
        #pragma unroll
        for (int j = 0; j < 8; ++j) {
          u32 pv = ((const u32*)&av8)[j >> 1];
          float val = __uint_as_float((j & 1) ? (pv & 0xffff0000u) : (pv << 16));
          u32 lwp = (j < 4) ? ((const u32*)&lq[f][0])[j] : ((const u32*)&lq[f][1])[j - 4];
          z0 = fmaf(val, __uint_as_float(lwp << 16), z0);
          z1 = fmaf(val, __uint_as_float(lwp & 0xffff0000u), z1);
          nr = fmaf(val, val, nr);
        }
      }
      z0 += __shfl_xor(z0, 32);
      z1 += __shfl_xor(z1, 32);
      nr += __shfl_xor(nr, 32);
      int lab = (vmask[0][n >> 5] >> (n & 31)) & 1;
      if (h8 == 0)
        emit_out<STAGED != 0>(out, pred_ws, b, n, NSTAGES - 1, z0 + lb0, z1 + lb1, nr, lab);
    }
  }
}

extern "C" void kernel_launch(void* const* d_in, const int* in_sizes, int n_in,
                              void* d_out, int out_size, void* d_ws, size_t ws_size,
                              hipStream_t stream) {
  const int*   x      = (const int*)d_in[0];
  const float* y      = (const float*)d_in[1];
  const float* emb_W  = (const float*)d_in[2];
  const float* emb_b  = (const float*)d_in[3];
  const float* labemb = (const float*)d_in[4];
  const float* cn_W1  = (const float*)d_in[5];
  const float* cn_b1  = (const float*)d_in[6];
  const float* cn_W2  = (const float*)d_in[7];
  const float* cn_b2  = (const float*)d_in[8];
  const float* bn_W1  = (const float*)d_in[9];
  const float* bn_b1  = (const float*)d_in[10];
  const float* bn_W2  = (const float*)d_in[11];
  const float* bn_b2  = (const float*)d_in[12];
  const float* llr_W  = (const float*)d_in[13];
  const float* llr_b  = (const float*)d_in[14];
  float* out = (float*)d_out;

  u16* wfrag = (u16*)d_ws;
  float* labW_g = (float*)((char*)d_ws + 65536);
  float* pred_ws = (float*)((char*)d_ws + STAGE_OFF);
  u16* e9_ws = (u16*)((char*)d_ws + E9_OFF);
  u32* vm_ws = (u32*)((char*)d_ws + VM_OFF);

  prep_kernel<<<13, 256, 0, stream>>>(cn_W1, bn_W1, cn_W2, bn_W2, labemb, llr_W,
                                      bn_b1, wfrag, labW_g);
  if (ws_size >= NEED_SPLIT) {
    polar_a_kernel<<<2 * NB, 512, 0, stream>>>(x, y, emb_W, emb_b, wfrag, labW_g,
                                               cn_b1, cn_b2, bn_b2, llr_W, llr_b,
                                               pred_ws, e9_ws, vm_ws, out);
    polar_b_kernel<<<NB, 512, 0, stream>>>(wfrag, labW_g, cn_b1, cn_b2, bn_b2,
                                           llr_b, pred_ws, e9_ws, vm_ws, out);
  } else if (ws_size >= NEED_STAGED) {
    polar_mono_kernel<1><<<NB, 512, 0, stream>>>(x, y, emb_W, emb_b, wfrag, labW_g,
                                                 cn_b1, cn_b2, bn_b2, llr_W, llr_b,
                                                 pred_ws, out);
    pred_transpose_kernel<<<NB, 512, 0, stream>>>(pred_ws, out);
  } else {
    polar_mono_kernel<0><<<NB, 512, 0, stream>>>(x, y, emb_W, emb_b, wfrag, labW_g,
                                                 cn_b1, cn_b2, bn_b2, llr_W, llr_b,
                                                 pred_ws, out);
  }
}

// Round 12
// 253.523 us; speedup vs baseline: 1.0146x; 1.0146x over previous
//
#include <hip/hip_runtime.h>
#include <hip/hip_bf16.h>

#define NB 256
#define NN 1024
#define NSTAGES 11
#define EPSF 1e-7f

typedef unsigned short u16;
typedef unsigned int u32;
typedef unsigned long long u64;
typedef __attribute__((ext_vector_type(8))) short short8;
typedef __attribute__((ext_vector_type(16))) float f32x16;

// Output layout (float32, concatenated):
//   losses (B, 11, N); preds (B, N, 11, 2); norms (B, 11, N)
static constexpr size_t PRED_BASE = (size_t)NB * NSTAGES * NN;
static constexpr size_t NORM_BASE = PRED_BASE + (size_t)NB * NN * NSTAGES * 2;

// wfrag (u16 units): 48 B-fragments for mfma_f32_32x32x16_bf16, channel-pair
// permuted: B[k][n] at lane l, frag (ks,nt): n = 2*(l&31)+nt, k = ks*16+(l>>5)*8+j.
//   cn_W1: 0..15 (K=128) | bn_W1[0:128]: 16..31 | cn_W2: 32..39 | bn_W2: 40..47
//   packed llr_W bf16 pairs (u32[64]) at u16 offset 24576
// labW_g (separate fp32[2][64]): lab_emb[v] @ bn_W1[128:192] + bn_b1  (prep-fused)
static constexpr int LW_OFF = 24576;

// SPLIT design (R10, confirmed: FETCH 330->11 MB): stages 1..9 have pair
// distance <= 256 -> pairs stay in 512-row halves. Kernel A: 2 blocks/batch,
// ALL 48 frags in LDS. Kernel B: stage 10 + epilogues 9/10.
// R11 falsified two refinements (reverted here): 144 B row padding DOUBLED
// bank conflicts (5.5M->11.6M; pad breaks the 16B-chunk swizzle's bank-quad
// disjointness), and fusing the pred transpose into B was neutral.
#define WLDS_FR 30   // kernel B / mono fallback

// Workspace layout:
//   wfrag @0 (64 KB) | labW_g @65536 | pred_ws @131072 (23,068,672 B)
//   e9_ws @E9_OFF (512 chunks x 65536 B) | vm_ws @VM_OFF (512 x 16 u32)
static constexpr size_t STAGE_OFF = 131072;
static constexpr size_t PRED_F2_PER_B = (size_t)NSTAGES * NN;
static constexpr size_t PRED_BYTES = (size_t)NB * NSTAGES * NN * 2 * sizeof(float);
static constexpr size_t E9_OFF = STAGE_OFF + PRED_BYTES;
static constexpr size_t E9_BYTES = (size_t)512 * 65536;
static constexpr size_t VM_OFF = E9_OFF + E9_BYTES;
static constexpr size_t NEED_SPLIT = VM_OFF + (size_t)512 * 16 * sizeof(u32);
static constexpr size_t NEED_STAGED = STAGE_OFF + PRED_BYTES;

__device__ __forceinline__ u16 f2bf(float f) {
  unsigned u = __float_as_uint(f);
  unsigned r = (u + 0x7fffu + ((u >> 16) & 1u)) >> 16;
  return (u16)r;
}
__device__ __forceinline__ unsigned pack_bf2(float a, float b) {
  __hip_bfloat162 h = __float22bfloat162_rn(make_float2(a, b));
  return *(unsigned*)&h;
}
__device__ __forceinline__ u32 spread16(u32 v) {
  v = (v | (v << 8)) & 0x00FF00FFu;
  v = (v | (v << 4)) & 0x0F0F0F0Fu;
  v = (v | (v << 2)) & 0x33333333u;
  v = (v | (v << 1)) & 0x55555555u;
  return v;
}
// STAGED: preds -> workspace in (b,s,n,2) order (dense 8 KB/stage window).
// !STAGED: direct scatter to the final (b,n,11,2) layout (fallback).
template <bool STAGED>
__device__ __forceinline__ void emit_out(float* __restrict__ out, float* __restrict__ pred_ws,
                                         int b, int n, int s,
                                         float z0, float z1, float nrm2, int label) {
  float m  = fmaxf(z0, z1);
  float p0 = expf(z0 - m), p1 = expf(z1 - m);
  float inv = 1.0f / (p0 + p1);
  p0 *= inv; p1 *= inv;
  float pt = label ? p1 : p0;
  pt = fminf(fmaxf(pt, EPSF), 1.0f);
  out[((size_t)b * NSTAGES + s) * NN + n] = -logf(pt);
  if (STAGED) {
    ((float2*)pred_ws)[((size_t)b * NSTAGES + s) * NN + n] = make_float2(p0, p1);
  } else {
    size_t pb = PRED_BASE + (((size_t)b * NN + n) * NSTAGES + s) * 2;
    out[pb + 0] = p0;
    out[pb + 1] = p1;
  }
  out[NORM_BASE + ((size_t)b * NSTAGES + s) * NN + n] = sqrtf(nrm2);
}

// Swizzled e-LDS addressing (u16 units). Row = 64 u16 (128 B) = 8 chunks of
// 16 B; physical chunk = logical_chunk XOR (row & 7) to break stride-128 bank
// conflicts on per-lane row gathers. (row & 7) is invariant under the 512-row
// local/global shift, so kernel A's local rows and kernel B's reads agree.
__device__ __forceinline__ int eaddr(int row, int c16) {
  return row * 64 + (((c16) ^ (row & 7)) << 3);
}
__device__ __forceinline__ int eaddr32(int row, int m31) {
  return row * 64 + (((((m31) >> 2) ^ (row & 7)) << 3) | (((m31) & 3) << 1));
}

__global__ __launch_bounds__(256) void prep_kernel(
    const float* __restrict__ cn_W1, const float* __restrict__ bn_W1,
    const float* __restrict__ cn_W2, const float* __restrict__ bn_W2,
    const float* __restrict__ lab_emb, const float* __restrict__ llr_W,
    const float* __restrict__ bn_b1,
    u16* __restrict__ wfrag, float* __restrict__ labW_g) {
  int t = blockIdx.x * 256 + threadIdx.x;
  if (t < 3072) {
    int f = t >> 6, l = t & 63, h = l >> 5, c = l & 31;
    const float* src; int ks, nt;
    if (f < 16)      { src = cn_W1; ks = f >> 1; nt = f & 1; }
    else if (f < 32) { int g = f - 16; src = bn_W1; ks = g >> 1; nt = g & 1; }
    else if (f < 40) { int g = f - 32; src = cn_W2; ks = g >> 1; nt = g & 1; }
    else             { int g = f - 40; src = bn_W2; ks = g >> 1; nt = g & 1; }
    int col = 2 * c + nt;
    u16 vals[8];
    #pragma unroll
    for (int j = 0; j < 8; ++j) {
      int k = ks * 16 + h * 8 + j;
      vals[j] = f2bf(src[k * 64 + col]);
    }
    uint4 u;
    u.x = (unsigned)vals[0] | ((unsigned)vals[1] << 16);
    u.y = (unsigned)vals[2] | ((unsigned)vals[3] << 16);
    u.z = (unsigned)vals[4] | ((unsigned)vals[5] << 16);
    u.w = (unsigned)vals[6] | ((unsigned)vals[7] << 16);
    *(uint4*)(wfrag + (size_t)t * 8) = u;
  } else if (t < 3136) {
    int k = t - 3072;
    unsigned wv = (unsigned)f2bf(llr_W[k * 2]) | ((unsigned)f2bf(llr_W[k * 2 + 1]) << 16);
    ((unsigned*)(wfrag + LW_OFF))[k] = wv;
  } else if (t < 3264) {
    int idx = t - 3136;
    int v = idx >> 6, c = idx & 63;
    float acc = bn_b1[c];
    for (int d = 0; d < 64; ++d)
      acc = fmaf(lab_emb[v * 64 + d], bn_W1[(128 + d) * 64 + c], acc);
    labW_g[idx] = acc;
  }
}

// Memory-only finisher: ws (b,s,n,2) -> out preds (b,n,11,2), both sides
// dense full-line accesses via an LDS tile.
__global__ __launch_bounds__(512) void pred_transpose_kernel(
    const float* __restrict__ pred_ws, float* __restrict__ out) {
  __shared__ float2 tb[NSTAGES * 1026];
  const int tid = threadIdx.x;
  const int b = blockIdx.x;
  const float2* src = (const float2*)pred_ws + (size_t)b * PRED_F2_PER_B;
  for (int i = tid; i < NSTAGES * NN; i += 512) {
    int s = i >> 10, n = i & (NN - 1);
    tb[s * 1026 + n] = src[i];
  }
  __syncthreads();
  float2* dst = (float2*)(out + PRED_BASE) + (size_t)b * PRED_F2_PER_B;
  for (int j = tid; j < NSTAGES * NN; j += 512) {
    int n = j / NSTAGES, s = j - n * NSTAGES;
    dst[j] = tb[s * 1026 + n];
  }
}

// All-LDS frag read (kernel A, 48 frags resident).
#define AFR(FI) (*(const short8*)(wlds + (FI) * 512 + ln * 8))
// Mixed read (kernel B / mono): 30 LDS + 18 global.
#define BFR(FI) (((FI) < WLDS_FR) ? *(const short8*)(wlds + (FI) * 512 + ln * 8) \
                                  : *(const short8*)(wfrag + (size_t)(FI) * 512 + ln * 8))

// ===================== Kernel A: stages 0..9, half-row blocks ==============
// grid 512: b = blockIdx.x >> 1, h = blockIdx.x & 1. Owns rows [512h,512h+512).
// 8 waves x 1 tile of 32 pairs (R9's flattening, correctness-proven).
// Pairs handled: global i in [256h, 256h+256); local p = i - 256h = 32w+m31.
__global__ __launch_bounds__(512, 2) void polar_a_kernel(
    const int* __restrict__ x, const float* __restrict__ y,
    const float* __restrict__ emb_W, const float* __restrict__ emb_b,
    const u16* __restrict__ wfrag, const float* __restrict__ labW_g,
    const float* __restrict__ cn_b1, const float* __restrict__ cn_b2,
    const float* __restrict__ bn_b2, const float* __restrict__ llr_W,
    const float* __restrict__ llr_b, float* __restrict__ pred_ws,
    u16* __restrict__ e9_ws, u32* __restrict__ vm_ws,
    float* __restrict__ out) {
  __shared__ __align__(16) u16 eLh[512 * 64];          // 65536 B
  __shared__ __align__(16) u16 wlds[48 * 512];         // 49152 B (ALL frags)
  __shared__ u32 lwL[64];                              // 256 B
  __shared__ u32 vmask[2][16];                         // 128 B
  __shared__ float labW[2][64];                        // 512 B

  const int tid = threadIdx.x;
  const int w = tid >> 6, ln = tid & 63;
  const int m31 = ln & 31, h8 = ln >> 5;
  const int b = blockIdx.x >> 1, h = blockIdx.x & 1;

  for (int i = tid; i < 48 * 64; i += 512)
    ((uint4*)wlds)[i] = ((const uint4*)wfrag)[i];
  if (tid < 64) lwL[tid] = ((const u32*)(wfrag + LW_OFF))[tid];
  if (tid < 128) ((float*)labW)[tid] = labW_g[tid];

  const float lb0 = llr_b[0], lb1 = llr_b[1];
  const float2 cb1 = *(const float2*)(cn_b1 + 2 * m31);
  const float2 cb2 = *(const float2*)(cn_b2 + 2 * m31);
  const float2 bb2 = *(const float2*)(bn_b2 + 2 * m31);

  // ---------------- stage 0: one row per thread ----------------
  {
    int nl = tid;
    int n = 512 * h + nl;
    float2 yv = *(const float2*)(y + ((size_t)b * NN + n) * 2);
    float z0 = lb0, z1 = lb1, nr = 0.f;
    #pragma unroll
    for (int o8 = 0; o8 < 8; ++o8) {
      u32 vals[4];
      #pragma unroll
      for (int jj = 0; jj < 4; ++jj) {
        int o = o8 * 8 + jj * 2;
        float e0 = fmaf(yv.x, emb_W[o],     fmaf(yv.y, emb_W[64 + o],     emb_b[o]));
        float e1 = fmaf(yv.x, emb_W[o + 1], fmaf(yv.y, emb_W[64 + o + 1], emb_b[o + 1]));
        vals[jj] = pack_bf2(e0, e1);
        z0 = fmaf(e0, llr_W[o * 2 + 0], z0); z1 = fmaf(e0, llr_W[o * 2 + 1], z1);
        nr = fmaf(e0, e0, nr);
        z0 = fmaf(e1, llr_W[o * 2 + 2], z0); z1 = fmaf(e1, llr_W[o * 2 + 3], z1);
        nr = fmaf(e1, e1, nr);
      }
      uint4 q; q.x = vals[0]; q.y = vals[1]; q.z = vals[2]; q.w = vals[3];
      *(uint4*)(eLh + eaddr(nl, o8)) = q;
    }
    int v = x[(size_t)b * NN + n] & 1;
    emit_out<true>(out, pred_ws, b, n, 0, z0, z1, nr, v);
    u64 bm = __ballot(v != 0);
    if (ln == 0)  vmask[0][2 * w]     = (u32)bm;
    if (ln == 32) vmask[0][2 * w + 1] = (u32)(bm >> 32);
  }
  __syncthreads();

  const float2 lwv0 = *(const float2*)(&labW[0][2 * m31]);
  const float2 lwv1 = *(const float2*)(&labW[1][2 * m31]);

  // ---------------- stages 1..9 (pairs stay in this half) ----------------
  #pragma unroll 1
  for (int s = 1; s <= 9; ++s) {
    const int sh = s - 1;
    const int half = 1 << sh;
    const u32* vmR = vmask[(s - 1) & 1];
    u32* vmW = vmask[s & 1];

    short8 Ao[4], Ae[4];
    int iog, ieg, iol, iel, vo, ve, vx;
    u32 bxs;
    {
      int i = 256 * h + 32 * w + m31;              // global pair index
      int g = i >> sh, u = i & (half - 1);
      iog = g * (half << 1) + u;
      ieg = iog + half;
      iol = iog & 511; iel = ieg & 511;            // local rows
      #pragma unroll
      for (int f = 0; f < 4; ++f) {
        Ao[f] = *(const short8*)(eLh + eaddr(iol, f * 2 + h8));
        Ae[f] = *(const short8*)(eLh + eaddr(iel, f * 2 + h8));
      }
      vo = (vmR[iol >> 5] >> (iol & 31)) & 1;
      ve = (vmR[iel >> 5] >> (iel & 31)) & 1;
      vx = vo ^ ve;
      u32 bx = (u32)__ballot(vx != 0);
      u32 be = (u32)__ballot(ve != 0);
      bxs = bx;
      u32 lo = spread16(bx & 0xffffu) | (spread16(be & 0xffffu) << 1);
      u32 hi = spread16(bx >> 16) | (spread16(be >> 16) << 1);
      if (ln == 0) { vmW[2 * w] = lo; vmW[2 * w + 1] = hi; }
    }
    __syncthreads();

    // epilogue for stage s-1 (s>=2), using A-frags in regs
    if (s >= 2) {
      const uint4* lwq = (const uint4*)lwL;
      uint4 lq[4][2];
      #pragma unroll
      for (int f = 0; f < 4; ++f) {
        lq[f][0] = lwq[f * 4 + h8 * 2];
        lq[f][1] = lwq[f * 4 + h8 * 2 + 1];
      }
      #pragma unroll
      for (int side = 0; side < 2; ++side) {
        float z0 = 0.f, z1 = 0.f, nr = 0.f;
        #pragma unroll
        for (int f = 0; f < 4; ++f) {
          short8 av8 = side ? Ae[f] : Ao[f];
          #pragma unroll
          for (int j = 0; j < 8; ++j) {
            u32 pv = ((const u32*)&av8)[j >> 1];
            float val = __uint_as_float((j & 1) ? (pv & 0xffff0000u) : (pv << 16));
            u32 lwp = (j < 4) ? ((const u32*)&lq[f][0])[j] : ((const u32*)&lq[f][1])[j - 4];
            z0 = fmaf(val, __uint_as_float(lwp << 16), z0);
            z1 = fmaf(val, __uint_as_float(lwp & 0xffff0000u), z1);
            nr = fmaf(val, val, nr);
          }
        }
        z0 += __shfl_xor(z0, 32);
        z1 += __shfl_xor(z1, 32);
        nr += __shfl_xor(nr, 32);
        if (h8 == 0)
          emit_out<true>(out, pred_ws, b, side ? ieg : iog, s - 1,
                         z0 + lb0, z1 + lb1, nr, side ? ve : vo);
      }
    }

    // ---- layer-1 cn (K=128) ----
    f32x16 a0, a1;
    #pragma unroll
    for (int r = 0; r < 16; ++r) { a0[r] = cb1.x; a1[r] = cb1.y; }
    #pragma unroll
    for (int ks = 0; ks < 8; ++ks) {
      short8 B0 = AFR(ks * 2 + 0);
      short8 B1 = AFR(ks * 2 + 1);
      short8 a = (ks < 4) ? Ao[ks] : Ae[ks - 4];
      a0 = __builtin_amdgcn_mfma_f32_32x32x16_bf16(a, B0, a0, 0, 0, 0);
      a1 = __builtin_amdgcn_mfma_f32_32x32x16_bf16(a, B1, a1, 0, 0, 0);
    }
    {
      int obase = 64 * w;
      #pragma unroll
      for (int r = 0; r < 16; ++r) {
        int row = (r & 3) + 8 * (r >> 2) + 4 * h8;
        int R = obase + 2 * row;
        *(u32*)(eLh + eaddr32(R, m31)) =
            pack_bf2(fmaxf(a0[r], 0.f), fmaxf(a1[r], 0.f));
      }
    }

    // ---- layer-1 bn (K=128 + fused labW bias) ----
    #pragma unroll
    for (int r = 0; r < 16; ++r) {
      int row = (r & 3) + 8 * (r >> 2) + 4 * h8;
      int bit = (bxs >> row) & 1;
      a0[r] = bit ? lwv1.x : lwv0.x;
      a1[r] = bit ? lwv1.y : lwv0.y;
    }
    #pragma unroll
    for (int ks = 0; ks < 8; ++ks) {
      short8 B0 = AFR(16 + ks * 2 + 0);
      short8 B1 = AFR(16 + ks * 2 + 1);
      short8 a = (ks < 4) ? Ao[ks] : Ae[ks - 4];
      a0 = __builtin_amdgcn_mfma_f32_32x32x16_bf16(a, B0, a0, 0, 0, 0);
      a1 = __builtin_amdgcn_mfma_f32_32x32x16_bf16(a, B1, a1, 0, 0, 0);
    }
    {
      int obase = 64 * w;
      #pragma unroll
      for (int r = 0; r < 16; ++r) {
        int row = (r & 3) + 8 * (r >> 2) + 4 * h8;
        int R = obase + 2 * row + 1;
        *(u32*)(eLh + eaddr32(R, m31)) =
            pack_bf2(fmaxf(a0[r], 0.f), fmaxf(a1[r], 0.f));
      }
    }

    // ---- layer-2 cn ----
    {
      short8 Hc[4];
      {
        int R = 64 * w + 2 * m31;
        #pragma unroll
        for (int f = 0; f < 4; ++f)
          Hc[f] = *(const short8*)(eLh + eaddr(R, f * 2 + h8));
      }
      f32x16 d0, d1;
      #pragma unroll
      for (int r = 0; r < 16; ++r) { d0[r] = cb2.x; d1[r] = cb2.y; }
      #pragma unroll
      for (int ks = 0; ks < 4; ++ks) {
        short8 B0 = AFR(32 + ks * 2 + 0);
        short8 B1 = AFR(32 + ks * 2 + 1);
        d0 = __builtin_amdgcn_mfma_f32_32x32x16_bf16(Hc[ks], B0, d0, 0, 0, 0);
        d1 = __builtin_amdgcn_mfma_f32_32x32x16_bf16(Hc[ks], B1, d1, 0, 0, 0);
      }
      int obase = 64 * w;
      #pragma unroll
      for (int r = 0; r < 16; ++r) {
        int row = (r & 3) + 8 * (r >> 2) + 4 * h8;
        int R = obase + 2 * row;
        *(u32*)(eLh + eaddr32(R, m31)) = pack_bf2(d0[r], d1[r]);
      }
    }

    // ---- layer-2 bn ----
    {
      short8 Hb[4];
      {
        int R = 64 * w + 2 * m31 + 1;
        #pragma unroll
        for (int f = 0; f < 4; ++f)
          Hb[f] = *(const short8*)(eLh + eaddr(R, f * 2 + h8));
      }
      f32x16 d0, d1;
      #pragma unroll
      for (int r = 0; r < 16; ++r) { d0[r] = bb2.x; d1[r] = bb2.y; }
      #pragma unroll
      for (int ks = 0; ks < 4; ++ks) {
        short8 B0 = AFR(40 + ks * 2 + 0);
        short8 B1 = AFR(40 + ks * 2 + 1);
        d0 = __builtin_amdgcn_mfma_f32_32x32x16_bf16(Hb[ks], B0, d0, 0, 0, 0);
        d1 = __builtin_amdgcn_mfma_f32_32x32x16_bf16(Hb[ks], B1, d1, 0, 0, 0);
      }
      int obase = 64 * w;
      #pragma unroll
      for (int r = 0; r < 16; ++r) {
        int row = (r & 3) + 8 * (r >> 2) + 4 * h8;
        int R = obase + 2 * row + 1;
        *(u32*)(eLh + eaddr32(R, m31)) = pack_bf2(d0[r], d1[r]);
      }
    }
    __syncthreads();
  }

  // ---------------- dump e9 half + stage-9 vmask ----------------
  {
    const uint4* src = (const uint4*)eLh;
    uint4* dst = (uint4*)(e9_ws + (size_t)(b * 2 + h) * 32768);
    for (int i = tid; i < 4096; i += 512) dst[i] = src[i];
    if (tid < 16) vm_ws[(b * 2 + h) * 16 + tid] = vmask[1][tid];  // 9&1 == 1
  }
}

// ===================== Kernel B: stage 10 + epilogues 9,10 =================
// grid 256 (b), 8 waves x 2 tiles (R6 proven shape). Reads e9 pairs (i, i+512)
// from workspace; computes stage 10 into full eL; final epilogue.
__global__ __launch_bounds__(512, 2) void polar_b_kernel(
    const u16* __restrict__ wfrag, const float* __restrict__ labW_g,
    const float* __restrict__ cn_b1, const float* __restrict__ cn_b2,
    const float* __restrict__ bn_b2, const float* __restrict__ llr_b,
    float* __restrict__ pred_ws, const u16* __restrict__ e9_ws,
    const u32* __restrict__ vm_ws, float* __restrict__ out) {
  __shared__ __align__(16) u16 eL[NN * 64];            // 131072 B
  __shared__ __align__(16) u16 wlds[WLDS_FR * 512];    // 30720 B
  __shared__ u32 lwL[64];                              // 256 B
  __shared__ u32 vmA[32];                              // stage-9 labels
  __shared__ u32 vmB[32];                              // stage-10 labels
  __shared__ float labW[2][64];                        // 512 B

  const int tid = threadIdx.x;
  const int w = tid >> 6, ln = tid & 63;
  const int m31 = ln & 31, h8 = ln >> 5;
  const int b = blockIdx.x;

  for (int i = tid; i < WLDS_FR * 64; i += 512)
    ((uint4*)wlds)[i] = ((const uint4*)wfrag)[i];
  if (tid < 64) lwL[tid] = ((const u32*)(wfrag + LW_OFF))[tid];
  if (tid < 128) ((float*)labW)[tid] = labW_g[tid];
  if (tid < 32) vmA[tid] = vm_ws[b * 32 + tid];        // h=0 words 0..15, h=1 16..31

  const float lb0 = llr_b[0], lb1 = llr_b[1];
  const float2 cb1 = *(const float2*)(cn_b1 + 2 * m31);
  const float2 cb2 = *(const float2*)(cn_b2 + 2 * m31);
  const float2 bb2 = *(const float2*)(bn_b2 + 2 * m31);
  __syncthreads();                                     // preamble LDS visible

  const float2 lwv0 = *(const float2*)(&labW[0][2 * m31]);
  const float2 lwv1 = *(const float2*)(&labW[1][2 * m31]);

  const u16* e9a = e9_ws + (size_t)(b * 2 + 0) * 32768;
  const u16* e9b = e9_ws + (size_t)(b * 2 + 1) * 32768;

  // ---- A-read phase: pairs (i, i+512) from the two halves ----
  short8 Ao[2][4], Ae[2][4];
  int io[2], ie[2], vo[2], ve[2], vx[2];
  u32 bxs[2];
  #pragma unroll
  for (int t = 0; t < 2; ++t) {
    int i = 64 * w + 32 * t + m31;                     // pair index [0,512)
    io[t] = i; ie[t] = i + 512;
    #pragma unroll
    for (int f = 0; f < 4; ++f) {
      Ao[t][f] = *(const short8*)(e9a + eaddr(i, f * 2 + h8));
      Ae[t][f] = *(const short8*)(e9b + eaddr(i, f * 2 + h8));  // local row = i
    }
    vo[t] = (vmA[i >> 5] >> (i & 31)) & 1;
    ve[t] = (vmA[(i >> 5) + 16] >> (i & 31)) & 1;
    vx[t] = vo[t] ^ ve[t];
    u32 bx = (u32)__ballot(vx[t] != 0);
    u32 be = (u32)__ballot(ve[t] != 0);
    bxs[t] = bx;
    u32 lo = spread16(bx & 0xffffu) | (spread16(be & 0xffffu) << 1);
    u32 hi = spread16(bx >> 16) | (spread16(be >> 16) << 1);
    if (ln == 0) { vmB[4 * w + 2 * t] = lo; vmB[4 * w + 2 * t + 1] = hi; }
  }
  __syncthreads();

  // ---- epilogue for stage 9 (A-frags in regs) ----
  {
    const uint4* lwq = (const uint4*)lwL;
    uint4 lq[4][2];
    #pragma unroll
    for (int f = 0; f < 4; ++f) {
      lq[f][0] = lwq[f * 4 + h8 * 2];
      lq[f][1] = lwq[f * 4 + h8 * 2 + 1];
    }
    #pragma unroll
    for (int t = 0; t < 2; ++t) {
      #pragma unroll
      for (int side = 0; side < 2; ++side) {
        float z0 = 0.f, z1 = 0.f, nr = 0.f;
        #pragma unroll
        for (int f = 0; f < 4; ++f) {
          short8 av8 = side ? Ae[t][f] : Ao[t][f];
          #pragma unroll
          for (int j = 0; j < 8; ++j) {
            u32 pv = ((const u32*)&av8)[j >> 1];
            float val = __uint_as_float((j & 1) ? (pv & 0xffff0000u) : (pv << 16));
            u32 lwp = (j < 4) ? ((const u32*)&lq[f][0])[j] : ((const u32*)&lq[f][1])[j - 4];
            z0 = fmaf(val, __uint_as_float(lwp << 16), z0);
            z1 = fmaf(val, __uint_as_float(lwp & 0xffff0000u), z1);
            nr = fmaf(val, val, nr);
          }
        }
        z0 += __shfl_xor(z0, 32);
        z1 += __shfl_xor(z1, 32);
        nr += __shfl_xor(nr, 32);
        if (h8 == 0)
          emit_out<true>(out, pred_ws, b, side ? ie[t] : io[t], 9,
                         z0 + lb0, z1 + lb1, nr, side ? ve[t] : vo[t]);
      }
    }
  }

  // ---- layer-1 cn ----
  f32x16 a0[2], a1[2];
  #pragma unroll
  for (int t = 0; t < 2; ++t)
    #pragma unroll
    for (int r = 0; r < 16; ++r) { a0[t][r] = cb1.x; a1[t][r] = cb1.y; }
  #pragma unroll
  for (int ks = 0; ks < 8; ++ks) {
    short8 B0 = BFR(ks * 2 + 0);
    short8 B1 = BFR(ks * 2 + 1);
    #pragma unroll
    for (int t = 0; t < 2; ++t) {
      short8 a = (ks < 4) ? Ao[t][ks] : Ae[t][ks - 4];
      a0[t] = __builtin_amdgcn_mfma_f32_32x32x16_bf16(a, B0, a0[t], 0, 0, 0);
      a1[t] = __builtin_amdgcn_mfma_f32_32x32x16_bf16(a, B1, a1[t], 0, 0, 0);
    }
  }
  #pragma unroll
  for (int t = 0; t < 2; ++t) {
    int obase = 128 * w + 64 * t;
    #pragma unroll
    for (int r = 0; r < 16; ++r) {
      int row = (r & 3) + 8 * (r >> 2) + 4 * h8;
      int R = obase + 2 * row;
      *(u32*)(eL + eaddr32(R, m31)) =
          pack_bf2(fmaxf(a0[t][r], 0.f), fmaxf(a1[t][r], 0.f));
    }
  }

  // ---- layer-1 bn ----
  #pragma unroll
  for (int t = 0; t < 2; ++t)
    #pragma unroll
    for (int r = 0; r < 16; ++r) {
      int row = (r & 3) + 8 * (r >> 2) + 4 * h8;
      int bit = (bxs[t] >> row) & 1;
      a0[t][r] = bit ? lwv1.x : lwv0.x;
      a1[t][r] = bit ? lwv1.y : lwv0.y;
    }
  #pragma unroll
  for (int ks = 0; ks < 8; ++ks) {
    short8 B0 = BFR(16 + ks * 2 + 0);
    short8 B1 = BFR(16 + ks * 2 + 1);
    #pragma unroll
    for (int t = 0; t < 2; ++t) {
      short8 a = (ks < 4) ? Ao[t][ks] : Ae[t][ks - 4];
      a0[t] = __builtin_amdgcn_mfma_f32_32x32x16_bf16(a, B0, a0[t], 0, 0, 0);
      a1[t] = __builtin_amdgcn_mfma_f32_32x32x16_bf16(a, B1, a1[t], 0, 0, 0);
    }
  }
  #pragma unroll
  for (int t = 0; t < 2; ++t) {
    int obase = 128 * w + 64 * t;
    #pragma unroll
    for (int r = 0; r < 16; ++r) {
      int row = (r & 3) + 8 * (r >> 2) + 4 * h8;
      int R = obase + 2 * row + 1;
      *(u32*)(eL + eaddr32(R, m31)) =
          pack_bf2(fmaxf(a0[t][r], 0.f), fmaxf(a1[t][r], 0.f));
    }
  }

  // ---- layer-2 cn ----
  {
    short8 Hc[2][4];
    #pragma unroll
    for (int t = 0; t < 2; ++t) {
      int R = 128 * w + 64 * t + 2 * m31;
      #pragma unroll
      for (int f = 0; f < 4; ++f)
        Hc[t][f] = *(const short8*)(eL + eaddr(R, f * 2 + h8));
    }
    f32x16 d0[2], d1[2];
    #pragma unroll
    for (int t = 0; t < 2; ++t)
      #pragma unroll
      for (int r = 0; r < 16; ++r) { d0[t][r] = cb2.x; d1[t][r] = cb2.y; }
    #pragma unroll
    for (int ks = 0; ks < 4; ++ks) {
      short8 B0 = BFR(32 + ks * 2 + 0);
      short8 B1 = BFR(32 + ks * 2 + 1);
      #pragma unroll
      for (int t = 0; t < 2; ++t) {
        d0[t] = __builtin_amdgcn_mfma_f32_32x32x16_bf16(Hc[t][ks], B0, d0[t], 0, 0, 0);
        d1[t] = __builtin_amdgcn_mfma_f32_32x32x16_bf16(Hc[t][ks], B1, d1[t], 0, 0, 0);
      }
    }
    #pragma unroll
    for (int t = 0; t < 2; ++t) {
      int obase = 128 * w + 64 * t;
      #pragma unroll
      for (int r = 0; r < 16; ++r) {
        int row = (r & 3) + 8 * (r >> 2) + 4 * h8;
        int R = obase + 2 * row;
        *(u32*)(eL + eaddr32(R, m31)) = pack_bf2(d0[t][r], d1[t][r]);
      }
    }
  }

  // ---- layer-2 bn ----
  {
    short8 Hb[2][4];
    #pragma unroll
    for (int t = 0; t < 2; ++t) {
      int R = 128 * w + 64 * t + 2 * m31 + 1;
      #pragma unroll
      for (int f = 0; f < 4; ++f)
        Hb[t][f] = *(const short8*)(eL + eaddr(R, f * 2 + h8));
    }
    f32x16 d0[2], d1[2];
    #pragma unroll
    for (int t = 0; t < 2; ++t)
      #pragma unroll
      for (int r = 0; r < 16; ++r) { d0[t][r] = bb2.x; d1[t][r] = bb2.y; }
    #pragma unroll
    for (int ks = 0; ks < 4; ++ks) {
      short8 B0 = BFR(40 + ks * 2 + 0);
      short8 B1 = BFR(40 + ks * 2 + 1);
      #pragma unroll
      for (int t = 0; t < 2; ++t) {
        d0[t] = __builtin_amdgcn_mfma_f32_32x32x16_bf16(Hb[t][ks], B0, d0[t], 0, 0, 0);
        d1[t] = __builtin_amdgcn_mfma_f32_32x32x16_bf16(Hb[t][ks], B1, d1[t], 0, 0, 0);
      }
    }
    #pragma unroll
    for (int t = 0; t < 2; ++t) {
      int obase = 128 * w + 64 * t;
      #pragma unroll
      for (int r = 0; r < 16; ++r) {
        int row = (r & 3) + 8 * (r >> 2) + 4 * h8;
        int R = obase + 2 * row + 1;
        *(u32*)(eL + eaddr32(R, m31)) = pack_bf2(d0[t][r], d1[t][r]);
      }
    }
  }
  __syncthreads();

  // ---- final epilogue (stage 10) ----
  {
    const uint4* lwq = (const uint4*)lwL;
    uint4 lq[4][2];
    #pragma unroll
    for (int f = 0; f < 4; ++f) {
      lq[f][0] = lwq[f * 4 + h8 * 2];
      lq[f][1] = lwq[f * 4 + h8 * 2 + 1];
    }
    #pragma unroll
    for (int it = 0; it < 4; ++it) {
      int n = 128 * w + 32 * it + m31;
      float z0 = 0.f, z1 = 0.f, nr = 0.f;
      #pragma unroll
      for (int f = 0; f < 4; ++f) {
        short8 av8 = *(const short8*)(eL + eaddr(n, f * 2 + h8));
        #pragma unroll
        for (int j = 0; j < 8; ++j) {
          u32 pv = ((const u32*)&av8)[j >> 1];
          float val = __uint_as_float((j & 1) ? (pv & 0xffff0000u) : (pv << 16));
          u32 lwp = (j < 4) ? ((const u32*)&lq[f][0])[j] : ((const u32*)&lq[f][1])[j - 4];
          z0 = fmaf(val, __uint_as_float(lwp << 16), z0);
          z1 = fmaf(val, __uint_as_float(lwp & 0xffff0000u), z1);
          nr = fmaf(val, val, nr);
        }
      }
      z0 += __shfl_xor(z0, 32);
      z1 += __shfl_xor(z1, 32);
      nr += __shfl_xor(nr, 32);
      int lab = (vmB[n >> 5] >> (n & 31)) & 1;
      if (h8 == 0)
        emit_out<true>(out, pred_ws, b, n, NSTAGES - 1, z0 + lb0, z1 + lb1, nr, lab);
    }
  }
}

// ===================== Mono fallback (R6, best single-kernel) ==============
template <int STAGED>
__global__ __launch_bounds__(512, 2) void polar_mono_kernel(
    const int* __restrict__ x, const float* __restrict__ y,
    const float* __restrict__ emb_W, const float* __restrict__ emb_b,
    const u16* __restrict__ wfrag, const float* __restrict__ labW_g,
    const float* __restrict__ cn_b1, const float* __restrict__ cn_b2,
    const float* __restrict__ bn_b2, const float* __restrict__ llr_W,
    const float* __restrict__ llr_b, float* __restrict__ pred_ws,
    float* __restrict__ out) {
  __shared__ __align__(16) u16 eL[NN * 64];
  __shared__ __align__(16) u16 wlds[WLDS_FR * 512];
  __shared__ u32 lwL[64];
  __shared__ u32 vmask[2][32];
  __shared__ float labW[2][64];

  const int tid = threadIdx.x;
  const int w = tid >> 6, ln = tid & 63;
  const int m31 = ln & 31, h8 = ln >> 5;
  const int b = blockIdx.x;

  for (int i = tid; i < WLDS_FR * 64; i += 512)
    ((uint4*)wlds)[i] = ((const uint4*)wfrag)[i];
  if (tid < 64) lwL[tid] = ((const u32*)(wfrag + LW_OFF))[tid];
  if (tid < 128) ((float*)labW)[tid] = labW_g[tid];

  const float lb0 = llr_b[0], lb1 = llr_b[1];
  const float2 cb1 = *(const float2*)(cn_b1 + 2 * m31);
  const float2 cb2 = *(const float2*)(cn_b2 + 2 * m31);
  const float2 bb2 = *(const float2*)(bn_b2 + 2 * m31);

  #pragma unroll
  for (int rep = 0; rep < 2; ++rep) {
    int n = rep * 512 + tid;
    float2 yv = *(const float2*)(y + ((size_t)b * NN + n) * 2);
    float z0 = lb0, z1 = lb1, nr = 0.f;
    #pragma unroll
    for (int o8 = 0; o8 < 8; ++o8) {
      u32 vals[4];
      #pragma unroll
      for (int jj = 0; jj < 4; ++jj) {
        int o = o8 * 8 + jj * 2;
        float e0 = fmaf(yv.x, emb_W[o],     fmaf(yv.y, emb_W[64 + o],     emb_b[o]));
        float e1 = fmaf(yv.x, emb_W[o + 1], fmaf(yv.y, emb_W[64 + o + 1], emb_b[o + 1]));
        vals[jj] = pack_bf2(e0, e1);
        z0 = fmaf(e0, llr_W[o * 2 + 0], z0); z1 = fmaf(e0, llr_W[o * 2 + 1], z1);
        nr = fmaf(e0, e0, nr);
        z0 = fmaf(e1, llr_W[o * 2 + 2], z0); z1 = fmaf(e1, llr_W[o * 2 + 3], z1);
        nr = fmaf(e1, e1, nr);
      }
      uint4 q; q.x = vals[0]; q.y = vals[1]; q.z = vals[2]; q.w = vals[3];
      *(uint4*)(eL + eaddr(n, o8)) = q;
    }
    int v = x[(size_t)b * NN + n] & 1;
    emit_out<STAGED != 0>(out, pred_ws, b, n, 0, z0, z1, nr, v);
    u64 bm = __ballot(v != 0);
    if (ln == 0)  vmask[0][rep * 16 + 2 * w]     = (u32)bm;
    if (ln == 32) vmask[0][rep * 16 + 2 * w + 1] = (u32)(bm >> 32);
  }
  __syncthreads();

  const float2 lwv0 = *(const float2*)(&labW[0][2 * m31]);
  const float2 lwv1 = *(const float2*)(&labW[1][2 * m31]);

  #pragma unroll 1
  for (int s = 1; s <= 10; ++s) {
    const int sh = s - 1;
    const int half = 1 << sh;
    const u32* vmR = vmask[(s - 1) & 1];
    u32* vmW = vmask[s & 1];

    short8 Ao[2][4], Ae[2][4];
    int io[2], ie[2], vo[2], ve[2], vx[2];
    u32 bxs[2];
    #pragma unroll
    for (int t = 0; t < 2; ++t) {
      int i = 64 * w + 32 * t + m31;
      int g = i >> sh, u = i & (half - 1);
      io[t] = g * (half << 1) + u;
      ie[t] = io[t] + half;
      #pragma unroll
      for (int f = 0; f < 4; ++f) {
        Ao[t][f] = *(const short8*)(eL + eaddr(io[t], f * 2 + h8));
        Ae[t][f] = *(const short8*)(eL + eaddr(ie[t], f * 2 + h8));
      }
      vo[t] = (vmR[io[t] >> 5] >> (io[t] & 31)) & 1;
      ve[t] = (vmR[ie[t] >> 5] >> (ie[t] & 31)) & 1;
      vx[t] = vo[t] ^ ve[t];
      u32 bx = (u32)__ballot(vx[t] != 0);
      u32 be = (u32)__ballot(ve[t] != 0);
      bxs[t] = bx;
      u32 lo = spread16(bx & 0xffffu) | (spread16(be & 0xffffu) << 1);
      u32 hi = spread16(bx >> 16) | (spread16(be >> 16) << 1);
      if (ln == 0) { vmW[4 * w + 2 * t] = lo; vmW[4 * w + 2 * t + 1] = hi; }
    }
    __syncthreads();

    if (s >= 2) {
      const uint4* lwq = (const uint4*)lwL;
      uint4 lq[4][2];
      #pragma unroll
      for (int f = 0; f < 4; ++f) {
        lq[f][0] = lwq[f * 4 + h8 * 2];
        lq[f][1] = lwq[f * 4 + h8 * 2 + 1];
      }
      #pragma unroll
      for (int t = 0; t < 2; ++t) {
        #pragma unroll
        for (int side = 0; side < 2; ++side) {
          float z0 = 0.f, z1 = 0.f, nr = 0.f;
          #pragma unroll
          for (int f = 0; f < 4; ++f) {
            short8 av8 = side ? Ae[t][f] : Ao[t][f];
            #pragma unroll
            for (int j = 0; j < 8; ++j) {
              u32 pv = ((const u32*)&av8)[j >> 1];
              float val = __uint_as_float((j & 1) ? (pv & 0xffff0000u) : (pv << 16));
              u32 lwp = (j < 4) ? ((const u32*)&lq[f][0])[j] : ((const u32*)&lq[f][1])[j - 4];
              z0 = fmaf(val, __uint_as_float(lwp << 16), z0);
              z1 = fmaf(val, __uint_as_float(lwp & 0xffff0000u), z1);
              nr = fmaf(val, val, nr);
            }
          }
          z0 += __shfl_xor(z0, 32);
          z1 += __shfl_xor(z1, 32);
          nr += __shfl_xor(nr, 32);
          if (h8 == 0)
            emit_out<STAGED != 0>(out, pred_ws, b, side ? ie[t] : io[t], s - 1,
                                  z0 + lb0, z1 + lb1, nr, side ? ve[t] : vo[t]);
        }
      }
    }

    f32x16 a0[2], a1[2];
    #pragma unroll
    for (int t = 0; t < 2; ++t)
      #pragma unroll
      for (int r = 0; r < 16; ++r) { a0[t][r] = cb1.x; a1[t][r] = cb1.y; }
    #pragma unroll
    for (int ks = 0; ks < 8; ++ks) {
      short8 B0 = BFR(ks * 2 + 0);
      short8 B1 = BFR(ks * 2 + 1);
      #pragma unroll
      for (int t = 0; t < 2; ++t) {
        short8 a = (ks < 4) ? Ao[t][ks] : Ae[t][ks - 4];
        a0[t] = __builtin_amdgcn_mfma_f32_32x32x16_bf16(a, B0, a0[t], 0, 0, 0);
        a1[t] = __builtin_amdgcn_mfma_f32_32x32x16_bf16(a, B1, a1[t], 0, 0, 0);
      }
    }
    #pragma unroll
    for (int t = 0; t < 2; ++t) {
      int obase = 128 * w + 64 * t;
      #pragma unroll
      for (int r = 0; r < 16; ++r) {
        int row = (r & 3) + 8 * (r >> 2) + 4 * h8;
        int R = obase + 2 * row;
        *(u32*)(eL + eaddr32(R, m31)) =
            pack_bf2(fmaxf(a0[t][r], 0.f), fmaxf(a1[t][r], 0.f));
      }
    }

    #pragma unroll
    for (int t = 0; t < 2; ++t)
      #pragma unroll
      for (int r = 0; r < 16; ++r) {
        int row = (r & 3) + 8 * (r >> 2) + 4 * h8;
        int bit = (bxs[t] >> row) & 1;
        a0[t][r] = bit ? lwv1.x : lwv0.x;
        a1[t][r] = bit ? lwv1.y : lwv0.y;
      }
    #pragma unroll
    for (int ks = 0; ks < 8; ++ks) {
      short8 B0 = BFR(16 + ks * 2 + 0);
      short8 B1 = BFR(16 + ks * 2 + 1);
      #pragma unroll
      for (int t = 0; t < 2; ++t) {
        short8 a = (ks < 4) ? Ao[t][ks] : Ae[t][ks - 4];
        a0[t] = __builtin_amdgcn_mfma_f32_32x32x16_bf16(a, B0, a0[t], 0, 0, 0);
        a1[t] = __builtin_amdgcn_mfma_f32_32x32x16_bf16(a, B1, a1[t], 0, 0, 0);
      }
    }
    #pragma unroll
    for (int t = 0; t < 2; ++t) {
      int obase = 128 * w + 64 * t;
      #pragma unroll
      for (int r = 0; r < 16; ++r) {
        int row = (r & 3) + 8 * (r >> 2) + 4 * h8;
        int R = obase + 2 * row + 1;
        *(u32*)(eL + eaddr32(R, m31)) =
            pack_bf2(fmaxf(a0[t][r], 0.f), fmaxf(a1[t][r], 0.f));
      }
    }

    {
      short8 Hc[2][4];
      #pragma unroll
      for (int t = 0; t < 2; ++t) {
        int R = 128 * w + 64 * t + 2 * m31;
        #pragma unroll
        for (int f = 0; f < 4; ++f)
          Hc[t][f] = *(const short8*)(eL + eaddr(R, f * 2 + h8));
      }
      f32x16 d0[2], d1[2];
      #pragma unroll
      for (int t = 0; t < 2; ++t)
        #pragma unroll
        for (int r = 0; r < 16; ++r) { d0[t][r] = cb2.x; d1[t][r] = cb2.y; }
      #pragma unroll
      for (int ks = 0; ks < 4; ++ks) {
        short8 B0 = BFR(32 + ks * 2 + 0);
        short8 B1 = BFR(32 + ks * 2 + 1);
        #pragma unroll
        for (int t = 0; t < 2; ++t) {
          d0[t] = __builtin_amdgcn_mfma_f32_32x32x16_bf16(Hc[t][ks], B0, d0[t], 0, 0, 0);
          d1[t] = __builtin_amdgcn_mfma_f32_32x32x16_bf16(Hc[t][ks], B1, d1[t], 0, 0, 0);
        }
      }
      #pragma unroll
      for (int t = 0; t < 2; ++t) {
        int obase = 128 * w + 64 * t;
        #pragma unroll
        for (int r = 0; r < 16; ++r) {
          int row = (r & 3) + 8 * (r >> 2) + 4 * h8;
          int R = obase + 2 * row;
          *(u32*)(eL + eaddr32(R, m31)) = pack_bf2(d0[t][r], d1[t][r]);
        }
      }
    }

    {
      short8 Hb[2][4];
      #pragma unroll
      for (int t = 0; t < 2; ++t) {
        int R = 128 * w + 64 * t + 2 * m31 + 1;
        #pragma unroll
        for (int f = 0; f < 4; ++f)
          Hb[t][f] = *(const short8*)(eL + eaddr(R, f * 2 + h8));
      }
      f32x16 d0[2], d1[2];
      #pragma unroll
      for (int t = 0; t < 2; ++t)
        #pragma unroll
        for (int r = 0; r < 16; ++r) { d0[t][r] = bb2.x; d1[t][r] = bb2.y; }
      #pragma unroll
      for (int ks = 0; ks < 4; ++ks) {
        short8 B0 = BFR(40 + ks * 2 + 0);
        short8 B1 = BFR(40 + ks * 2 + 1);
        #pragma unroll
        for (int t = 0; t < 2; ++t) {
          d0[t] = __builtin_amdgcn_mfma_f32_32x32x16_bf16(Hb[t][ks], B0, d0[t], 0, 0, 0);
          d1[t] = __builtin_amdgcn_mfma_f32_32x32x16_bf16(Hb[t][ks], B1, d1[t], 0, 0, 0);
        }
      }
      #pragma unroll
      for (int t = 0; t < 2; ++t) {
        int obase = 128 * w + 64 * t;
        #pragma unroll
        for (int r = 0; r < 16; ++r) {
          int row = (r & 3) + 8 * (r >> 2) + 4 * h8;
          int R = obase + 2 * row + 1;
          *(u32*)(eL + eaddr32(R, m31)) = pack_bf2(d0[t][r], d1[t][r]);
        }
      }
    }
    __syncthreads();
  }

  {
    const uint4* lwq = (const uint4*)lwL;
    uint4 lq[4][2];
    #pragma unroll
    for (int f = 0; f < 4; ++f) {
      lq[f][0] = lwq[f * 4 + h8 * 2];
      lq[f][1] = lwq[f * 4 + h8 * 2 + 1];
    }
    #pragma unroll
    for (int it = 0; it < 4; ++it) {
      int n = 128 * w + 32 * it + m31;
      float z0 = 0.f, z1 = 0.f, nr = 0.f;
      #pragma unroll
      for (int f = 0; f < 4; ++f) {
        short8 av8 = *(const short8*)(eL + eaddr(n, f * 2 + h8));
        #pragma unroll
        for (int j = 0; j < 8; ++j) {
          u32 pv = ((const u32*)&av8)[j >> 1];
          float val = __uint_as_float((j & 1) ? (pv & 0xffff0000u) : (pv << 16));
          u32 lwp = (j < 4) ? ((const u32*)&lq[f][0])[j] : ((const u32*)&lq[f][1])[j - 4];
          z0 = fmaf(val, __uint_as_float(lwp << 16), z0);
          z1 = fmaf(val, __uint_as_float(lwp & 0xffff0000u), z1);
          nr = fmaf(val, val, nr);
        }
      }
      z0 += __shfl_xor(z0, 32);
      z1 += __shfl_xor(z1, 32);
      nr += __shfl_xor(nr, 32);
      int lab = (vmask[0][n >> 5] >> (n & 31)) & 1;
      if (h8 == 0)
        emit_out<STAGED != 0>(out, pred_ws, b, n, NSTAGES - 1, z0 + lb0, z1 + lb1, nr, lab);
    }
  }
}

extern "C" void kernel_launch(void* const* d_in, const int* in_sizes, int n_in,
                              void* d_out, int out_size, void* d_ws, size_t ws_size,
                              hipStream_t stream) {
  const int*   x      = (const int*)d_in[0];
  const float* y      = (const float*)d_in[1];
  const float* emb_W  = (const float*)d_in[2];
  const float* emb_b  = (const float*)d_in[3];
  const float* labemb = (const float*)d_in[4];
  const float* cn_W1  = (const float*)d_in[5];
  const float* cn_b1  = (const float*)d_in[6];
  const float* cn_W2  = (const float*)d_in[7];
  const float* cn_b2  = (const float*)d_in[8];
  const float* bn_W1  = (const float*)d_in[9];
  const float* bn_b1  = (const float*)d_in[10];
  const float* bn_W2  = (const float*)d_in[11];
  const float* bn_b2  = (const float*)d_in[12];
  const float* llr_W  = (const float*)d_in[13];
  const float* llr_b  = (const float*)d_in[14];
  float* out = (float*)d_out;

  u16* wfrag = (u16*)d_ws;
  float* labW_g = (float*)((char*)d_ws + 65536);
  float* pred_ws = (float*)((char*)d_ws + STAGE_OFF);
  u16* e9_ws = (u16*)((char*)d_ws + E9_OFF);
  u32* vm_ws = (u32*)((char*)d_ws + VM_OFF);

  prep_kernel<<<13, 256, 0, stream>>>(cn_W1, bn_W1, cn_W2, bn_W2, labemb, llr_W,
                                      bn_b1, wfrag, labW_g);
  if (ws_size >= NEED_SPLIT) {
    polar_a_kernel<<<2 * NB, 512, 0, stream>>>(x, y, emb_W, emb_b, wfrag, labW_g,
                                               cn_b1, cn_b2, bn_b2, llr_W, llr_b,
                                               pred_ws, e9_ws, vm_ws, out);
    polar_b_kernel<<<NB, 512, 0, stream>>>(wfrag, labW_g, cn_b1, cn_b2, bn_b2,
                                           llr_b, pred_ws, e9_ws, vm_ws, out);
    pred_transpose_kernel<<<NB, 512, 0, stream>>>(pred_ws, out);
  } else if (ws_size >= NEED_STAGED) {
    polar_mono_kernel<1><<<NB, 512, 0, stream>>>(x, y, emb_W, emb_b, wfrag, labW_g,
                                                 cn_b1, cn_b2, bn_b2, llr_W, llr_b,
                                                 pred_ws, out);
    pred_transpose_kernel<<<NB, 512, 0, stream>>>(pred_ws, out);
  } else {
    polar_mono_kernel<0><<<NB, 512, 0, stream>>>(x, y, emb_W, emb_b, wfrag, labW_g,
                                                 cn_b1, cn_b2, bn_b2, llr_W, llr_b,
                                                 pred_ws, out);
  }
}

// Round 13
// 231.388 us; speedup vs baseline: 1.1117x; 1.0957x over previous
//
#include <hip/hip_runtime.h>
#include <hip/hip_bf16.h>

#define NB 256
#define NN 1024
#define NSTAGES 11
#define EPSF 1e-7f

typedef unsigned short u16;
typedef unsigned int u32;
typedef unsigned long long u64;
typedef __attribute__((ext_vector_type(8))) short short8;
typedef __attribute__((ext_vector_type(16))) float f32x16;

// Output layout (float32, concatenated):
//   losses (B, 11, N); preds (B, N, 11, 2); norms (B, 11, N)
static constexpr size_t PRED_BASE = (size_t)NB * NSTAGES * NN;
static constexpr size_t NORM_BASE = PRED_BASE + (size_t)NB * NN * NSTAGES * 2;

// wfrag (u16 units): 48 B-fragments for mfma_f32_32x32x16_bf16, channel-pair
// permuted: B[k][n] at lane l, frag (ks,nt): n = 2*(l&31)+nt, k = ks*16+(l>>5)*8+j.
//   cn_W1: 0..15 (K=128) | bn_W1[0:128]: 16..31 | cn_W2: 32..39 | bn_W2: 40..47
//   packed llr_W bf16 pairs (u32[64]) at u16 offset 24576
//   column-packed llr_W pairs (u32[64]: lwc0[32] | lwc1[32]) at u16 24704
//     lwc_c[p] = (W[2p][c], W[2p+1][c]) bf16-packed -> feeds v_dot2_f32_bf16
// labW_g (separate fp32[2][64]): lab_emb[v] @ bn_W1[128:192] + bn_b1  (prep-fused)
static constexpr int LW_OFF = 24576;
static constexpr int LW2_OFF = 24704;

// SPLIT design (R10, confirmed: FETCH 330->11 MB): stages 1..9 have pair
// distance <= 256 -> pairs stay in 512-row halves. Kernel A: 2 blocks/batch,
// ALL 48 frags in LDS. Kernel B: stage 10 + epilogues 9/10.
// R13: epilogue dot products via v_dot2_f32_bf16 (packed bf16 dot2) — the
// scalar extract+fma chain was ~384 VALU ops/stage/thread (the largest
// reducible slice of the 50% VALUBusy); dot2 cuts it to ~96. __has_builtin
// guard -> exact-scalar fallback if the builtin is unavailable.
#define WLDS_FR 30   // kernel B / mono fallback

// Workspace layout:
//   wfrag @0 (64 KB) | labW_g @65536 | pred_ws @131072 (23,068,672 B)
//   e9_ws @E9_OFF (512 chunks x 65536 B) | vm_ws @VM_OFF (512 x 16 u32)
static constexpr size_t STAGE_OFF = 131072;
static constexpr size_t PRED_F2_PER_B = (size_t)NSTAGES * NN;
static constexpr size_t PRED_BYTES = (size_t)NB * NSTAGES * NN * 2 * sizeof(float);
static constexpr size_t E9_OFF = STAGE_OFF + PRED_BYTES;
static constexpr size_t E9_BYTES = (size_t)512 * 65536;
static constexpr size_t VM_OFF = E9_OFF + E9_BYTES;
static constexpr size_t NEED_SPLIT = VM_OFF + (size_t)512 * 16 * sizeof(u32);
static constexpr size_t NEED_STAGED = STAGE_OFF + PRED_BYTES;

__device__ __forceinline__ u16 f2bf(float f) {
  unsigned u = __float_as_uint(f);
  unsigned r = (u + 0x7fffu + ((u >> 16) & 1u)) >> 16;
  return (u16)r;
}
__device__ __forceinline__ unsigned pack_bf2(float a, float b) {
  __hip_bfloat162 h = __float22bfloat162_rn(make_float2(a, b));
  return *(unsigned*)&h;
}
__device__ __forceinline__ u32 spread16(u32 v) {
  v = (v | (v << 8)) & 0x00FF00FFu;
  v = (v | (v << 4)) & 0x0F0F0F0Fu;
  v = (v | (v << 2)) & 0x33333333u;
  v = (v | (v << 1)) & 0x55555555u;
  return v;
}

// Packed bf16 dot2 accumulate: c += a.lo*b.lo + a.hi*b.hi.
// Hardware path: v_dot2_f32_bf16. Fallback: exact scalar equivalent of the
// previous extract+fma chain.
__device__ __forceinline__ float bdot(u32 a, u32 b, float c) {
#if __has_builtin(__builtin_amdgcn_fdot2_f32_bf16)
  typedef __attribute__((ext_vector_type(2))) __bf16 bf2;
  union { u32 u; bf2 v; } ua, ub;
  ua.u = a; ub.u = b;
  return __builtin_amdgcn_fdot2_f32_bf16(ua.v, ub.v, c, false);
#else
  float a0 = __uint_as_float(a << 16), a1 = __uint_as_float(a & 0xffff0000u);
  float b0 = __uint_as_float(b << 16), b1 = __uint_as_float(b & 0xffff0000u);
  return fmaf(a1, b1, fmaf(a0, b0, c));
#endif
}

// STAGED: preds -> workspace in (b,s,n,2) order (dense 8 KB/stage window).
// !STAGED: direct scatter to the final (b,n,11,2) layout (fallback).
template <bool STAGED>
__device__ __forceinline__ void emit_out(float* __restrict__ out, float* __restrict__ pred_ws,
                                         int b, int n, int s,
                                         float z0, float z1, float nrm2, int label) {
  float m  = fmaxf(z0, z1);
  float p0 = expf(z0 - m), p1 = expf(z1 - m);
  float inv = 1.0f / (p0 + p1);
  p0 *= inv; p1 *= inv;
  float pt = label ? p1 : p0;
  pt = fminf(fmaxf(pt, EPSF), 1.0f);
  out[((size_t)b * NSTAGES + s) * NN + n] = -logf(pt);
  if (STAGED) {
    ((float2*)pred_ws)[((size_t)b * NSTAGES + s) * NN + n] = make_float2(p0, p1);
  } else {
    size_t pb = PRED_BASE + (((size_t)b * NN + n) * NSTAGES + s) * 2;
    out[pb + 0] = p0;
    out[pb + 1] = p1;
  }
  out[NORM_BASE + ((size_t)b * NSTAGES + s) * NN + n] = sqrtf(nrm2);
}

// Swizzled e-LDS addressing (u16 units). Row = 64 u16 (128 B) = 8 chunks of
// 16 B; physical chunk = logical_chunk XOR (row & 7) to break stride-128 bank
// conflicts on per-lane row gathers. (row & 7) is invariant under the 512-row
// local/global shift, so kernel A's local rows and kernel B's reads agree.
__device__ __forceinline__ int eaddr(int row, int c16) {
  return row * 64 + (((c16) ^ (row & 7)) << 3);
}
__device__ __forceinline__ int eaddr32(int row, int m31) {
  return row * 64 + (((((m31) >> 2) ^ (row & 7)) << 3) | (((m31) & 3) << 1));
}

__global__ __launch_bounds__(256) void prep_kernel(
    const float* __restrict__ cn_W1, const float* __restrict__ bn_W1,
    const float* __restrict__ cn_W2, const float* __restrict__ bn_W2,
    const float* __restrict__ lab_emb, const float* __restrict__ llr_W,
    const float* __restrict__ bn_b1,
    u16* __restrict__ wfrag, float* __restrict__ labW_g) {
  int t = blockIdx.x * 256 + threadIdx.x;
  if (t < 3072) {
    int f = t >> 6, l = t & 63, h = l >> 5, c = l & 31;
    const float* src; int ks, nt;
    if (f < 16)      { src = cn_W1; ks = f >> 1; nt = f & 1; }
    else if (f < 32) { int g = f - 16; src = bn_W1; ks = g >> 1; nt = g & 1; }
    else if (f < 40) { int g = f - 32; src = cn_W2; ks = g >> 1; nt = g & 1; }
    else             { int g = f - 40; src = bn_W2; ks = g >> 1; nt = g & 1; }
    int col = 2 * c + nt;
    u16 vals[8];
    #pragma unroll
    for (int j = 0; j < 8; ++j) {
      int k = ks * 16 + h * 8 + j;
      vals[j] = f2bf(src[k * 64 + col]);
    }
    uint4 u;
    u.x = (unsigned)vals[0] | ((unsigned)vals[1] << 16);
    u.y = (unsigned)vals[2] | ((unsigned)vals[3] << 16);
    u.z = (unsigned)vals[4] | ((unsigned)vals[5] << 16);
    u.w = (unsigned)vals[6] | ((unsigned)vals[7] << 16);
    *(uint4*)(wfrag + (size_t)t * 8) = u;
  } else if (t < 3136) {
    int k = t - 3072;
    unsigned wv = (unsigned)f2bf(llr_W[k * 2]) | ((unsigned)f2bf(llr_W[k * 2 + 1]) << 16);
    ((unsigned*)(wfrag + LW_OFF))[k] = wv;
  } else if (t < 3264) {
    int idx = t - 3136;
    int v = idx >> 6, c = idx & 63;
    float acc = bn_b1[c];
    for (int d = 0; d < 64; ++d)
      acc = fmaf(lab_emb[v * 64 + d], bn_W1[(128 + d) * 64 + c], acc);
    labW_g[idx] = acc;
  } else if (t < 3328) {
    // column-packed llr pairs for the dot2 epilogue:
    // lwc_c[p] = (W[2p][c], W[2p+1][c]) packed bf16.
    int idx2 = t - 3264;
    int col = idx2 >> 5, p = idx2 & 31;
    unsigned lw = (unsigned)f2bf(llr_W[(2 * p) * 2 + col]) |
                  ((unsigned)f2bf(llr_W[(2 * p + 1) * 2 + col]) << 16);
    ((unsigned*)(wfrag + LW2_OFF))[col * 32 + p] = lw;
  }
}

// Memory-only finisher: ws (b,s,n,2) -> out preds (b,n,11,2), both sides
// dense full-line accesses via an LDS tile.
__global__ __launch_bounds__(512) void pred_transpose_kernel(
    const float* __restrict__ pred_ws, float* __restrict__ out) {
  __shared__ float2 tb[NSTAGES * 1026];
  const int tid = threadIdx.x;
  const int b = blockIdx.x;
  const float2* src = (const float2*)pred_ws + (size_t)b * PRED_F2_PER_B;
  for (int i = tid; i < NSTAGES * NN; i += 512) {
    int s = i >> 10, n = i & (NN - 1);
    tb[s * 1026 + n] = src[i];
  }
  __syncthreads();
  float2* dst = (float2*)(out + PRED_BASE) + (size_t)b * PRED_F2_PER_B;
  for (int j = tid; j < NSTAGES * NN; j += 512) {
    int n = j / NSTAGES, s = j - n * NSTAGES;
    dst[j] = tb[s * 1026 + n];
  }
}

// All-LDS frag read (kernel A, 48 frags resident).
#define AFR(FI) (*(const short8*)(wlds + (FI) * 512 + ln * 8))
// Mixed read (kernel B / mono): 30 LDS + 18 global.
#define BFR(FI) (((FI) < WLDS_FR) ? *(const short8*)(wlds + (FI) * 512 + ln * 8) \
                                  : *(const short8*)(wfrag + (size_t)(FI) * 512 + ln * 8))

// ===================== Kernel A: stages 0..9, half-row blocks ==============
// grid 512: b = blockIdx.x >> 1, h = blockIdx.x & 1. Owns rows [512h,512h+512).
// 8 waves x 1 tile of 32 pairs (R9's flattening, correctness-proven).
// Pairs handled: global i in [256h, 256h+256); local p = i - 256h = 32w+m31.
__global__ __launch_bounds__(512, 2) void polar_a_kernel(
    const int* __restrict__ x, const float* __restrict__ y,
    const float* __restrict__ emb_W, const float* __restrict__ emb_b,
    const u16* __restrict__ wfrag, const float* __restrict__ labW_g,
    const float* __restrict__ cn_b1, const float* __restrict__ cn_b2,
    const float* __restrict__ bn_b2, const float* __restrict__ llr_W,
    const float* __restrict__ llr_b, float* __restrict__ pred_ws,
    u16* __restrict__ e9_ws, u32* __restrict__ vm_ws,
    float* __restrict__ out) {
  __shared__ __align__(16) u16 eLh[512 * 64];          // 65536 B
  __shared__ __align__(16) u16 wlds[48 * 512];         // 49152 B (ALL frags)
  __shared__ __align__(16) u32 lwcL[64];               // 256 B (col-packed llr)
  __shared__ u32 vmask[2][16];                         // 128 B
  __shared__ float labW[2][64];                        // 512 B

  const int tid = threadIdx.x;
  const int w = tid >> 6, ln = tid & 63;
  const int m31 = ln & 31, h8 = ln >> 5;
  const int b = blockIdx.x >> 1, h = blockIdx.x & 1;

  for (int i = tid; i < 48 * 64; i += 512)
    ((uint4*)wlds)[i] = ((const uint4*)wfrag)[i];
  if (tid < 64) lwcL[tid] = ((const u32*)(wfrag + LW2_OFF))[tid];
  if (tid < 128) ((float*)labW)[tid] = labW_g[tid];

  const float lb0 = llr_b[0], lb1 = llr_b[1];
  const float2 cb1 = *(const float2*)(cn_b1 + 2 * m31);
  const float2 cb2 = *(const float2*)(cn_b2 + 2 * m31);
  const float2 bb2 = *(const float2*)(bn_b2 + 2 * m31);

  // ---------------- stage 0: one row per thread ----------------
  {
    int nl = tid;
    int n = 512 * h + nl;
    float2 yv = *(const float2*)(y + ((size_t)b * NN + n) * 2);
    float z0 = lb0, z1 = lb1, nr = 0.f;
    #pragma unroll
    for (int o8 = 0; o8 < 8; ++o8) {
      u32 vals[4];
      #pragma unroll
      for (int jj = 0; jj < 4; ++jj) {
        int o = o8 * 8 + jj * 2;
        float e0 = fmaf(yv.x, emb_W[o],     fmaf(yv.y, emb_W[64 + o],     emb_b[o]));
        float e1 = fmaf(yv.x, emb_W[o + 1], fmaf(yv.y, emb_W[64 + o + 1], emb_b[o + 1]));
        vals[jj] = pack_bf2(e0, e1);
        z0 = fmaf(e0, llr_W[o * 2 + 0], z0); z1 = fmaf(e0, llr_W[o * 2 + 1], z1);
        nr = fmaf(e0, e0, nr);
        z0 = fmaf(e1, llr_W[o * 2 + 2], z0); z1 = fmaf(e1, llr_W[o * 2 + 3], z1);
        nr = fmaf(e1, e1, nr);
      }
      uint4 q; q.x = vals[0]; q.y = vals[1]; q.z = vals[2]; q.w = vals[3];
      *(uint4*)(eLh + eaddr(nl, o8)) = q;
    }
    int v = x[(size_t)b * NN + n] & 1;
    emit_out<true>(out, pred_ws, b, n, 0, z0, z1, nr, v);
    u64 bm = __ballot(v != 0);
    if (ln == 0)  vmask[0][2 * w]     = (u32)bm;
    if (ln == 32) vmask[0][2 * w + 1] = (u32)(bm >> 32);
  }
  __syncthreads();

  const float2 lwv0 = *(const float2*)(&labW[0][2 * m31]);
  const float2 lwv1 = *(const float2*)(&labW[1][2 * m31]);

  // ---------------- stages 1..9 (pairs stay in this half) ----------------
  #pragma unroll 1
  for (int s = 1; s <= 9; ++s) {
    const int sh = s - 1;
    const int half = 1 << sh;
    const u32* vmR = vmask[(s - 1) & 1];
    u32* vmW = vmask[s & 1];

    short8 Ao[4], Ae[4];
    int iog, ieg, iol, iel, vo, ve, vx;
    u32 bxs;
    {
      int i = 256 * h + 32 * w + m31;              // global pair index
      int g = i >> sh, u = i & (half - 1);
      iog = g * (half << 1) + u;
      ieg = iog + half;
      iol = iog & 511; iel = ieg & 511;            // local rows
      #pragma unroll
      for (int f = 0; f < 4; ++f) {
        Ao[f] = *(const short8*)(eLh + eaddr(iol, f * 2 + h8));
        Ae[f] = *(const short8*)(eLh + eaddr(iel, f * 2 + h8));
      }
      vo = (vmR[iol >> 5] >> (iol & 31)) & 1;
      ve = (vmR[iel >> 5] >> (iel & 31)) & 1;
      vx = vo ^ ve;
      u32 bx = (u32)__ballot(vx != 0);
      u32 be = (u32)__ballot(ve != 0);
      bxs = bx;
      u32 lo = spread16(bx & 0xffffu) | (spread16(be & 0xffffu) << 1);
      u32 hi = spread16(bx >> 16) | (spread16(be >> 16) << 1);
      if (ln == 0) { vmW[2 * w] = lo; vmW[2 * w + 1] = hi; }
    }
    __syncthreads();

    // epilogue for stage s-1 (s>=2), A-frags in regs; dot2 path (R13):
    // lane's u32 jj of frag f covers k-pair p = 8f+4h8+jj -> lwc quad 2f+h8.
    if (s >= 2) {
      const uint4* lwq2 = (const uint4*)lwcL;
      #pragma unroll
      for (int side = 0; side < 2; ++side) {
        float z0 = 0.f, z1 = 0.f, nr = 0.f;
        #pragma unroll
        for (int f = 0; f < 4; ++f) {
          short8 av8 = side ? Ae[f] : Ao[f];
          uint4 c0 = lwq2[2 * f + h8];
          uint4 c1 = lwq2[8 + 2 * f + h8];
          #pragma unroll
          for (int jj = 0; jj < 4; ++jj) {
            u32 pv = ((const u32*)&av8)[jj];
            z0 = bdot(pv, ((const u32*)&c0)[jj], z0);
            z1 = bdot(pv, ((const u32*)&c1)[jj], z1);
            nr = bdot(pv, pv, nr);
          }
        }
        z0 += __shfl_xor(z0, 32);
        z1 += __shfl_xor(z1, 32);
        nr += __shfl_xor(nr, 32);
        if (h8 == 0)
          emit_out<true>(out, pred_ws, b, side ? ieg : iog, s - 1,
                         z0 + lb0, z1 + lb1, nr, side ? ve : vo);
      }
    }

    // ---- layer-1 cn (K=128) ----
    f32x16 a0, a1;
    #pragma unroll
    for (int r = 0; r < 16; ++r) { a0[r] = cb1.x; a1[r] = cb1.y; }
    #pragma unroll
    for (int ks = 0; ks < 8; ++ks) {
      short8 B0 = AFR(ks * 2 + 0);
      short8 B1 = AFR(ks * 2 + 1);
      short8 a = (ks < 4) ? Ao[ks] : Ae[ks - 4];
      a0 = __builtin_amdgcn_mfma_f32_32x32x16_bf16(a, B0, a0, 0, 0, 0);
      a1 = __builtin_amdgcn_mfma_f32_32x32x16_bf16(a, B1, a1, 0, 0, 0);
    }
    {
      int obase = 64 * w;
      #pragma unroll
      for (int r = 0; r < 16; ++r) {
        int row = (r & 3) + 8 * (r >> 2) + 4 * h8;
        int R = obase + 2 * row;
        *(u32*)(eLh + eaddr32(R, m31)) =
            pack_bf2(fmaxf(a0[r], 0.f), fmaxf(a1[r], 0.f));
      }
    }

    // ---- layer-1 bn (K=128 + fused labW bias) ----
    #pragma unroll
    for (int r = 0; r < 16; ++r) {
      int row = (r & 3) + 8 * (r >> 2) + 4 * h8;
      int bit = (bxs >> row) & 1;
      a0[r] = bit ? lwv1.x : lwv0.x;
      a1[r] = bit ? lwv1.y : lwv0.y;
    }
    #pragma unroll
    for (int ks = 0; ks < 8; ++ks) {
      short8 B0 = AFR(16 + ks * 2 + 0);
      short8 B1 = AFR(16 + ks * 2 + 1);
      short8 a = (ks < 4) ? Ao[ks] : Ae[ks - 4];
      a0 = __builtin_amdgcn_mfma_f32_32x32x16_bf16(a, B0, a0, 0, 0, 0);
      a1 = __builtin_amdgcn_mfma_f32_32x32x16_bf16(a, B1, a1, 0, 0, 0);
    }
    {
      int obase = 64 * w;
      #pragma unroll
      for (int r = 0; r < 16; ++r) {
        int row = (r & 3) + 8 * (r >> 2) + 4 * h8;
        int R = obase + 2 * row + 1;
        *(u32*)(eLh + eaddr32(R, m31)) =
            pack_bf2(fmaxf(a0[r], 0.f), fmaxf(a1[r], 0.f));
      }
    }

    // ---- layer-2 cn ----
    {
      short8 Hc[4];
      {
        int R = 64 * w + 2 * m31;
        #pragma unroll
        for (int f = 0; f < 4; ++f)
          Hc[f] = *(const short8*)(eLh + eaddr(R, f * 2 + h8));
      }
      f32x16 d0, d1;
      #pragma unroll
      for (int r = 0; r < 16; ++r) { d0[r] = cb2.x; d1[r] = cb2.y; }
      #pragma unroll
      for (int ks = 0; ks < 4; ++ks) {
        short8 B0 = AFR(32 + ks * 2 + 0);
        short8 B1 = AFR(32 + ks * 2 + 1);
        d0 = __builtin_amdgcn_mfma_f32_32x32x16_bf16(Hc[ks], B0, d0, 0, 0, 0);
        d1 = __builtin_amdgcn_mfma_f32_32x32x16_bf16(Hc[ks], B1, d1, 0, 0, 0);
      }
      int obase = 64 * w;
      #pragma unroll
      for (int r = 0; r < 16; ++r) {
        int row = (r & 3) + 8 * (r >> 2) + 4 * h8;
        int R = obase + 2 * row;
        *(u32*)(eLh + eaddr32(R, m31)) = pack_bf2(d0[r], d1[r]);
      }
    }

    // ---- layer-2 bn ----
    {
      short8 Hb[4];
      {
        int R = 64 * w + 2 * m31 + 1;
        #pragma unroll
        for (int f = 0; f < 4; ++f)
          Hb[f] = *(const short8*)(eLh + eaddr(R, f * 2 + h8));
      }
      f32x16 d0, d1;
      #pragma unroll
      for (int r = 0; r < 16; ++r) { d0[r] = bb2.x; d1[r] = bb2.y; }
      #pragma unroll
      for (int ks = 0; ks < 4; ++ks) {
        short8 B0 = AFR(40 + ks * 2 + 0);
        short8 B1 = AFR(40 + ks * 2 + 1);
        d0 = __builtin_amdgcn_mfma_f32_32x32x16_bf16(Hb[ks], B0, d0, 0, 0, 0);
        d1 = __builtin_amdgcn_mfma_f32_32x32x16_bf16(Hb[ks], B1, d1, 0, 0, 0);
      }
      int obase = 64 * w;
      #pragma unroll
      for (int r = 0; r < 16; ++r) {
        int row = (r & 3) + 8 * (r >> 2) + 4 * h8;
        int R = obase + 2 * row + 1;
        *(u32*)(eLh + eaddr32(R, m31)) = pack_bf2(d0[r], d1[r]);
      }
    }
    __syncthreads();
  }

  // ---------------- dump e9 half + stage-9 vmask ----------------
  {
    const uint4* src = (const uint4*)eLh;
    uint4* dst = (uint4*)(e9_ws + (size_t)(b * 2 + h) * 32768);
    for (int i = tid; i < 4096; i += 512) dst[i] = src[i];
    if (tid < 16) vm_ws[(b * 2 + h) * 16 + tid] = vmask[1][tid];  // 9&1 == 1
  }
}

// ===================== Kernel B: stage 10 + epilogues 9,10 =================
// grid 256 (b), 8 waves x 2 tiles (R6 proven shape). Reads e9 pairs (i, i+512)
// from workspace; computes stage 10 into full eL; final epilogue.
__global__ __launch_bounds__(512, 2) void polar_b_kernel(
    const u16* __restrict__ wfrag, const float* __restrict__ labW_g,
    const float* __restrict__ cn_b1, const float* __restrict__ cn_b2,
    const float* __restrict__ bn_b2, const float* __restrict__ llr_b,
    float* __restrict__ pred_ws, const u16* __restrict__ e9_ws,
    const u32* __restrict__ vm_ws, float* __restrict__ out) {
  __shared__ __align__(16) u16 eL[NN * 64];            // 131072 B
  __shared__ __align__(16) u16 wlds[WLDS_FR * 512];    // 30720 B
  __shared__ __align__(16) u32 lwcL[64];               // 256 B (col-packed llr)
  __shared__ u32 vmA[32];                              // stage-9 labels
  __shared__ u32 vmB[32];                              // stage-10 labels
  __shared__ float labW[2][64];                        // 512 B

  const int tid = threadIdx.x;
  const int w = tid >> 6, ln = tid & 63;
  const int m31 = ln & 31, h8 = ln >> 5;
  const int b = blockIdx.x;

  for (int i = tid; i < WLDS_FR * 64; i += 512)
    ((uint4*)wlds)[i] = ((const uint4*)wfrag)[i];
  if (tid < 64) lwcL[tid] = ((const u32*)(wfrag + LW2_OFF))[tid];
  if (tid < 128) ((float*)labW)[tid] = labW_g[tid];
  if (tid < 32) vmA[tid] = vm_ws[b * 32 + tid];        // h=0 words 0..15, h=1 16..31

  const float lb0 = llr_b[0], lb1 = llr_b[1];
  const float2 cb1 = *(const float2*)(cn_b1 + 2 * m31);
  const float2 cb2 = *(const float2*)(cn_b2 + 2 * m31);
  const float2 bb2 = *(const float2*)(bn_b2 + 2 * m31);
  __syncthreads();                                     // preamble LDS visible

  const float2 lwv0 = *(const float2*)(&labW[0][2 * m31]);
  const float2 lwv1 = *(const float2*)(&labW[1][2 * m31]);

  const u16* e9a = e9_ws + (size_t)(b * 2 + 0) * 32768;
  const u16* e9b = e9_ws + (size_t)(b * 2 + 1) * 32768;

  // ---- A-read phase: pairs (i, i+512) from the two halves ----
  short8 Ao[2][4], Ae[2][4];
  int io[2], ie[2], vo[2], ve[2], vx[2];
  u32 bxs[2];
  #pragma unroll
  for (int t = 0; t < 2; ++t) {
    int i = 64 * w + 32 * t + m31;                     // pair index [0,512)
    io[t] = i; ie[t] = i + 512;
    #pragma unroll
    for (int f = 0; f < 4; ++f) {
      Ao[t][f] = *(const short8*)(e9a + eaddr(i, f * 2 + h8));
      Ae[t][f] = *(const short8*)(e9b + eaddr(i, f * 2 + h8));  // local row = i
    }
    vo[t] = (vmA[i >> 5] >> (i & 31)) & 1;
    ve[t] = (vmA[(i >> 5) + 16] >> (i & 31)) & 1;
    vx[t] = vo[t] ^ ve[t];
    u32 bx = (u32)__ballot(vx[t] != 0);
    u32 be = (u32)__ballot(ve[t] != 0);
    bxs[t] = bx;
    u32 lo = spread16(bx & 0xffffu) | (spread16(be & 0xffffu) << 1);
    u32 hi = spread16(bx >> 16) | (spread16(be >> 16) << 1);
    if (ln == 0) { vmB[4 * w + 2 * t] = lo; vmB[4 * w + 2 * t + 1] = hi; }
  }
  __syncthreads();

  // ---- epilogue for stage 9 (A-frags in regs; dot2 path) ----
  {
    const uint4* lwq2 = (const uint4*)lwcL;
    #pragma unroll
    for (int t = 0; t < 2; ++t) {
      #pragma unroll
      for (int side = 0; side < 2; ++side) {
        float z0 = 0.f, z1 = 0.f, nr = 0.f;
        #pragma unroll
        for (int f = 0; f < 4; ++f) {
          short8 av8 = side ? Ae[t][f] : Ao[t][f];
          uint4 c0 = lwq2[2 * f + h8];
          uint4 c1 = lwq2[8 + 2 * f + h8];
          #pragma unroll
          for (int jj = 0; jj < 4; ++jj) {
            u32 pv = ((const u32*)&av8)[jj];
            z0 = bdot(pv, ((const u32*)&c0)[jj], z0);
            z1 = bdot(pv, ((const u32*)&c1)[jj], z1);
            nr = bdot(pv, pv, nr);
          }
        }
        z0 += __shfl_xor(z0, 32);
        z1 += __shfl_xor(z1, 32);
        nr += __shfl_xor(nr, 32);
        if (h8 == 0)
          emit_out<true>(out, pred_ws, b, side ? ie[t] : io[t], 9,
                         z0 + lb0, z1 + lb1, nr, side ? ve[t] : vo[t]);
      }
    }
  }

  // ---- layer-1 cn ----
  f32x16 a0[2], a1[2];
  #pragma unroll
  for (int t = 0; t < 2; ++t)
    #pragma unroll
    for (int r = 0; r < 16; ++r) { a0[t][r] = cb1.x; a1[t][r] = cb1.y; }
  #pragma unroll
  for (int ks = 0; ks < 8; ++ks) {
    short8 B0 = BFR(ks * 2 + 0);
    short8 B1 = BFR(ks * 2 + 1);
    #pragma unroll
    for (int t = 0; t < 2; ++t) {
      short8 a = (ks < 4) ? Ao[t][ks] : Ae[t][ks - 4];
      a0[t] = __builtin_amdgcn_mfma_f32_32x32x16_bf16(a, B0, a0[t], 0, 0, 0);
      a1[t] = __builtin_amdgcn_mfma_f32_32x32x16_bf16(a, B1, a1[t], 0, 0, 0);
    }
  }
  #pragma unroll
  for (int t = 0; t < 2; ++t) {
    int obase = 128 * w + 64 * t;
    #pragma unroll
    for (int r = 0; r < 16; ++r) {
      int row = (r & 3) + 8 * (r >> 2) + 4 * h8;
      int R = obase + 2 * row;
      *(u32*)(eL + eaddr32(R, m31)) =
          pack_bf2(fmaxf(a0[t][r], 0.f), fmaxf(a1[t][r], 0.f));
    }
  }

  // ---- layer-1 bn ----
  #pragma unroll
  for (int t = 0; t < 2; ++t)
    #pragma unroll
    for (int r = 0; r < 16; ++r) {
      int row = (r & 3) + 8 * (r >> 2) + 4 * h8;
      int bit = (bxs[t] >> row) & 1;
      a0[t][r] = bit ? lwv1.x : lwv0.x;
      a1[t][r] = bit ? lwv1.y : lwv0.y;
    }
  #pragma unroll
  for (int ks = 0; ks < 8; ++ks) {
    short8 B0 = BFR(16 + ks * 2 + 0);
    short8 B1 = BFR(16 + ks * 2 + 1);
    #pragma unroll
    for (int t = 0; t < 2; ++t) {
      short8 a = (ks < 4) ? Ao[t][ks] : Ae[t][ks - 4];
      a0[t] = __builtin_amdgcn_mfma_f32_32x32x16_bf16(a, B0, a0[t], 0, 0, 0);
      a1[t] = __builtin_amdgcn_mfma_f32_32x32x16_bf16(a, B1, a1[t], 0, 0, 0);
    }
  }
  #pragma unroll
  for (int t = 0; t < 2; ++t) {
    int obase = 128 * w + 64 * t;
    #pragma unroll
    for (int r = 0; r < 16; ++r) {
      int row = (r & 3) + 8 * (r >> 2) + 4 * h8;
      int R = obase + 2 * row + 1;
      *(u32*)(eL + eaddr32(R, m31)) =
          pack_bf2(fmaxf(a0[t][r], 0.f), fmaxf(a1[t][r], 0.f));
    }
  }

  // ---- layer-2 cn ----
  {
    short8 Hc[2][4];
    #pragma unroll
    for (int t = 0; t < 2; ++t) {
      int R = 128 * w + 64 * t + 2 * m31;
      #pragma unroll
      for (int f = 0; f < 4; ++f)
        Hc[t][f] = *(const short8*)(eL + eaddr(R, f * 2 + h8));
    }
    f32x16 d0[2], d1[2];
    #pragma unroll
    for (int t = 0; t < 2; ++t)
      #pragma unroll
      for (int r = 0; r < 16; ++r) { d0[t][r] = cb2.x; d1[t][r] = cb2.y; }
    #pragma unroll
    for (int ks = 0; ks < 4; ++ks) {
      short8 B0 = BFR(32 + ks * 2 + 0);
      short8 B1 = BFR(32 + ks * 2 + 1);
      #pragma unroll
      for (int t = 0; t < 2; ++t) {
        d0[t] = __builtin_amdgcn_mfma_f32_32x32x16_bf16(Hc[t][ks], B0, d0[t], 0, 0, 0);
        d1[t] = __builtin_amdgcn_mfma_f32_32x32x16_bf16(Hc[t][ks], B1, d1[t], 0, 0, 0);
      }
    }
    #pragma unroll
    for (int t = 0; t < 2; ++t) {
      int obase = 128 * w + 64 * t;
      #pragma unroll
      for (int r = 0; r < 16; ++r) {
        int row = (r & 3) + 8 * (r >> 2) + 4 * h8;
        int R = obase + 2 * row;
        *(u32*)(eL + eaddr32(R, m31)) = pack_bf2(d0[t][r], d1[t][r]);
      }
    }
  }

  // ---- layer-2 bn ----
  {
    short8 Hb[2][4];
    #pragma unroll
    for (int t = 0; t < 2; ++t) {
      int R = 128 * w + 64 * t + 2 * m31 + 1;
      #pragma unroll
      for (int f = 0; f < 4; ++f)
        Hb[t][f] = *(const short8*)(eL + eaddr(R, f * 2 + h8));
    }
    f32x16 d0[2], d1[2];
    #pragma unroll
    for (int t = 0; t < 2; ++t)
      #pragma unroll
      for (int r = 0; r < 16; ++r) { d0[t][r] = bb2.x; d1[t][r] = bb2.y; }
    #pragma unroll
    for (int ks = 0; ks < 4; ++ks) {
      short8 B0 = BFR(40 + ks * 2 + 0);
      short8 B1 = BFR(40 + ks * 2 + 1);
      #pragma unroll
      for (int t = 0; t < 2; ++t) {
        d0[t] = __builtin_amdgcn_mfma_f32_32x32x16_bf16(Hb[t][ks], B0, d0[t], 0, 0, 0);
        d1[t] = __builtin_amdgcn_mfma_f32_32x32x16_bf16(Hb[t][ks], B1, d1[t], 0, 0, 0);
      }
    }
    #pragma unroll
    for (int t = 0; t < 2; ++t) {
      int obase = 128 * w + 64 * t;
      #pragma unroll
      for (int r = 0; r < 16; ++r) {
        int row = (r & 3) + 8 * (r >> 2) + 4 * h8;
        int R = obase + 2 * row + 1;
        *(u32*)(eL + eaddr32(R, m31)) = pack_bf2(d0[t][r], d1[t][r]);
      }
    }
  }
  __syncthreads();

  // ---- final epilogue (stage 10; dot2 path) ----
  {
    const uint4* lwq2 = (const uint4*)lwcL;
    #pragma unroll
    for (int it = 0; it < 4; ++it) {
      int n = 128 * w + 32 * it + m31;
      float z0 = 0.f, z1 = 0.f, nr = 0.f;
      #pragma unroll
      for (int f = 0; f < 4; ++f) {
        short8 av8 = *(const short8*)(eL + eaddr(n, f * 2 + h8));
        uint4 c0 = lwq2[2 * f + h8];
        uint4 c1 = lwq2[8 + 2 * f + h8];
        #pragma unroll
        for (int jj = 0; jj < 4; ++jj) {
          u32 pv = ((const u32*)&av8)[jj];
          z0 = bdot(pv, ((const u32*)&c0)[jj], z0);
          z1 = bdot(pv, ((const u32*)&c1)[jj], z1);
          nr = bdot(pv, pv, nr);
        }
      }
      z0 += __shfl_xor(z0, 32);
      z1 += __shfl_xor(z1, 32);
      nr += __shfl_xor(nr, 32);
      int lab = (vmB[n >> 5] >> (n & 31)) & 1;
      if (h8 == 0)
        emit_out<true>(out, pred_ws, b, n, NSTAGES - 1, z0 + lb0, z1 + lb1, nr, lab);
    }
  }
}

// ===================== Mono fallback (R6, best single-kernel) ==============
template <int STAGED>
__global__ __launch_bounds__(512, 2) void polar_mono_kernel(
    const int* __restrict__ x, const float* __restrict__ y,
    const float* __restrict__ emb_W, const float* __restrict__ emb_b,
    const u16* __restrict__ wfrag, const float* __restrict__ labW_g,
    const float* __restrict__ cn_b1, const float* __restrict__ cn_b2,
    const float* __restrict__ bn_b2, const float* __restrict__ llr_W,
    const float* __restrict__ llr_b, float* __restrict__ pred_ws,
    float* __restrict__ out) {
  __shared__ __align__(16) u16 eL[NN * 64];
  __shared__ __align__(16) u16 wlds[WLDS_FR * 512];
  __shared__ u32 lwL[64];
  __shared__ u32 vmask[2][32];
  __shared__ float labW[2][64];

  const int tid = threadIdx.x;
  const int w = tid >> 6, ln = tid & 63;
  const int m31 = ln & 31, h8 = ln >> 5;
  const int b = blockIdx.x;

  for (int i = tid; i < WLDS_FR * 64; i += 512)
    ((uint4*)wlds)[i] = ((const uint4*)wfrag)[i];
  if (tid < 64) lwL[tid] = ((const u32*)(wfrag + LW_OFF))[tid];
  if (tid < 128) ((float*)labW)[tid] = labW_g[tid];

  const float lb0 = llr_b[0], lb1 = llr_b[1];
  const float2 cb1 = *(const float2*)(cn_b1 + 2 * m31);
  const float2 cb2 = *(const float2*)(cn_b2 + 2 * m31);
  const float2 bb2 = *(const float2*)(bn_b2 + 2 * m31);

  #pragma unroll
  for (int rep = 0; rep < 2; ++rep) {
    int n = rep * 512 + tid;
    float2 yv = *(const float2*)(y + ((size_t)b * NN + n) * 2);
    float z0 = lb0, z1 = lb1, nr = 0.f;
    #pragma unroll
    for (int o8 = 0; o8 < 8; ++o8) {
      u32 vals[4];
      #pragma unroll
      for (int jj = 0; jj < 4; ++jj) {
        int o = o8 * 8 + jj * 2;
        float e0 = fmaf(yv.x, emb_W[o],     fmaf(yv.y, emb_W[64 + o],     emb_b[o]));
        float e1 = fmaf(yv.x, emb_W[o + 1], fmaf(yv.y, emb_W[64 + o + 1], emb_b[o + 1]));
        vals[jj] = pack_bf2(e0, e1);
        z0 = fmaf(e0, llr_W[o * 2 + 0], z0); z1 = fmaf(e0, llr_W[o * 2 + 1], z1);
        nr = fmaf(e0, e0, nr);
        z0 = fmaf(e1, llr_W[o * 2 + 2], z0); z1 = fmaf(e1, llr_W[o * 2 + 3], z1);
        nr = fmaf(e1, e1, nr);
      }
      uint4 q; q.x = vals[0]; q.y = vals[1]; q.z = vals[2]; q.w = vals[3];
      *(uint4*)(eL + eaddr(n, o8)) = q;
    }
    int v = x[(size_t)b * NN + n] & 1;
    emit_out<STAGED != 0>(out, pred_ws, b, n, 0, z0, z1, nr, v);
    u64 bm = __ballot(v != 0);
    if (ln == 0)  vmask[0][rep * 16 + 2 * w]     = (u32)bm;
    if (ln == 32) vmask[0][rep * 16 + 2 * w + 1] = (u32)(bm >> 32);
  }
  __syncthreads();

  const float2 lwv0 = *(const float2*)(&labW[0][2 * m31]);
  const float2 lwv1 = *(const float2*)(&labW[1][2 * m31]);

  #pragma unroll 1
  for (int s = 1; s <= 10; ++s) {
    const int sh = s - 1;
    const int half = 1 << sh;
    const u32* vmR = vmask[(s - 1) & 1];
    u32* vmW = vmask[s & 1];

    short8 Ao[2][4], Ae[2][4];
    int io[2], ie[2], vo[2], ve[2], vx[2];
    u32 bxs[2];
    #pragma unroll
    for (int t = 0; t < 2; ++t) {
      int i = 64 * w + 32 * t + m31;
      int g = i >> sh, u = i & (half - 1);
      io[t] = g * (half << 1) + u;
      ie[t] = io[t] + half;
      #pragma unroll
      for (int f = 0; f < 4; ++f) {
        Ao[t][f] = *(const short8*)(eL + eaddr(io[t], f * 2 + h8));
        Ae[t][f] = *(const short8*)(eL + eaddr(ie[t], f * 2 + h8));
      }
      vo[t] = (vmR[io[t] >> 5] >> (io[t] & 31)) & 1;
      ve[t] = (vmR[ie[t] >> 5] >> (ie[t] & 31)) & 1;
      vx[t] = vo[t] ^ ve[t];
      u32 bx = (u32)__ballot(vx[t] != 0);
      u32 be = (u32)__ballot(ve[t] != 0);
      bxs[t] = bx;
      u32 lo = spread16(bx & 0xffffu) | (spread16(be & 0xffffu) << 1);
      u32 hi = spread16(bx >> 16) | (spread16(be >> 16) << 1);
      if (ln == 0) { vmW[4 * w + 2 * t] = lo; vmW[4 * w + 2 * t + 1] = hi; }
    }
    __syncthreads();

    if (s >= 2) {
      const uint4* lwq = (const uint4*)lwL;
      uint4 lq[4][2];
      #pragma unroll
      for (int f = 0; f < 4; ++f) {
        lq[f][0] = lwq[f * 4 + h8 * 2];
        lq[f][1] = lwq[f * 4 + h8 * 2 + 1];
      }
      #pragma unroll
      for (int t = 0; t < 2; ++t) {
        #pragma unroll
        for (int side = 0; side < 2; ++side) {
          float z0 = 0.f, z1 = 0.f, nr = 0.f;
          #pragma unroll
          for (int f = 0; f < 4; ++f) {
            short8 av8 = side ? Ae[t][f] : Ao[t][f];
            #pragma unroll
            for (int j = 0; j < 8; ++j) {
              u32 pv = ((const u32*)&av8)[j >> 1];
              float val = __uint_as_float((j & 1) ? (pv & 0xffff0000u) : (pv << 16));
              u32 lwp = (j < 4) ? ((const u32*)&lq[f][0])[j] : ((const u32*)&lq[f][1])[j - 4];
              z0 = fmaf(val, __uint_as_float(lwp << 16), z0);
              z1 = fmaf(val, __uint_as_float(lwp & 0xffff0000u), z1);
              nr = fmaf(val, val, nr);
            }
          }
          z0 += __shfl_xor(z0, 32);
          z1 += __shfl_xor(z1, 32);
          nr += __shfl_xor(nr, 32);
          if (h8 == 0)
            emit_out<STAGED != 0>(out, pred_ws, b, side ? ie[t] : io[t], s - 1,
                                  z0 + lb0, z1 + lb1, nr, side ? ve[t] : vo[t]);
        }
      }
    }

    f32x16 a0[2], a1[2];
    #pragma unroll
    for (int t = 0; t < 2; ++t)
      #pragma unroll
      for (int r = 0; r < 16; ++r) { a0[t][r] = cb1.x; a1[t][r] = cb1.y; }
    #pragma unroll
    for (int ks = 0; ks < 8; ++ks) {
      short8 B0 = BFR(ks * 2 + 0);
      short8 B1 = BFR(ks * 2 + 1);
      #pragma unroll
      for (int t = 0; t < 2; ++t) {
        short8 a = (ks < 4) ? Ao[t][ks] : Ae[t][ks - 4];
        a0[t] = __builtin_amdgcn_mfma_f32_32x32x16_bf16(a, B0, a0[t], 0, 0, 0);
        a1[t] = __builtin_amdgcn_mfma_f32_32x32x16_bf16(a, B1, a1[t], 0, 0, 0);
      }
    }
    #pragma unroll
    for (int t = 0; t < 2; ++t) {
      int obase = 128 * w + 64 * t;
      #pragma unroll
      for (int r = 0; r < 16; ++r) {
        int row = (r & 3) + 8 * (r >> 2) + 4 * h8;
        int R = obase + 2 * row;
        *(u32*)(eL + eaddr32(R, m31)) =
            pack_bf2(fmaxf(a0[t][r], 0.f), fmaxf(a1[t][r], 0.f));
      }
    }

    #pragma unroll
    for (int t = 0; t < 2; ++t)
      #pragma unroll
      for (int r = 0; r < 16; ++r) {
        int row = (r & 3) + 8 * (r >> 2) + 4 * h8;
        int bit = (bxs[t] >> row) & 1;
        a0[t][r] = bit ? lwv1.x : lwv0.x;
        a1[t][r] = bit ? lwv1.y : lwv0.y;
      }
    #pragma unroll
    for (int ks = 0; ks < 8; ++ks) {
      short8 B0 = BFR(16 + ks * 2 + 0);
      short8 B1 = BFR(16 + ks * 2 + 1);
      #pragma unroll
      for (int t = 0; t < 2; ++t) {
        short8 a = (ks < 4) ? Ao[t][ks] : Ae[t][ks - 4];
        a0[t] = __builtin_amdgcn_mfma_f32_32x32x16_bf16(a, B0, a0[t], 0, 0, 0);
        a1[t] = __builtin_amdgcn_mfma_f32_32x32x16_bf16(a, B1, a1[t], 0, 0, 0);
      }
    }
    #pragma unroll
    for (int t = 0; t < 2; ++t) {
      int obase = 128 * w + 64 * t;
      #pragma unroll
      for (int r = 0; r < 16; ++r) {
        int row = (r & 3) + 8 * (r >> 2) + 4 * h8;
        int R = obase + 2 * row + 1;
        *(u32*)(eL + eaddr32(R, m31)) =
            pack_bf2(fmaxf(a0[t][r], 0.f), fmaxf(a1[t][r], 0.f));
      }
    }

    {
      short8 Hc[2][4];
      #pragma unroll
      for (int t = 0; t < 2; ++t) {
        int R = 128 * w + 64 * t + 2 * m31;
        #pragma unroll
        for (int f = 0; f < 4; ++f)
          Hc[t][f] = *(const short8*)(eL + eaddr(R, f * 2 + h8));
      }
      f32x16 d0[2], d1[2];
      #pragma unroll
      for (int t = 0; t < 2; ++t)
        #pragma unroll
        for (int r = 0; r < 16; ++r) { d0[t][r] = cb2.x; d1[t][r] = cb2.y; }
      #pragma unroll
      for (int ks = 0; ks < 4; ++ks) {
        short8 B0 = BFR(32 + ks * 2 + 0);
        short8 B1 = BFR(32 + ks * 2 + 1);
        #pragma unroll
        for (int t = 0; t < 2; ++t) {
          d0[t] = __builtin_amdgcn_mfma_f32_32x32x16_bf16(Hc[t][ks], B0, d0[t], 0, 0, 0);
          d1[t] = __builtin_amdgcn_mfma_f32_32x32x16_bf16(Hc[t][ks], B1, d1[t], 0, 0, 0);
        }
      }
      #pragma unroll
      for (int t = 0; t < 2; ++t) {
        int obase = 128 * w + 64 * t;
        #pragma unroll
        for (int r = 0; r < 16; ++r) {
          int row = (r & 3) + 8 * (r >> 2) + 4 * h8;
          int R = obase + 2 * row;
          *(u32*)(eL + eaddr32(R, m31)) = pack_bf2(d0[t][r], d1[t][r]);
        }
      }
    }

    {
      short8 Hb[2][4];
      #pragma unroll
      for (int t = 0; t < 2; ++t) {
        int R = 128 * w + 64 * t + 2 * m31 + 1;
        #pragma unroll
        for (int f = 0; f < 4; ++f)
          Hb[t][f] = *(const short8*)(eL + eaddr(R, f * 2 + h8));
      }
      f32x16 d0[2], d1[2];
      #pragma unroll
      for (int t = 0; t < 2; ++t)
        #pragma unroll
        for (int r = 0; r < 16; ++r) { d0[t][r] = bb2.x; d1[t][r] = bb2.y; }
      #pragma unroll
      for (int ks = 0; ks < 4; ++ks) {
        short8 B0 = BFR(40 + ks * 2 + 0);
        short8 B1 = BFR(40 + ks * 2 + 1);
        #pragma unroll
        for (int t = 0; t < 2; ++t) {
          d0[t] = __builtin_amdgcn_mfma_f32_32x32x16_bf16(Hb[t][ks], B0, d0[t], 0, 0, 0);
          d1[t] = __builtin_amdgcn_mfma_f32_32x32x16_bf16(Hb[t][ks], B1, d1[t], 0, 0, 0);
        }
      }
      #pragma unroll
      for (int t = 0; t < 2; ++t) {
        int obase = 128 * w + 64 * t;
        #pragma unroll
        for (int r = 0; r < 16; ++r) {
          int row = (r & 3) + 8 * (r >> 2) + 4 * h8;
          int R = obase + 2 * row + 1;
          *(u32*)(eL + eaddr32(R, m31)) = pack_bf2(d0[t][r], d1[t][r]);
        }
      }
    }
    __syncthreads();
  }

  {
    const uint4* lwq = (const uint4*)lwL;
    uint4 lq[4][2];
    #pragma unroll
    for (int f = 0; f < 4; ++f) {
      lq[f][0] = lwq[f * 4 + h8 * 2];
      lq[f][1] = lwq[f * 4 + h8 * 2 + 1];
    }
    #pragma unroll
    for (int it = 0; it < 4; ++it) {
      int n = 128 * w + 32 * it + m31;
      float z0 = 0.f, z1 = 0.f, nr = 0.f;
      #pragma unroll
      for (int f = 0; f < 4; ++f) {
        short8 av8 = *(const short8*)(eL + eaddr(n, f * 2 + h8));
        #pragma unroll
        for (int j = 0; j < 8; ++j) {
          u32 pv = ((const u32*)&av8)[j >> 1];
          float val = __uint_as_float((j & 1) ? (pv & 0xffff0000u) : (pv << 16));
          u32 lwp = (j < 4) ? ((const u32*)&lq[f][0])[j] : ((const u32*)&lq[f][1])[j - 4];
          z0 = fmaf(val, __uint_as_float(lwp << 16), z0);
          z1 = fmaf(val, __uint_as_float(lwp & 0xffff0000u), z1);
          nr = fmaf(val, val, nr);
        }
      }
      z0 += __shfl_xor(z0, 32);
      z1 += __shfl_xor(z1, 32);
      nr += __shfl_xor(nr, 32);
      int lab = (vmask[0][n >> 5] >> (n & 31)) & 1;
      if (h8 == 0)
        emit_out<STAGED != 0>(out, pred_ws, b, n, NSTAGES - 1, z0 + lb0, z1 + lb1, nr, lab);
    }
  }
}

extern "C" void kernel_launch(void* const* d_in, const int* in_sizes, int n_in,
                              void* d_out, int out_size, void* d_ws, size_t ws_size,
                              hipStream_t stream) {
  const int*   x      = (const int*)d_in[0];
  const float* y      = (const float*)d_in[1];
  const float* emb_W  = (const float*)d_in[2];
  const float* emb_b  = (const float*)d_in[3];
  const float* labemb = (const float*)d_in[4];
  const float* cn_W1  = (const float*)d_in[5];
  const float* cn_b1  = (const float*)d_in[6];
  const float* cn_W2  = (const float*)d_in[7];
  const float* cn_b2  = (const float*)d_in[8];
  const float* bn_W1  = (const float*)d_in[9];
  const float* bn_b1  = (const float*)d_in[10];
  const float* bn_W2  = (const float*)d_in[11];
  const float* bn_b2  = (const float*)d_in[12];
  const float* llr_W  = (const float*)d_in[13];
  const float* llr_b  = (const float*)d_in[14];
  float* out = (float*)d_out;

  u16* wfrag = (u16*)d_ws;
  float* labW_g = (float*)((char*)d_ws + 65536);
  float* pred_ws = (float*)((char*)d_ws + STAGE_OFF);
  u16* e9_ws = (u16*)((char*)d_ws + E9_OFF);
  u32* vm_ws = (u32*)((char*)d_ws + VM_OFF);

  prep_kernel<<<13, 256, 0, stream>>>(cn_W1, bn_W1, cn_W2, bn_W2, labemb, llr_W,
                                      bn_b1, wfrag, labW_g);
  if (ws_size >= NEED_SPLIT) {
    polar_a_kernel<<<2 * NB, 512, 0, stream>>>(x, y, emb_W, emb_b, wfrag, labW_g,
                                               cn_b1, cn_b2, bn_b2, llr_W, llr_b,
                                               pred_ws, e9_ws, vm_ws, out);
    polar_b_kernel<<<NB, 512, 0, stream>>>(wfrag, labW_g, cn_b1, cn_b2, bn_b2,
                                           llr_b, pred_ws, e9_ws, vm_ws, out);
    pred_transpose_kernel<<<NB, 512, 0, stream>>>(pred_ws, out);
  } else if (ws_size >= NEED_STAGED) {
    polar_mono_kernel<1><<<NB, 512, 0, stream>>>(x, y, emb_W, emb_b, wfrag, labW_g,
                                                 cn_b1, cn_b2, bn_b2, llr_W, llr_b,
                                                 pred_ws, out);
    pred_transpose_kernel<<<NB, 512, 0, stream>>>(pred_ws, out);
  } else {
    polar_mono_kernel<0><<<NB, 512, 0, stream>>>(x, y, emb_W, emb_b, wfrag, labW_g,
                                                 cn_b1, cn_b2, bn_b2, llr_W, llr_b,
                                                 pred_ws, out);
  }
}

// Round 14
// 230.310 us; speedup vs baseline: 1.1169x; 1.0047x over previous
//
#include <hip/hip_runtime.h>
#include <hip/hip_bf16.h>

#define NB 256
#define NN 1024
#define NSTAGES 11
#define EPSF 1e-7f

typedef unsigned short u16;
typedef unsigned int u32;
typedef unsigned long long u64;
typedef __attribute__((ext_vector_type(8))) short short8;
typedef __attribute__((ext_vector_type(16))) float f32x16;

// Output layout (float32, concatenated):
//   losses (B, 11, N); preds (B, N, 11, 2); norms (B, 11, N)
static constexpr size_t PRED_BASE = (size_t)NB * NSTAGES * NN;
static constexpr size_t NORM_BASE = PRED_BASE + (size_t)NB * NN * NSTAGES * 2;

// wfrag (u16 units): 48 B-fragments for mfma_f32_32x32x16_bf16, channel-pair
// permuted: B[k][n] at lane l, frag (ks,nt): n = 2*(l&31)+nt, k = ks*16+(l>>5)*8+j.
//   cn_W1: 0..15 (K=128) | bn_W1[0:128]: 16..31 | cn_W2: 32..39 | bn_W2: 40..47
//   packed llr_W bf16 pairs (u32[64]) at u16 offset 24576
//   column-packed llr_W pairs (u32[64]: lwc0[32] | lwc1[32]) at u16 24704
//     lwc_c[p] = (W[2p][c], W[2p+1][c]) bf16-packed -> feeds v_dot2_f32_bf16
// labW_g (separate fp32[2][64]): lab_emb[v] @ bn_W1[128:192] + bn_b1  (prep-fused)
static constexpr int LW_OFF = 24576;
static constexpr int LW2_OFF = 24704;

// SPLIT design (R10, confirmed: FETCH 330->11 MB): stages 1..9 have pair
// distance <= 256 -> pairs stay in 512-row halves. Kernel A: 2 blocks/batch,
// ALL 48 frags in LDS. Kernel B: stage 10 + epilogues 9/10 + fused pred
// transpose (R14: saves the separate 256-block dispatch; eL is dead after
// the final epilogue and fits the 90 KB (s,n) tile).
// R13 (confirmed +22 us): epilogue dot products via v_dot2_f32_bf16 — the
// scalar extract+fma chain was ~384 VALU ops/stage/thread; dot2 cut it to
// ~96 (polar_a 144->123 us, VALUBusy 50->45%).
#define WLDS_FR 30   // kernel B / mono fallback

// Workspace layout:
//   wfrag @0 (64 KB) | labW_g @65536 | pred_ws @131072 (23,068,672 B)
//   e9_ws @E9_OFF (512 chunks x 65536 B) | vm_ws @VM_OFF (512 x 16 u32)
static constexpr size_t STAGE_OFF = 131072;
static constexpr size_t PRED_F2_PER_B = (size_t)NSTAGES * NN;
static constexpr size_t PRED_BYTES = (size_t)NB * NSTAGES * NN * 2 * sizeof(float);
static constexpr size_t E9_OFF = STAGE_OFF + PRED_BYTES;
static constexpr size_t E9_BYTES = (size_t)512 * 65536;
static constexpr size_t VM_OFF = E9_OFF + E9_BYTES;
static constexpr size_t NEED_SPLIT = VM_OFF + (size_t)512 * 16 * sizeof(u32);
static constexpr size_t NEED_STAGED = STAGE_OFF + PRED_BYTES;

__device__ __forceinline__ u16 f2bf(float f) {
  unsigned u = __float_as_uint(f);
  unsigned r = (u + 0x7fffu + ((u >> 16) & 1u)) >> 16;
  return (u16)r;
}
__device__ __forceinline__ unsigned pack_bf2(float a, float b) {
  __hip_bfloat162 h = __float22bfloat162_rn(make_float2(a, b));
  return *(unsigned*)&h;
}
__device__ __forceinline__ u32 spread16(u32 v) {
  v = (v | (v << 8)) & 0x00FF00FFu;
  v = (v | (v << 4)) & 0x0F0F0F0Fu;
  v = (v | (v << 2)) & 0x33333333u;
  v = (v | (v << 1)) & 0x55555555u;
  return v;
}

// Packed bf16 dot2 accumulate: c += a.lo*b.lo + a.hi*b.hi.
// Hardware path: v_dot2_f32_bf16. Fallback: exact scalar equivalent of the
// previous extract+fma chain.
__device__ __forceinline__ float bdot(u32 a, u32 b, float c) {
#if __has_builtin(__builtin_amdgcn_fdot2_f32_bf16)
  typedef __attribute__((ext_vector_type(2))) __bf16 bf2;
  union { u32 u; bf2 v; } ua, ub;
  ua.u = a; ub.u = b;
  return __builtin_amdgcn_fdot2_f32_bf16(ua.v, ub.v, c, false);
#else
  float a0 = __uint_as_float(a << 16), a1 = __uint_as_float(a & 0xffff0000u);
  float b0 = __uint_as_float(b << 16), b1 = __uint_as_float(b & 0xffff0000u);
  return fmaf(a1, b1, fmaf(a0, b0, c));
#endif
}

// STAGED: preds -> workspace in (b,s,n,2) order (dense 8 KB/stage window).
// !STAGED: direct scatter to the final (b,n,11,2) layout (fallback).
template <bool STAGED>
__device__ __forceinline__ void emit_out(float* __restrict__ out, float* __restrict__ pred_ws,
                                         int b, int n, int s,
                                         float z0, float z1, float nrm2, int label) {
  float m  = fmaxf(z0, z1);
  float p0 = expf(z0 - m), p1 = expf(z1 - m);
  float inv = 1.0f / (p0 + p1);
  p0 *= inv; p1 *= inv;
  float pt = label ? p1 : p0;
  pt = fminf(fmaxf(pt, EPSF), 1.0f);
  out[((size_t)b * NSTAGES + s) * NN + n] = -logf(pt);
  if (STAGED) {
    ((float2*)pred_ws)[((size_t)b * NSTAGES + s) * NN + n] = make_float2(p0, p1);
  } else {
    size_t pb = PRED_BASE + (((size_t)b * NN + n) * NSTAGES + s) * 2;
    out[pb + 0] = p0;
    out[pb + 1] = p1;
  }
  out[NORM_BASE + ((size_t)b * NSTAGES + s) * NN + n] = sqrtf(nrm2);
}

// Swizzled e-LDS addressing (u16 units). Row = 64 u16 (128 B) = 8 chunks of
// 16 B; physical chunk = logical_chunk XOR (row & 7) to break stride-128 bank
// conflicts on per-lane row gathers. (row & 7) is invariant under the 512-row
// local/global shift, so kernel A's local rows and kernel B's reads agree.
__device__ __forceinline__ int eaddr(int row, int c16) {
  return row * 64 + (((c16) ^ (row & 7)) << 3);
}
__device__ __forceinline__ int eaddr32(int row, int m31) {
  return row * 64 + (((((m31) >> 2) ^ (row & 7)) << 3) | (((m31) & 3) << 1));
}

__global__ __launch_bounds__(256) void prep_kernel(
    const float* __restrict__ cn_W1, const float* __restrict__ bn_W1,
    const float* __restrict__ cn_W2, const float* __restrict__ bn_W2,
    const float* __restrict__ lab_emb, const float* __restrict__ llr_W,
    const float* __restrict__ bn_b1,
    u16* __restrict__ wfrag, float* __restrict__ labW_g) {
  int t = blockIdx.x * 256 + threadIdx.x;
  if (t < 3072) {
    int f = t >> 6, l = t & 63, h = l >> 5, c = l & 31;
    const float* src; int ks, nt;
    if (f < 16)      { src = cn_W1; ks = f >> 1; nt = f & 1; }
    else if (f < 32) { int g = f - 16; src = bn_W1; ks = g >> 1; nt = g & 1; }
    else if (f < 40) { int g = f - 32; src = cn_W2; ks = g >> 1; nt = g & 1; }
    else             { int g = f - 40; src = bn_W2; ks = g >> 1; nt = g & 1; }
    int col = 2 * c + nt;
    u16 vals[8];
    #pragma unroll
    for (int j = 0; j < 8; ++j) {
      int k = ks * 16 + h * 8 + j;
      vals[j] = f2bf(src[k * 64 + col]);
    }
    uint4 u;
    u.x = (unsigned)vals[0] | ((unsigned)vals[1] << 16);
    u.y = (unsigned)vals[2] | ((unsigned)vals[3] << 16);
    u.z = (unsigned)vals[4] | ((unsigned)vals[5] << 16);
    u.w = (unsigned)vals[6] | ((unsigned)vals[7] << 16);
    *(uint4*)(wfrag + (size_t)t * 8) = u;
  } else if (t < 3136) {
    int k = t - 3072;
    unsigned wv = (unsigned)f2bf(llr_W[k * 2]) | ((unsigned)f2bf(llr_W[k * 2 + 1]) << 16);
    ((unsigned*)(wfrag + LW_OFF))[k] = wv;
  } else if (t < 3264) {
    int idx = t - 3136;
    int v = idx >> 6, c = idx & 63;
    float acc = bn_b1[c];
    for (int d = 0; d < 64; ++d)
      acc = fmaf(lab_emb[v * 64 + d], bn_W1[(128 + d) * 64 + c], acc);
    labW_g[idx] = acc;
  } else if (t < 3328) {
    // column-packed llr pairs for the dot2 epilogue:
    // lwc_c[p] = (W[2p][c], W[2p+1][c]) packed bf16.
    int idx2 = t - 3264;
    int col = idx2 >> 5, p = idx2 & 31;
    unsigned lw = (unsigned)f2bf(llr_W[(2 * p) * 2 + col]) |
                  ((unsigned)f2bf(llr_W[(2 * p + 1) * 2 + col]) << 16);
    ((unsigned*)(wfrag + LW2_OFF))[col * 32 + p] = lw;
  }
}

// Memory-only finisher (mono fallback only; split path fuses into polar_b):
// ws (b,s,n,2) -> out preds (b,n,11,2) via an LDS tile.
__global__ __launch_bounds__(512) void pred_transpose_kernel(
    const float* __restrict__ pred_ws, float* __restrict__ out) {
  __shared__ float2 tb[NSTAGES * 1026];
  const int tid = threadIdx.x;
  const int b = blockIdx.x;
  const float2* src = (const float2*)pred_ws + (size_t)b * PRED_F2_PER_B;
  for (int i = tid; i < NSTAGES * NN; i += 512) {
    int s = i >> 10, n = i & (NN - 1);
    tb[s * 1026 + n] = src[i];
  }
  __syncthreads();
  float2* dst = (float2*)(out + PRED_BASE) + (size_t)b * PRED_F2_PER_B;
  for (int j = tid; j < NSTAGES * NN; j += 512) {
    int n = j / NSTAGES, s = j - n * NSTAGES;
    dst[j] = tb[s * 1026 + n];
  }
}

// All-LDS frag read (kernel A, 48 frags resident).
#define AFR(FI) (*(const short8*)(wlds + (FI) * 512 + ln * 8))
// Mixed read (kernel B / mono): 30 LDS + 18 global.
#define BFR(FI) (((FI) < WLDS_FR) ? *(const short8*)(wlds + (FI) * 512 + ln * 8) \
                                  : *(const short8*)(wfrag + (size_t)(FI) * 512 + ln * 8))

// ===================== Kernel A: stages 0..9, half-row blocks ==============
// grid 512: b = blockIdx.x >> 1, h = blockIdx.x & 1. Owns rows [512h,512h+512).
// 8 waves x 1 tile of 32 pairs (R9's flattening, correctness-proven).
// Pairs handled: global i in [256h, 256h+256); local p = i - 256h = 32w+m31.
__global__ __launch_bounds__(512, 2) void polar_a_kernel(
    const int* __restrict__ x, const float* __restrict__ y,
    const float* __restrict__ emb_W, const float* __restrict__ emb_b,
    const u16* __restrict__ wfrag, const float* __restrict__ labW_g,
    const float* __restrict__ cn_b1, const float* __restrict__ cn_b2,
    const float* __restrict__ bn_b2, const float* __restrict__ llr_W,
    const float* __restrict__ llr_b, float* __restrict__ pred_ws,
    u16* __restrict__ e9_ws, u32* __restrict__ vm_ws,
    float* __restrict__ out) {
  __shared__ __align__(16) u16 eLh[512 * 64];          // 65536 B
  __shared__ __align__(16) u16 wlds[48 * 512];         // 49152 B (ALL frags)
  __shared__ __align__(16) u32 lwcL[64];               // 256 B (col-packed llr)
  __shared__ u32 vmask[2][16];                         // 128 B
  __shared__ float labW[2][64];                        // 512 B

  const int tid = threadIdx.x;
  const int w = tid >> 6, ln = tid & 63;
  const int m31 = ln & 31, h8 = ln >> 5;
  const int b = blockIdx.x >> 1, h = blockIdx.x & 1;

  for (int i = tid; i < 48 * 64; i += 512)
    ((uint4*)wlds)[i] = ((const uint4*)wfrag)[i];
  if (tid < 64) lwcL[tid] = ((const u32*)(wfrag + LW2_OFF))[tid];
  if (tid < 128) ((float*)labW)[tid] = labW_g[tid];

  const float lb0 = llr_b[0], lb1 = llr_b[1];
  const float2 cb1 = *(const float2*)(cn_b1 + 2 * m31);
  const float2 cb2 = *(const float2*)(cn_b2 + 2 * m31);
  const float2 bb2 = *(const float2*)(bn_b2 + 2 * m31);

  // ---------------- stage 0: one row per thread ----------------
  {
    int nl = tid;
    int n = 512 * h + nl;
    float2 yv = *(const float2*)(y + ((size_t)b * NN + n) * 2);
    float z0 = lb0, z1 = lb1, nr = 0.f;
    #pragma unroll
    for (int o8 = 0; o8 < 8; ++o8) {
      u32 vals[4];
      #pragma unroll
      for (int jj = 0; jj < 4; ++jj) {
        int o = o8 * 8 + jj * 2;
        float e0 = fmaf(yv.x, emb_W[o],     fmaf(yv.y, emb_W[64 + o],     emb_b[o]));
        float e1 = fmaf(yv.x, emb_W[o + 1], fmaf(yv.y, emb_W[64 + o + 1], emb_b[o + 1]));
        vals[jj] = pack_bf2(e0, e1);
        z0 = fmaf(e0, llr_W[o * 2 + 0], z0); z1 = fmaf(e0, llr_W[o * 2 + 1], z1);
        nr = fmaf(e0, e0, nr);
        z0 = fmaf(e1, llr_W[o * 2 + 2], z0); z1 = fmaf(e1, llr_W[o * 2 + 3], z1);
        nr = fmaf(e1, e1, nr);
      }
      uint4 q; q.x = vals[0]; q.y = vals[1]; q.z = vals[2]; q.w = vals[3];
      *(uint4*)(eLh + eaddr(nl, o8)) = q;
    }
    int v = x[(size_t)b * NN + n] & 1;
    emit_out<true>(out, pred_ws, b, n, 0, z0, z1, nr, v);
    u64 bm = __ballot(v != 0);
    if (ln == 0)  vmask[0][2 * w]     = (u32)bm;
    if (ln == 32) vmask[0][2 * w + 1] = (u32)(bm >> 32);
  }
  __syncthreads();

  const float2 lwv0 = *(const float2*)(&labW[0][2 * m31]);
  const float2 lwv1 = *(const float2*)(&labW[1][2 * m31]);

  // ---------------- stages 1..9 (pairs stay in this half) ----------------
  #pragma unroll 1
  for (int s = 1; s <= 9; ++s) {
    const int sh = s - 1;
    const int half = 1 << sh;
    const u32* vmR = vmask[(s - 1) & 1];
    u32* vmW = vmask[s & 1];

    short8 Ao[4], Ae[4];
    int iog, ieg, iol, iel, vo, ve, vx;
    u32 bxs;
    {
      int i = 256 * h + 32 * w + m31;              // global pair index
      int g = i >> sh, u = i & (half - 1);
      iog = g * (half << 1) + u;
      ieg = iog + half;
      iol = iog & 511; iel = ieg & 511;            // local rows
      #pragma unroll
      for (int f = 0; f < 4; ++f) {
        Ao[f] = *(const short8*)(eLh + eaddr(iol, f * 2 + h8));
        Ae[f] = *(const short8*)(eLh + eaddr(iel, f * 2 + h8));
      }
      vo = (vmR[iol >> 5] >> (iol & 31)) & 1;
      ve = (vmR[iel >> 5] >> (iel & 31)) & 1;
      vx = vo ^ ve;
      u32 bx = (u32)__ballot(vx != 0);
      u32 be = (u32)__ballot(ve != 0);
      bxs = bx;
      u32 lo = spread16(bx & 0xffffu) | (spread16(be & 0xffffu) << 1);
      u32 hi = spread16(bx >> 16) | (spread16(be >> 16) << 1);
      if (ln == 0) { vmW[2 * w] = lo; vmW[2 * w + 1] = hi; }
    }
    __syncthreads();

    // epilogue for stage s-1 (s>=2), A-frags in regs; dot2 path (R13):
    // lane's u32 jj of frag f covers k-pair p = 8f+4h8+jj -> lwc quad 2f+h8.
    if (s >= 2) {
      const uint4* lwq2 = (const uint4*)lwcL;
      #pragma unroll
      for (int side = 0; side < 2; ++side) {
        float z0 = 0.f, z1 = 0.f, nr = 0.f;
        #pragma unroll
        for (int f = 0; f < 4; ++f) {
          short8 av8 = side ? Ae[f] : Ao[f];
          uint4 c0 = lwq2[2 * f + h8];
          uint4 c1 = lwq2[8 + 2 * f + h8];
          #pragma unroll
          for (int jj = 0; jj < 4; ++jj) {
            u32 pv = ((const u32*)&av8)[jj];
            z0 = bdot(pv, ((const u32*)&c0)[jj], z0);
            z1 = bdot(pv, ((const u32*)&c1)[jj], z1);
            nr = bdot(pv, pv, nr);
          }
        }
        z0 += __shfl_xor(z0, 32);
        z1 += __shfl_xor(z1, 32);
        nr += __shfl_xor(nr, 32);
        if (h8 == 0)
          emit_out<true>(out, pred_ws, b, side ? ieg : iog, s - 1,
                         z0 + lb0, z1 + lb1, nr, side ? ve : vo);
      }
    }

    // ---- layer-1 cn (K=128) ----
    f32x16 a0, a1;
    #pragma unroll
    for (int r = 0; r < 16; ++r) { a0[r] = cb1.x; a1[r] = cb1.y; }
    #pragma unroll
    for (int ks = 0; ks < 8; ++ks) {
      short8 B0 = AFR(ks * 2 + 0);
      short8 B1 = AFR(ks * 2 + 1);
      short8 a = (ks < 4) ? Ao[ks] : Ae[ks - 4];
      a0 = __builtin_amdgcn_mfma_f32_32x32x16_bf16(a, B0, a0, 0, 0, 0);
      a1 = __builtin_amdgcn_mfma_f32_32x32x16_bf16(a, B1, a1, 0, 0, 0);
    }
    {
      int obase = 64 * w;
      #pragma unroll
      for (int r = 0; r < 16; ++r) {
        int row = (r & 3) + 8 * (r >> 2) + 4 * h8;
        int R = obase + 2 * row;
        *(u32*)(eLh + eaddr32(R, m31)) =
            pack_bf2(fmaxf(a0[r], 0.f), fmaxf(a1[r], 0.f));
      }
    }

    // ---- layer-1 bn (K=128 + fused labW bias) ----
    #pragma unroll
    for (int r = 0; r < 16; ++r) {
      int row = (r & 3) + 8 * (r >> 2) + 4 * h8;
      int bit = (bxs >> row) & 1;
      a0[r] = bit ? lwv1.x : lwv0.x;
      a1[r] = bit ? lwv1.y : lwv0.y;
    }
    #pragma unroll
    for (int ks = 0; ks < 8; ++ks) {
      short8 B0 = AFR(16 + ks * 2 + 0);
      short8 B1 = AFR(16 + ks * 2 + 1);
      short8 a = (ks < 4) ? Ao[ks] : Ae[ks - 4];
      a0 = __builtin_amdgcn_mfma_f32_32x32x16_bf16(a, B0, a0, 0, 0, 0);
      a1 = __builtin_amdgcn_mfma_f32_32x32x16_bf16(a, B1, a1, 0, 0, 0);
    }
    {
      int obase = 64 * w;
      #pragma unroll
      for (int r = 0; r < 16; ++r) {
        int row = (r & 3) + 8 * (r >> 2) + 4 * h8;
        int R = obase + 2 * row + 1;
        *(u32*)(eLh + eaddr32(R, m31)) =
            pack_bf2(fmaxf(a0[r], 0.f), fmaxf(a1[r], 0.f));
      }
    }

    // ---- layer-2 cn ----
    {
      short8 Hc[4];
      {
        int R = 64 * w + 2 * m31;
        #pragma unroll
        for (int f = 0; f < 4; ++f)
          Hc[f] = *(const short8*)(eLh + eaddr(R, f * 2 + h8));
      }
      f32x16 d0, d1;
      #pragma unroll
      for (int r = 0; r < 16; ++r) { d0[r] = cb2.x; d1[r] = cb2.y; }
      #pragma unroll
      for (int ks = 0; ks < 4; ++ks) {
        short8 B0 = AFR(32 + ks * 2 + 0);
        short8 B1 = AFR(32 + ks * 2 + 1);
        d0 = __builtin_amdgcn_mfma_f32_32x32x16_bf16(Hc[ks], B0, d0, 0, 0, 0);
        d1 = __builtin_amdgcn_mfma_f32_32x32x16_bf16(Hc[ks], B1, d1, 0, 0, 0);
      }
      int obase = 64 * w;
      #pragma unroll
      for (int r = 0; r < 16; ++r) {
        int row = (r & 3) + 8 * (r >> 2) + 4 * h8;
        int R = obase + 2 * row;
        *(u32*)(eLh + eaddr32(R, m31)) = pack_bf2(d0[r], d1[r]);
      }
    }

    // ---- layer-2 bn ----
    {
      short8 Hb[4];
      {
        int R = 64 * w + 2 * m31 + 1;
        #pragma unroll
        for (int f = 0; f < 4; ++f)
          Hb[f] = *(const short8*)(eLh + eaddr(R, f * 2 + h8));
      }
      f32x16 d0, d1;
      #pragma unroll
      for (int r = 0; r < 16; ++r) { d0[r] = bb2.x; d1[r] = bb2.y; }
      #pragma unroll
      for (int ks = 0; ks < 4; ++ks) {
        short8 B0 = AFR(40 + ks * 2 + 0);
        short8 B1 = AFR(40 + ks * 2 + 1);
        d0 = __builtin_amdgcn_mfma_f32_32x32x16_bf16(Hb[ks], B0, d0, 0, 0, 0);
        d1 = __builtin_amdgcn_mfma_f32_32x32x16_bf16(Hb[ks], B1, d1, 0, 0, 0);
      }
      int obase = 64 * w;
      #pragma unroll
      for (int r = 0; r < 16; ++r) {
        int row = (r & 3) + 8 * (r >> 2) + 4 * h8;
        int R = obase + 2 * row + 1;
        *(u32*)(eLh + eaddr32(R, m31)) = pack_bf2(d0[r], d1[r]);
      }
    }
    __syncthreads();
  }

  // ---------------- dump e9 half + stage-9 vmask ----------------
  {
    const uint4* src = (const uint4*)eLh;
    uint4* dst = (uint4*)(e9_ws + (size_t)(b * 2 + h) * 32768);
    for (int i = tid; i < 4096; i += 512) dst[i] = src[i];
    if (tid < 16) vm_ws[(b * 2 + h) * 16 + tid] = vmask[1][tid];  // 9&1 == 1
  }
}

// ===================== Kernel B: stage 10 + epilogues 9,10 + transpose =====
// grid 256 (b), 8 waves x 2 tiles. Reads e9 pairs (i, i+512) from workspace;
// computes stage 10 into full eL; final epilogue; then reuses the dead eL as
// the pred-transpose tile (replaces the separate transpose kernel).
__global__ __launch_bounds__(512, 2) void polar_b_kernel(
    const u16* __restrict__ wfrag, const float* __restrict__ labW_g,
    const float* __restrict__ cn_b1, const float* __restrict__ cn_b2,
    const float* __restrict__ bn_b2, const float* __restrict__ llr_b,
    float* __restrict__ pred_ws, const u16* __restrict__ e9_ws,
    const u32* __restrict__ vm_ws, float* __restrict__ out) {
  __shared__ __align__(16) u16 eL[NN * 64];            // 131072 B
  __shared__ __align__(16) u16 wlds[WLDS_FR * 512];    // 30720 B
  __shared__ __align__(16) u32 lwcL[64];               // 256 B (col-packed llr)
  __shared__ u32 vmA[32];                              // stage-9 labels
  __shared__ u32 vmB[32];                              // stage-10 labels
  __shared__ float labW[2][64];                        // 512 B

  const int tid = threadIdx.x;
  const int w = tid >> 6, ln = tid & 63;
  const int m31 = ln & 31, h8 = ln >> 5;
  const int b = blockIdx.x;

  for (int i = tid; i < WLDS_FR * 64; i += 512)
    ((uint4*)wlds)[i] = ((const uint4*)wfrag)[i];
  if (tid < 64) lwcL[tid] = ((const u32*)(wfrag + LW2_OFF))[tid];
  if (tid < 128) ((float*)labW)[tid] = labW_g[tid];
  if (tid < 32) vmA[tid] = vm_ws[b * 32 + tid];        // h=0 words 0..15, h=1 16..31

  const float lb0 = llr_b[0], lb1 = llr_b[1];
  const float2 cb1 = *(const float2*)(cn_b1 + 2 * m31);
  const float2 cb2 = *(const float2*)(cn_b2 + 2 * m31);
  const float2 bb2 = *(const float2*)(bn_b2 + 2 * m31);
  __syncthreads();                                     // preamble LDS visible

  const float2 lwv0 = *(const float2*)(&labW[0][2 * m31]);
  const float2 lwv1 = *(const float2*)(&labW[1][2 * m31]);

  const u16* e9a = e9_ws + (size_t)(b * 2 + 0) * 32768;
  const u16* e9b = e9_ws + (size_t)(b * 2 + 1) * 32768;

  // ---- A-read phase: pairs (i, i+512) from the two halves ----
  short8 Ao[2][4], Ae[2][4];
  int io[2], ie[2], vo[2], ve[2], vx[2];
  u32 bxs[2];
  #pragma unroll
  for (int t = 0; t < 2; ++t) {
    int i = 64 * w + 32 * t + m31;                     // pair index [0,512)
    io[t] = i; ie[t] = i + 512;
    #pragma unroll
    for (int f = 0; f < 4; ++f) {
      Ao[t][f] = *(const short8*)(e9a + eaddr(i, f * 2 + h8));
      Ae[t][f] = *(const short8*)(e9b + eaddr(i, f * 2 + h8));  // local row = i
    }
    vo[t] = (vmA[i >> 5] >> (i & 31)) & 1;
    ve[t] = (vmA[(i >> 5) + 16] >> (i & 31)) & 1;
    vx[t] = vo[t] ^ ve[t];
    u32 bx = (u32)__ballot(vx[t] != 0);
    u32 be = (u32)__ballot(ve[t] != 0);
    bxs[t] = bx;
    u32 lo = spread16(bx & 0xffffu) | (spread16(be & 0xffffu) << 1);
    u32 hi = spread16(bx >> 16) | (spread16(be >> 16) << 1);
    if (ln == 0) { vmB[4 * w + 2 * t] = lo; vmB[4 * w + 2 * t + 1] = hi; }
  }
  __syncthreads();

  // ---- epilogue for stage 9 (A-frags in regs; dot2 path) ----
  {
    const uint4* lwq2 = (const uint4*)lwcL;
    #pragma unroll
    for (int t = 0; t < 2; ++t) {
      #pragma unroll
      for (int side = 0; side < 2; ++side) {
        float z0 = 0.f, z1 = 0.f, nr = 0.f;
        #pragma unroll
        for (int f = 0; f < 4; ++f) {
          short8 av8 = side ? Ae[t][f] : Ao[t][f];
          uint4 c0 = lwq2[2 * f + h8];
          uint4 c1 = lwq2[8 + 2 * f + h8];
          #pragma unroll
          for (int jj = 0; jj < 4; ++jj) {
            u32 pv = ((const u32*)&av8)[jj];
            z0 = bdot(pv, ((const u32*)&c0)[jj], z0);
            z1 = bdot(pv, ((const u32*)&c1)[jj], z1);
            nr = bdot(pv, pv, nr);
          }
        }
        z0 += __shfl_xor(z0, 32);
        z1 += __shfl_xor(z1, 32);
        nr += __shfl_xor(nr, 32);
        if (h8 == 0)
          emit_out<true>(out, pred_ws, b, side ? ie[t] : io[t], 9,
                         z0 + lb0, z1 + lb1, nr, side ? ve[t] : vo[t]);
      }
    }
  }

  // ---- layer-1 cn ----
  f32x16 a0[2], a1[2];
  #pragma unroll
  for (int t = 0; t < 2; ++t)
    #pragma unroll
    for (int r = 0; r < 16; ++r) { a0[t][r] = cb1.x; a1[t][r] = cb1.y; }
  #pragma unroll
  for (int ks = 0; ks < 8; ++ks) {
    short8 B0 = BFR(ks * 2 + 0);
    short8 B1 = BFR(ks * 2 + 1);
    #pragma unroll
    for (int t = 0; t < 2; ++t) {
      short8 a = (ks < 4) ? Ao[t][ks] : Ae[t][ks - 4];
      a0[t] = __builtin_amdgcn_mfma_f32_32x32x16_bf16(a, B0, a0[t], 0, 0, 0);
      a1[t] = __builtin_amdgcn_mfma_f32_32x32x16_bf16(a, B1, a1[t], 0, 0, 0);
    }
  }
  #pragma unroll
  for (int t = 0; t < 2; ++t) {
    int obase = 128 * w + 64 * t;
    #pragma unroll
    for (int r = 0; r < 16; ++r) {
      int row = (r & 3) + 8 * (r >> 2) + 4 * h8;
      int R = obase + 2 * row;
      *(u32*)(eL + eaddr32(R, m31)) =
          pack_bf2(fmaxf(a0[t][r], 0.f), fmaxf(a1[t][r], 0.f));
    }
  }

  // ---- layer-1 bn ----
  #pragma unroll
  for (int t = 0; t < 2; ++t)
    #pragma unroll
    for (int r = 0; r < 16; ++r) {
      int row = (r & 3) + 8 * (r >> 2) + 4 * h8;
      int bit = (bxs[t] >> row) & 1;
      a0[t][r] = bit ? lwv1.x : lwv0.x;
      a1[t][r] = bit ? lwv1.y : lwv0.y;
    }
  #pragma unroll
  for (int ks = 0; ks < 8; ++ks) {
    short8 B0 = BFR(16 + ks * 2 + 0);
    short8 B1 = BFR(16 + ks * 2 + 1);
    #pragma unroll
    for (int t = 0; t < 2; ++t) {
      short8 a = (ks < 4) ? Ao[t][ks] : Ae[t][ks - 4];
      a0[t] = __builtin_amdgcn_mfma_f32_32x32x16_bf16(a, B0, a0[t], 0, 0, 0);
      a1[t] = __builtin_amdgcn_mfma_f32_32x32x16_bf16(a, B1, a1[t], 0, 0, 0);
    }
  }
  #pragma unroll
  for (int t = 0; t < 2; ++t) {
    int obase = 128 * w + 64 * t;
    #pragma unroll
    for (int r = 0; r < 16; ++r) {
      int row = (r & 3) + 8 * (r >> 2) + 4 * h8;
      int R = obase + 2 * row + 1;
      *(u32*)(eL + eaddr32(R, m31)) =
          pack_bf2(fmaxf(a0[t][r], 0.f), fmaxf(a1[t][r], 0.f));
    }
  }

  // ---- layer-2 cn ----
  {
    short8 Hc[2][4];
    #pragma unroll
    for (int t = 0; t < 2; ++t) {
      int R = 128 * w + 64 * t + 2 * m31;
      #pragma unroll
      for (int f = 0; f < 4; ++f)
        Hc[t][f] = *(const short8*)(eL + eaddr(R, f * 2 + h8));
    }
    f32x16 d0[2], d1[2];
    #pragma unroll
    for (int t = 0; t < 2; ++t)
      #pragma unroll
      for (int r = 0; r < 16; ++r) { d0[t][r] = cb2.x; d1[t][r] = cb2.y; }
    #pragma unroll
    for (int ks = 0; ks < 4; ++ks) {
      short8 B0 = BFR(32 + ks * 2 + 0);
      short8 B1 = BFR(32 + ks * 2 + 1);
      #pragma unroll
      for (int t = 0; t < 2; ++t) {
        d0[t] = __builtin_amdgcn_mfma_f32_32x32x16_bf16(Hc[t][ks], B0, d0[t], 0, 0, 0);
        d1[t] = __builtin_amdgcn_mfma_f32_32x32x16_bf16(Hc[t][ks], B1, d1[t], 0, 0, 0);
      }
    }
    #pragma unroll
    for (int t = 0; t < 2; ++t) {
      int obase = 128 * w + 64 * t;
      #pragma unroll
      for (int r = 0; r < 16; ++r) {
        int row = (r & 3) + 8 * (r >> 2) + 4 * h8;
        int R = obase + 2 * row;
        *(u32*)(eL + eaddr32(R, m31)) = pack_bf2(d0[t][r], d1[t][r]);
      }
    }
  }

  // ---- layer-2 bn ----
  {
    short8 Hb[2][4];
    #pragma unroll
    for (int t = 0; t < 2; ++t) {
      int R = 128 * w + 64 * t + 2 * m31 + 1;
      #pragma unroll
      for (int f = 0; f < 4; ++f)
        Hb[t][f] = *(const short8*)(eL + eaddr(R, f * 2 + h8));
    }
    f32x16 d0[2], d1[2];
    #pragma unroll
    for (int t = 0; t < 2; ++t)
      #pragma unroll
      for (int r = 0; r < 16; ++r) { d0[t][r] = bb2.x; d1[t][r] = bb2.y; }
    #pragma unroll
    for (int ks = 0; ks < 4; ++ks) {
      short8 B0 = BFR(40 + ks * 2 + 0);
      short8 B1 = BFR(40 + ks * 2 + 1);
      #pragma unroll
      for (int t = 0; t < 2; ++t) {
        d0[t] = __builtin_amdgcn_mfma_f32_32x32x16_bf16(Hb[t][ks], B0, d0[t], 0, 0, 0);
        d1[t] = __builtin_amdgcn_mfma_f32_32x32x16_bf16(Hb[t][ks], B1, d1[t], 0, 0, 0);
      }
    }
    #pragma unroll
    for (int t = 0; t < 2; ++t) {
      int obase = 128 * w + 64 * t;
      #pragma unroll
      for (int r = 0; r < 16; ++r) {
        int row = (r & 3) + 8 * (r >> 2) + 4 * h8;
        int R = obase + 2 * row + 1;
        *(u32*)(eL + eaddr32(R, m31)) = pack_bf2(d0[t][r], d1[t][r]);
      }
    }
  }
  __syncthreads();

  // ---- final epilogue (stage 10; dot2 path) ----
  {
    const uint4* lwq2 = (const uint4*)lwcL;
    #pragma unroll
    for (int it = 0; it < 4; ++it) {
      int n = 128 * w + 32 * it + m31;
      float z0 = 0.f, z1 = 0.f, nr = 0.f;
      #pragma unroll
      for (int f = 0; f < 4; ++f) {
        short8 av8 = *(const short8*)(eL + eaddr(n, f * 2 + h8));
        uint4 c0 = lwq2[2 * f + h8];
        uint4 c1 = lwq2[8 + 2 * f + h8];
        #pragma unroll
        for (int jj = 0; jj < 4; ++jj) {
          u32 pv = ((const u32*)&av8)[jj];
          z0 = bdot(pv, ((const u32*)&c0)[jj], z0);
          z1 = bdot(pv, ((const u32*)&c1)[jj], z1);
          nr = bdot(pv, pv, nr);
        }
      }
      z0 += __shfl_xor(z0, 32);
      z1 += __shfl_xor(z1, 32);
      nr += __shfl_xor(nr, 32);
      int lab = (vmB[n >> 5] >> (n & 31)) & 1;
      if (h8 == 0)
        emit_out<true>(out, pred_ws, b, n, NSTAGES - 1, z0 + lb0, z1 + lb1, nr, lab);
    }
  }

  // ---- fused pred transpose (eL is dead; reuse as (s,n) tile) ----
  // __syncthreads orders this block's own pred_ws global writes (stages 9,10)
  // before the read-back; stages 0..8 were written by polar_a (kernel-ordered).
  __syncthreads();
  {
    float2* tb = (float2*)eL;                          // 11*1026*8 = 90288 B
    const float2* srcp = (const float2*)pred_ws + (size_t)b * PRED_F2_PER_B;
    for (int i = tid; i < NSTAGES * NN; i += 512) {
      int s = i >> 10, n = i & (NN - 1);
      tb[s * 1026 + n] = srcp[i];
    }
    __syncthreads();
    float2* dstp = (float2*)(out + PRED_BASE) + (size_t)b * PRED_F2_PER_B;
    for (int j = tid; j < NSTAGES * NN; j += 512) {
      int n = j / NSTAGES, s = j - n * NSTAGES;
      dstp[j] = tb[s * 1026 + n];
    }
  }
}

// ===================== Mono fallback (R6, best single-kernel) ==============
template <int STAGED>
__global__ __launch_bounds__(512, 2) void polar_mono_kernel(
    const int* __restrict__ x, const float* __restrict__ y,
    const float* __restrict__ emb_W, const float* __restrict__ emb_b,
    const u16* __restrict__ wfrag, const float* __restrict__ labW_g,
    const float* __restrict__ cn_b1, const float* __restrict__ cn_b2,
    const float* __restrict__ bn_b2, const float* __restrict__ llr_W,
    const float* __restrict__ llr_b, float* __restrict__ pred_ws,
    float* __restrict__ out) {
  __shared__ __align__(16) u16 eL[NN * 64];
  __shared__ __align__(16) u16 wlds[WLDS_FR * 512];
  __shared__ u32 lwL[64];
  __shared__ u32 vmask[2][32];
  __shared__ float labW[2][64];

  const int tid = threadIdx.x;
  const int w = tid >> 6, ln = tid & 63;
  const int m31 = ln & 31, h8 = ln >> 5;
  const int b = blockIdx.x;

  for (int i = tid; i < WLDS_FR * 64; i += 512)
    ((uint4*)wlds)[i] = ((const uint4*)wfrag)[i];
  if (tid < 64) lwL[tid] = ((const u32*)(wfrag + LW_OFF))[tid];
  if (tid < 128) ((float*)labW)[tid] = labW_g[tid];

  const float lb0 = llr_b[0], lb1 = llr_b[1];
  const float2 cb1 = *(const float2*)(cn_b1 + 2 * m31);
  const float2 cb2 = *(const float2*)(cn_b2 + 2 * m31);
  const float2 bb2 = *(const float2*)(bn_b2 + 2 * m31);

  #pragma unroll
  for (int rep = 0; rep < 2; ++rep) {
    int n = rep * 512 + tid;
    float2 yv = *(const float2*)(y + ((size_t)b * NN + n) * 2);
    float z0 = lb0, z1 = lb1, nr = 0.f;
    #pragma unroll
    for (int o8 = 0; o8 < 8; ++o8) {
      u32 vals[4];
      #pragma unroll
      for (int jj = 0; jj < 4; ++jj) {
        int o = o8 * 8 + jj * 2;
        float e0 = fmaf(yv.x, emb_W[o],     fmaf(yv.y, emb_W[64 + o],     emb_b[o]));
        float e1 = fmaf(yv.x, emb_W[o + 1], fmaf(yv.y, emb_W[64 + o + 1], emb_b[o + 1]));
        vals[jj] = pack_bf2(e0, e1);
        z0 = fmaf(e0, llr_W[o * 2 + 0], z0); z1 = fmaf(e0, llr_W[o * 2 + 1], z1);
        nr = fmaf(e0, e0, nr);
        z0 = fmaf(e1, llr_W[o * 2 + 2], z0); z1 = fmaf(e1, llr_W[o * 2 + 3], z1);
        nr = fmaf(e1, e1, nr);
      }
      uint4 q; q.x = vals[0]; q.y = vals[1]; q.z = vals[2]; q.w = vals[3];
      *(uint4*)(eL + eaddr(n, o8)) = q;
    }
    int v = x[(size_t)b * NN + n] & 1;
    emit_out<STAGED != 0>(out, pred_ws, b, n, 0, z0, z1, nr, v);
    u64 bm = __ballot(v != 0);
    if (ln == 0)  vmask[0][rep * 16 + 2 * w]     = (u32)bm;
    if (ln == 32) vmask[0][rep * 16 + 2 * w + 1] = (u32)(bm >> 32);
  }
  __syncthreads();

  const float2 lwv0 = *(const float2*)(&labW[0][2 * m31]);
  const float2 lwv1 = *(const float2*)(&labW[1][2 * m31]);

  #pragma unroll 1
  for (int s = 1; s <= 10; ++s) {
    const int sh = s - 1;
    const int half = 1 << sh;
    const u32* vmR = vmask[(s - 1) & 1];
    u32* vmW = vmask[s & 1];

    short8 Ao[2][4], Ae[2][4];
    int io[2], ie[2], vo[2], ve[2], vx[2];
    u32 bxs[2];
    #pragma unroll
    for (int t = 0; t < 2; ++t) {
      int i = 64 * w + 32 * t + m31;
      int g = i >> sh, u = i & (half - 1);
      io[t] = g * (half << 1) + u;
      ie[t] = io[t] + half;
      #pragma unroll
      for (int f = 0; f < 4; ++f) {
        Ao[t][f] = *(const short8*)(eL + eaddr(io[t], f * 2 + h8));
        Ae[t][f] = *(const short8*)(eL + eaddr(ie[t], f * 2 + h8));
      }
      vo[t] = (vmR[io[t] >> 5] >> (io[t] & 31)) & 1;
      ve[t] = (vmR[ie[t] >> 5] >> (ie[t] & 31)) & 1;
      vx[t] = vo[t] ^ ve[t];
      u32 bx = (u32)__ballot(vx[t] != 0);
      u32 be = (u32)__ballot(ve[t] != 0);
      bxs[t] = bx;
      u32 lo = spread16(bx & 0xffffu) | (spread16(be & 0xffffu) << 1);
      u32 hi = spread16(bx >> 16) | (spread16(be >> 16) << 1);
      if (ln == 0) { vmW[4 * w + 2 * t] = lo; vmW[4 * w + 2 * t + 1] = hi; }
    }
    __syncthreads();

    if (s >= 2) {
      const uint4* lwq = (const uint4*)lwL;
      uint4 lq[4][2];
      #pragma unroll
      for (int f = 0; f < 4; ++f) {
        lq[f][0] = lwq[f * 4 + h8 * 2];
        lq[f][1] = lwq[f * 4 + h8 * 2 + 1];
      }
      #pragma unroll
      for (int t = 0; t < 2; ++t) {
        #pragma unroll
        for (int side = 0; side < 2; ++side) {
          float z0 = 0.f, z1 = 0.f, nr = 0.f;
          #pragma unroll
          for (int f = 0; f < 4; ++f) {
            short8 av8 = side ? Ae[t][f] : Ao[t][f];
            #pragma unroll
            for (int j = 0; j < 8; ++j) {
              u32 pv = ((const u32*)&av8)[j >> 1];
              float val = __uint_as_float((j & 1) ? (pv & 0xffff0000u) : (pv << 16));
              u32 lwp = (j < 4) ? ((const u32*)&lq[f][0])[j] : ((const u32*)&lq[f][1])[j - 4];
              z0 = fmaf(val, __uint_as_float(lwp << 16), z0);
              z1 = fmaf(val, __uint_as_float(lwp & 0xffff0000u), z1);
              nr = fmaf(val, val, nr);
            }
          }
          z0 += __shfl_xor(z0, 32);
          z1 += __shfl_xor(z1, 32);
          nr += __shfl_xor(nr, 32);
          if (h8 == 0)
            emit_out<STAGED != 0>(out, pred_ws, b, side ? ie[t] : io[t], s - 1,
                                  z0 + lb0, z1 + lb1, nr, side ? ve[t] : vo[t]);
        }
      }
    }

    f32x16 a0[2], a1[2];
    #pragma unroll
    for (int t = 0; t < 2; ++t)
      #pragma unroll
      for (int r = 0; r < 16; ++r) { a0[t][r] = cb1.x; a1[t][r] = cb1.y; }
    #pragma unroll
    for (int ks = 0; ks < 8; ++ks) {
      short8 B0 = BFR(ks * 2 + 0);
      short8 B1 = BFR(ks * 2 + 1);
      #pragma unroll
      for (int t = 0; t < 2; ++t) {
        short8 a = (ks < 4) ? Ao[t][ks] : Ae[t][ks - 4];
        a0[t] = __builtin_amdgcn_mfma_f32_32x32x16_bf16(a, B0, a0[t], 0, 0, 0);
        a1[t] = __builtin_amdgcn_mfma_f32_32x32x16_bf16(a, B1, a1[t], 0, 0, 0);
      }
    }
    #pragma unroll
    for (int t = 0; t < 2; ++t) {
      int obase = 128 * w + 64 * t;
      #pragma unroll
      for (int r = 0; r < 16; ++r) {
        int row = (r & 3) + 8 * (r >> 2) + 4 * h8;
        int R = obase + 2 * row;
        *(u32*)(eL + eaddr32(R, m31)) =
            pack_bf2(fmaxf(a0[t][r], 0.f), fmaxf(a1[t][r], 0.f));
      }
    }

    #pragma unroll
    for (int t = 0; t < 2; ++t)
      #pragma unroll
      for (int r = 0; r < 16; ++r) {
        int row = (r & 3) + 8 * (r >> 2) + 4 * h8;
        int bit = (bxs[t] >> row) & 1;
        a0[t][r] = bit ? lwv1.x : lwv0.x;
        a1[t][r] = bit ? lwv1.y : lwv0.y;
      }
    #pragma unroll
    for (int ks = 0; ks < 8; ++ks) {
      short8 B0 = BFR(16 + ks * 2 + 0);
      short8 B1 = BFR(16 + ks * 2 + 1);
      #pragma unroll
      for (int t = 0; t < 2; ++t) {
        short8 a = (ks < 4) ? Ao[t][ks] : Ae[t][ks - 4];
        a0[t] = __builtin_amdgcn_mfma_f32_32x32x16_bf16(a, B0, a0[t], 0, 0, 0);
        a1[t] = __builtin_amdgcn_mfma_f32_32x32x16_bf16(a, B1, a1[t], 0, 0, 0);
      }
    }
    #pragma unroll
    for (int t = 0; t < 2; ++t) {
      int obase = 128 * w + 64 * t;
      #pragma unroll
      for (int r = 0; r < 16; ++r) {
        int row = (r & 3) + 8 * (r >> 2) + 4 * h8;
        int R = obase + 2 * row + 1;
        *(u32*)(eL + eaddr32(R, m31)) =
            pack_bf2(fmaxf(a0[t][r], 0.f), fmaxf(a1[t][r], 0.f));
      }
    }

    {
      short8 Hc[2][4];
      #pragma unroll
      for (int t = 0; t < 2; ++t) {
        int R = 128 * w + 64 * t + 2 * m31;
        #pragma unroll
        for (int f = 0; f < 4; ++f)
          Hc[t][f] = *(const short8*)(eL + eaddr(R, f * 2 + h8));
      }
      f32x16 d0[2], d1[2];
      #pragma unroll
      for (int t = 0; t < 2; ++t)
        #pragma unroll
        for (int r = 0; r < 16; ++r) { d0[t][r] = cb2.x; d1[t][r] = cb2.y; }
      #pragma unroll
      for (int ks = 0; ks < 4; ++ks) {
        short8 B0 = BFR(32 + ks * 2 + 0);
        short8 B1 = BFR(32 + ks * 2 + 1);
        #pragma unroll
        for (int t = 0; t < 2; ++t) {
          d0[t] = __builtin_amdgcn_mfma_f32_32x32x16_bf16(Hc[t][ks], B0, d0[t], 0, 0, 0);
          d1[t] = __builtin_amdgcn_mfma_f32_32x32x16_bf16(Hc[t][ks], B1, d1[t], 0, 0, 0);
        }
      }
      #pragma unroll
      for (int t = 0; t < 2; ++t) {
        int obase = 128 * w + 64 * t;
        #pragma unroll
        for (int r = 0; r < 16; ++r) {
          int row = (r & 3) + 8 * (r >> 2) + 4 * h8;
          int R = obase + 2 * row;
          *(u32*)(eL + eaddr32(R, m31)) = pack_bf2(d0[t][r], d1[t][r]);
        }
      }
    }

    {
      short8 Hb[2][4];
      #pragma unroll
      for (int t = 0; t < 2; ++t) {
        int R = 128 * w + 64 * t + 2 * m31 + 1;
        #pragma unroll
        for (int f = 0; f < 4; ++f)
          Hb[t][f] = *(const short8*)(eL + eaddr(R, f * 2 + h8));
      }
      f32x16 d0[2], d1[2];
      #pragma unroll
      for (int t = 0; t < 2; ++t)
        #pragma unroll
        for (int r = 0; r < 16; ++r) { d0[t][r] = bb2.x; d1[t][r] = bb2.y; }
      #pragma unroll
      for (int ks = 0; ks < 4; ++ks) {
        short8 B0 = BFR(40 + ks * 2 + 0);
        short8 B1 = BFR(40 + ks * 2 + 1);
        #pragma unroll
        for (int t = 0; t < 2; ++t) {
          d0[t] = __builtin_amdgcn_mfma_f32_32x32x16_bf16(Hb[t][ks], B0, d0[t], 0, 0, 0);
          d1[t] = __builtin_amdgcn_mfma_f32_32x32x16_bf16(Hb[t][ks], B1, d1[t], 0, 0, 0);
        }
      }
      #pragma unroll
      for (int t = 0; t < 2; ++t) {
        int obase = 128 * w + 64 * t;
        #pragma unroll
        for (int r = 0; r < 16; ++r) {
          int row = (r & 3) + 8 * (r >> 2) + 4 * h8;
          int R = obase + 2 * row + 1;
          *(u32*)(eL + eaddr32(R, m31)) = pack_bf2(d0[t][r], d1[t][r]);
        }
      }
    }
    __syncthreads();
  }

  {
    const uint4* lwq = (const uint4*)lwL;
    uint4 lq[4][2];
    #pragma unroll
    for (int f = 0; f < 4; ++f) {
      lq[f][0] = lwq[f * 4 + h8 * 2];
      lq[f][1] = lwq[f * 4 + h8 * 2 + 1];
    }
    #pragma unroll
    for (int it = 0; it < 4; ++it) {
      int n = 128 * w + 32 * it + m31;
      float z0 = 0.f, z1 = 0.f, nr = 0.f;
      #pragma unroll
      for (int f = 0; f < 4; ++f) {
        short8 av8 = *(const short8*)(eL + eaddr(n, f * 2 + h8));
        #pragma unroll
        for (int j = 0; j < 8; ++j) {
          u32 pv = ((const u32*)&av8)[j >> 1];
          float val = __uint_as_float((j & 1) ? (pv & 0xffff0000u) : (pv << 16));
          u32 lwp = (j < 4) ? ((const u32*)&lq[f][0])[j] : ((const u32*)&lq[f][1])[j - 4];
          z0 = fmaf(val, __uint_as_float(lwp << 16), z0);
          z1 = fmaf(val, __uint_as_float(lwp & 0xffff0000u), z1);
          nr = fmaf(val, val, nr);
        }
      }
      z0 += __shfl_xor(z0, 32);
      z1 += __shfl_xor(z1, 32);
      nr += __shfl_xor(nr, 32);
      int lab = (vmask[0][n >> 5] >> (n & 31)) & 1;
      if (h8 == 0)
        emit_out<STAGED != 0>(out, pred_ws, b, n, NSTAGES - 1, z0 + lb0, z1 + lb1, nr, lab);
    }
  }
}

extern "C" void kernel_launch(void* const* d_in, const int* in_sizes, int n_in,
                              void* d_out, int out_size, void* d_ws, size_t ws_size,
                              hipStream_t stream) {
  const int*   x      = (const int*)d_in[0];
  const float* y      = (const float*)d_in[1];
  const float* emb_W  = (const float*)d_in[2];
  const float* emb_b  = (const float*)d_in[3];
  const float* labemb = (const float*)d_in[4];
  const float* cn_W1  = (const float*)d_in[5];
  const float* cn_b1  = (const float*)d_in[6];
  const float* cn_W2  = (const float*)d_in[7];
  const float* cn_b2  = (const float*)d_in[8];
  const float* bn_W1  = (const float*)d_in[9];
  const float* bn_b1  = (const float*)d_in[10];
  const float* bn_W2  = (const float*)d_in[11];
  const float* bn_b2  = (const float*)d_in[12];
  const float* llr_W  = (const float*)d_in[13];
  const float* llr_b  = (const float*)d_in[14];
  float* out = (float*)d_out;

  u16* wfrag = (u16*)d_ws;
  float* labW_g = (float*)((char*)d_ws + 65536);
  float* pred_ws = (float*)((char*)d_ws + STAGE_OFF);
  u16* e9_ws = (u16*)((char*)d_ws + E9_OFF);
  u32* vm_ws = (u32*)((char*)d_ws + VM_OFF);

  prep_kernel<<<13, 256, 0, stream>>>(cn_W1, bn_W1, cn_W2, bn_W2, labemb, llr_W,
                                      bn_b1, wfrag, labW_g);
  if (ws_size >= NEED_SPLIT) {
    polar_a_kernel<<<2 * NB, 512, 0, stream>>>(x, y, emb_W, emb_b, wfrag, labW_g,
                                               cn_b1, cn_b2, bn_b2, llr_W, llr_b,
                                               pred_ws, e9_ws, vm_ws, out);
    polar_b_kernel<<<NB, 512, 0, stream>>>(wfrag, labW_g, cn_b1, cn_b2, bn_b2,
                                           llr_b, pred_ws, e9_ws, vm_ws, out);
  } else if (ws_size >= NEED_STAGED) {
    polar_mono_kernel<1><<<NB, 512, 0, stream>>>(x, y, emb_W, emb_b, wfrag, labW_g,
                                                 cn_b1, cn_b2, bn_b2, llr_W, llr_b,
                                                 pred_ws, out);
    pred_transpose_kernel<<<NB, 512, 0, stream>>>(pred_ws, out);
  } else {
    polar_mono_kernel<0><<<NB, 512, 0, stream>>>(x, y, emb_W, emb_b, wfrag, labW_g,
                                                 cn_b1, cn_b2, bn_b2, llr_W, llr_b,
                                                 pred_ws, out);
  }
}